// Round 7
// baseline (482.783 us; speedup 1.0000x reference)
//
#include <hip/hip_runtime.h>
#include <math.h>

// ---- problem constants ----
#define TT 2048
#define HH 1024
#define NHEADS 16
#define NKVH 4
#define HDIM 64
#define NEXP 32
#define TOPK_ 4
#define NGRP 4
#define IMID 384
#define ISHARED 384
#define QKV_W (24*64)   // 1536
#define EPS_ 1e-5f

typedef __attribute__((ext_vector_type(8))) short short8;
typedef __attribute__((ext_vector_type(4))) float f32x4;

__device__ __forceinline__ ushort f2bf(float x) {
  union { float f; unsigned u; } v; v.f = x;
  unsigned r = v.u + 0x7fffu + ((v.u >> 16) & 1u);
  return (ushort)(r >> 16);
}
__device__ __forceinline__ float bf2f(ushort u) {
  union { unsigned i; float f; } v; v.i = (unsigned)u << 16; return v.f;
}

// async global->LDS, 16B per lane; lds dst = wave-uniform base + lane*16
__device__ __forceinline__ void gload16(const void* g, void* l) {
  __builtin_amdgcn_global_load_lds(
      (const __attribute__((address_space(1))) unsigned int*)g,
      (__attribute__((address_space(3))) unsigned int*)l, 16, 0, 0);
}

// =====================================================================
// MFMA fragment layouts (16x16x32 bf16), verified rounds 1-6:
//   A-frag lane l: A[row=l&15][k in {4g+j, 16+4g+j}], g=l>>4
//   B-frag lane l: B[k in {4g+j, 16+4g+j}][col=l&15]
//   C lane l: C[row=(l>>4)*4+i][col=l&15]
// A LDS plane: [g][128 rows][8] with row^g swizzle (8 KB / buffer).
// B LDS plane: 4 planes x 1024B, 16B-granular column XOR swizzle (4 KB).
// =====================================================================
__device__ __forceinline__ void write_A_regs(ushort* As, int g, int row,
                                             float4 h0, float4 h1) {
  short8 v;
  v[0]=(short)f2bf(h0.x); v[1]=(short)f2bf(h0.y); v[2]=(short)f2bf(h0.z); v[3]=(short)f2bf(h0.w);
  v[4]=(short)f2bf(h1.x); v[5]=(short)f2bf(h1.y); v[6]=(short)f2bf(h1.z); v[7]=(short)f2bf(h1.w);
  *(short8*)(As + ((g * 128 + (row ^ g)) * 8)) = v;
}
__device__ __forceinline__ void write_A_bf16(ushort* As, int g, int row,
                                             ushort4 lo, ushort4 hi) {
  short8 v;
  v[0]=(short)lo.x; v[1]=(short)lo.y; v[2]=(short)lo.z; v[3]=(short)lo.w;
  v[4]=(short)hi.x; v[5]=(short)hi.y; v[6]=(short)hi.z; v[7]=(short)hi.w;
  *(short8*)(As + ((g * 128 + (row ^ g)) * 8)) = v;
}
__device__ __forceinline__ short8 read_a_frag128(const ushort* As, int lg, int row) {
  return *(const short8*)(As + ((lg * 128 + (row ^ lg)) * 8));
}
__device__ __forceinline__ short8 read_b_frag(const ushort* Bs, int lg, int col) {
  int boff = (col * 16) ^ (((col >> 3) & 7) << 4);
  return *(const short8*)((const char*)Bs + lg * 1024 + boff);
}

// B-tile staging from f32 (used by pack kernel and attention V)
__device__ __forceinline__ void stage_B_tile(const float* __restrict__ B, int ldb,
                                             int k0, int col0, ushort* Bs, int tid) {
  int a = tid >> 4;
  int cG = tid & 15;
  int k = 2 * a;
  const float* p0 = B + (size_t)(k0 + k) * ldb + col0 + cG * 4;
  const float* p1 = p0 + ldb;
  float4 r0 = *(const float4*)p0;
  float4 r1 = *(const float4*)p1;
  int gg = (k & 15) >> 2;
  int slot = (k & 3) + ((k >> 4) << 2);
  float v0[4] = {r0.x, r0.y, r0.z, r0.w};
  float v1[4] = {r1.x, r1.y, r1.z, r1.w};
  char* plane = (char*)Bs + gg * 1024;
  #pragma unroll
  for (int j = 0; j < 4; ++j) {
    int c = cG * 4 + j;
    unsigned pk = (unsigned)f2bf(v0[j]) | ((unsigned)f2bf(v1[j]) << 16);
    int boff = ((c * 16) ^ (((c >> 3) & 7) << 4)) + slot * 2;
    *(unsigned*)(plane + boff) = pk;
  }
}

// ---------------------------------------------------------------------
// Pack kernel: f32 KxN matrix -> bf16 pre-swizzled B-tile images.
// grid (N/64, Ktot/32). Tile (kt,nt) -> dst[(kt*gridDim.x + nt)*2048].
// Bit-identical to stage_B_tile's LDS image by construction.
// ---------------------------------------------------------------------
__global__ __launch_bounds__(256) void pack_B_kernel(
    const float* __restrict__ src, ushort* __restrict__ dst, int N) {
  __shared__ ushort tileB[2048];
  int tid = threadIdx.x;
  stage_B_tile(src, N, blockIdx.y * 32, blockIdx.x * 64, tileB, tid);
  __syncthreads();
  size_t toff = ((size_t)blockIdx.y * gridDim.x + blockIdx.x) * 2048;
  *(short8*)(dst + toff + tid * 8) = *(const short8*)(tileB + tid * 8);
}

// ---------------------------------------------------------------------
// Dense GEMM, packed B: C(MxN,f32) = A(MxK,f32) @ Bpk. BM=128, BN=64.
// B: global_load_lds double-buffered; A: reg-prefetch + late ds_write.
// ---------------------------------------------------------------------
__global__ __launch_bounds__(256) void gemm128_pk(
    const float* __restrict__ A, const ushort* __restrict__ Bpk,
    float* __restrict__ C, int M, int N, int K) {
  __shared__ ushort As[2][4096];
  __shared__ ushort Bs[2][2048];
  int tid = threadIdx.x;
  int row0 = blockIdx.y * 128, col0 = blockIdx.x * 64;
  int g = tid & 3, r = tid >> 2;
  const float* arow0 = A + (size_t)(row0 + r) * K + 4 * g;
  const float* arow1 = arow0 + (size_t)64 * K;
  int ntn = N >> 6;
  const ushort* bt0 = Bpk + (size_t)blockIdx.x * 2048;
  int wid = tid >> 6, lane = tid & 63;
  int lg = lane >> 4, lr = lane & 15;
  int wrow = wid * 32;
  int lbase = (tid & 192) * 8;                 // wave-uniform LDS ushort offset
  int NT = K >> 5;
  f32x4 acc[2][4] = {};
  float4 a00 = *(const float4*)(arow0);
  float4 a01 = *(const float4*)(arow0 + 16);
  float4 a10 = *(const float4*)(arow1);
  float4 a11 = *(const float4*)(arow1 + 16);
  gload16(bt0 + tid * 8, &Bs[0][lbase]);
  write_A_regs(&As[0][0], g, r, a00, a01);
  write_A_regs(&As[0][0], g, r + 64, a10, a11);
  __syncthreads();
  int cur = 0;
  for (int t = 0; t < NT; ++t) {
    bool more = (t + 1 < NT);
    if (more) {
      gload16(bt0 + (size_t)(t + 1) * ntn * 2048 + tid * 8, &Bs[cur ^ 1][lbase]);
      int k0 = (t + 1) << 5;
      a00 = *(const float4*)(arow0 + k0);
      a01 = *(const float4*)(arow0 + k0 + 16);
      a10 = *(const float4*)(arow1 + k0);
      a11 = *(const float4*)(arow1 + k0 + 16);
    }
    short8 af0 = read_a_frag128(&As[cur][0], lg, wrow + lr);
    short8 af1 = read_a_frag128(&As[cur][0], lg, wrow + 16 + lr);
    #pragma unroll
    for (int nn = 0; nn < 4; ++nn) {
      short8 bf_ = read_b_frag(&Bs[cur][0], lg, nn * 16 + lr);
      acc[0][nn] = __builtin_amdgcn_mfma_f32_16x16x32_bf16(af0, bf_, acc[0][nn], 0, 0, 0);
      acc[1][nn] = __builtin_amdgcn_mfma_f32_16x16x32_bf16(af1, bf_, acc[1][nn], 0, 0, 0);
    }
    if (more) {
      write_A_regs(&As[cur ^ 1][0], g, r, a00, a01);
      write_A_regs(&As[cur ^ 1][0], g, r + 64, a10, a11);
    }
    __syncthreads();
    cur ^= 1;
  }
  #pragma unroll
  for (int mm = 0; mm < 2; ++mm)
    #pragma unroll
    for (int nn = 0; nn < 4; ++nn) {
      int row = row0 + wrow + mm * 16 + lg * 4;
      int col = col0 + nn * 16 + lr;
      #pragma unroll
      for (int i = 0; i < 4; ++i)
        C[(size_t)(row + i) * N + col] = acc[mm][nn][i];
    }
}

// ---------------------------------------------------------------------
// MoE up-proj, packed Wgu: 128 slots x 64 cols, dual g/u, SiLU*mul.
// grid (NEXP, 16, IMID/64). Writes ACT as bf16.
// ---------------------------------------------------------------------
__global__ __launch_bounds__(256) void moe_up_pk(
    const float* __restrict__ hln, const ushort* __restrict__ Wpk,
    const int* __restrict__ perm, const int* __restrict__ offs,
    const int* __restrict__ counts, ushort* __restrict__ actb) {
  int e = blockIdx.x;
  int cnt = counts[e];
  int base = blockIdx.y * 128;
  if (base >= cnt) return;
  int start = offs[e];
  int nt = min(128, cnt - base);
  __shared__ int tokmap[128];
  int tid = threadIdx.x;
  if (tid < 128) {
    int idx = start + base + ((tid < nt) ? tid : 0);
    tokmap[tid] = perm[idx] >> 2;
  }
  __shared__ ushort As[2][4096];
  __shared__ ushort Bg[2][2048];
  __shared__ ushort Bu[2][2048];
  __syncthreads();
  int bz = blockIdx.z, col0 = bz * 64;
  // Wgu packed as (E*HH) x (2*IMID): ntn = 12; kt = e*32 + t
  const ushort* bgt = Wpk + ((size_t)(e * 32) * 12 + bz) * 2048;
  const ushort* but = bgt + (size_t)6 * 2048;
  int g = tid & 3, r = tid >> 2;
  const float* arow0 = hln + (size_t)tokmap[r] * HH + 4 * g;
  const float* arow1 = hln + (size_t)tokmap[r + 64] * HH + 4 * g;
  int wid = tid >> 6, lane = tid & 63;
  int lg = lane >> 4, lr = lane & 15;
  int wrow = wid * 32;
  int lbase = (tid & 192) * 8;
  f32x4 accg[2][4] = {}, accu[2][4] = {};
  float4 a00 = *(const float4*)(arow0);
  float4 a01 = *(const float4*)(arow0 + 16);
  float4 a10 = *(const float4*)(arow1);
  float4 a11 = *(const float4*)(arow1 + 16);
  gload16(bgt + tid * 8, &Bg[0][lbase]);
  gload16(but + tid * 8, &Bu[0][lbase]);
  write_A_regs(&As[0][0], g, r, a00, a01);
  write_A_regs(&As[0][0], g, r + 64, a10, a11);
  __syncthreads();
  int cur = 0;
  const int NT = HH >> 5;
  for (int t = 0; t < NT; ++t) {
    bool more = (t + 1 < NT);
    if (more) {
      size_t tb = (size_t)(t + 1) * 12 * 2048;
      gload16(bgt + tb + tid * 8, &Bg[cur ^ 1][lbase]);
      gload16(but + tb + tid * 8, &Bu[cur ^ 1][lbase]);
      int k0 = (t + 1) << 5;
      a00 = *(const float4*)(arow0 + k0);
      a01 = *(const float4*)(arow0 + k0 + 16);
      a10 = *(const float4*)(arow1 + k0);
      a11 = *(const float4*)(arow1 + k0 + 16);
    }
    short8 af0 = read_a_frag128(&As[cur][0], lg, wrow + lr);
    short8 af1 = read_a_frag128(&As[cur][0], lg, wrow + 16 + lr);
    #pragma unroll
    for (int nn = 0; nn < 4; ++nn) {
      short8 bgf = read_b_frag(&Bg[cur][0], lg, nn * 16 + lr);
      short8 buf_ = read_b_frag(&Bu[cur][0], lg, nn * 16 + lr);
      accg[0][nn] = __builtin_amdgcn_mfma_f32_16x16x32_bf16(af0, bgf, accg[0][nn], 0, 0, 0);
      accg[1][nn] = __builtin_amdgcn_mfma_f32_16x16x32_bf16(af1, bgf, accg[1][nn], 0, 0, 0);
      accu[0][nn] = __builtin_amdgcn_mfma_f32_16x16x32_bf16(af0, buf_, accu[0][nn], 0, 0, 0);
      accu[1][nn] = __builtin_amdgcn_mfma_f32_16x16x32_bf16(af1, buf_, accu[1][nn], 0, 0, 0);
    }
    if (more) {
      write_A_regs(&As[cur ^ 1][0], g, r, a00, a01);
      write_A_regs(&As[cur ^ 1][0], g, r + 64, a10, a11);
    }
    __syncthreads();
    cur ^= 1;
  }
  #pragma unroll
  for (int mm = 0; mm < 2; ++mm)
    #pragma unroll
    for (int nn = 0; nn < 4; ++nn)
      #pragma unroll
      for (int i = 0; i < 4; ++i) {
        int rr = wrow + mm * 16 + lg * 4 + i;
        if (rr < nt) {
          float gv = accg[mm][nn][i], uv = accu[mm][nn][i];
          float av = gv / (1.f + expf(-gv)) * uv;
          actb[(size_t)(start + base + rr) * IMID + col0 + nn * 16 + lr] = f2bf(av);
        }
      }
}

// ---------------------------------------------------------------------
// MoE down-proj, packed Wd, bf16 A (ACT): grid (NEXP, 16, HH/64).
// Writes PARTIAL as bf16.
// ---------------------------------------------------------------------
__global__ __launch_bounds__(256) void moe_down_pk(
    const ushort* __restrict__ actb, const ushort* __restrict__ Wpk,
    const int* __restrict__ offs, const int* __restrict__ counts,
    ushort* __restrict__ partialb) {
  int e = blockIdx.x;
  int cnt = counts[e];
  int base = blockIdx.y * 128;
  if (base >= cnt) return;
  int start = offs[e];
  int nt = min(128, cnt - base);
  __shared__ ushort As[2][4096];
  __shared__ ushort Bs[2][2048];
  int tid = threadIdx.x;
  int bz = blockIdx.z, col0 = bz * 64;
  // Wd packed as (E*IMID) x HH: ntn = 16; kt = e*12 + t
  const ushort* bt0 = Wpk + ((size_t)(e * 12) * 16 + bz) * 2048;
  int g = tid & 3, r = tid >> 2;
  const ushort* arow0 = actb + (size_t)(start + base + r) * IMID + 4 * g;
  const ushort* arow1 = arow0 + (size_t)64 * IMID;
  int wid = tid >> 6, lane = tid & 63;
  int lg = lane >> 4, lr = lane & 15;
  int wrow = wid * 32;
  int lbase = (tid & 192) * 8;
  const int NT = IMID >> 5;   // 12
  f32x4 acc[2][4] = {};
  ushort4 l0 = *(const ushort4*)(arow0);
  ushort4 h0 = *(const ushort4*)(arow0 + 16);
  ushort4 l1 = *(const ushort4*)(arow1);
  ushort4 h1 = *(const ushort4*)(arow1 + 16);
  gload16(bt0 + tid * 8, &Bs[0][lbase]);
  write_A_bf16(&As[0][0], g, r, l0, h0);
  write_A_bf16(&As[0][0], g, r + 64, l1, h1);
  __syncthreads();
  int cur = 0;
  for (int t = 0; t < NT; ++t) {
    bool more = (t + 1 < NT);
    if (more) {
      gload16(bt0 + (size_t)(t + 1) * 16 * 2048 + tid * 8, &Bs[cur ^ 1][lbase]);
      int k0 = (t + 1) << 5;
      l0 = *(const ushort4*)(arow0 + k0);
      h0 = *(const ushort4*)(arow0 + k0 + 16);
      l1 = *(const ushort4*)(arow1 + k0);
      h1 = *(const ushort4*)(arow1 + k0 + 16);
    }
    short8 af0 = read_a_frag128(&As[cur][0], lg, wrow + lr);
    short8 af1 = read_a_frag128(&As[cur][0], lg, wrow + 16 + lr);
    #pragma unroll
    for (int nn = 0; nn < 4; ++nn) {
      short8 bf_ = read_b_frag(&Bs[cur][0], lg, nn * 16 + lr);
      acc[0][nn] = __builtin_amdgcn_mfma_f32_16x16x32_bf16(af0, bf_, acc[0][nn], 0, 0, 0);
      acc[1][nn] = __builtin_amdgcn_mfma_f32_16x16x32_bf16(af1, bf_, acc[1][nn], 0, 0, 0);
    }
    if (more) {
      write_A_bf16(&As[cur ^ 1][0], g, r, l0, h0);
      write_A_bf16(&As[cur ^ 1][0], g, r + 64, l1, h1);
    }
    __syncthreads();
    cur ^= 1;
  }
  #pragma unroll
  for (int mm = 0; mm < 2; ++mm)
    #pragma unroll
    for (int nn = 0; nn < 4; ++nn)
      #pragma unroll
      for (int i = 0; i < 4; ++i) {
        int rr = wrow + mm * 16 + lg * 4 + i;
        if (rr < nt)
          partialb[(size_t)(start + base + rr) * HH + col0 + nn * 16 + lr] = f2bf(acc[mm][nn][i]);
      }
}

// =====================================================================
// residual add + RMSNorm
// =====================================================================
__global__ __launch_bounds__(256) void add_rms_kernel(
    const float* __restrict__ a, const float* __restrict__ b,
    const float* __restrict__ w, float* __restrict__ sum_out,
    float* __restrict__ ln_out) {
  int t = blockIdx.x, tid = threadIdx.x;
  float4 x = reinterpret_cast<const float4*>(a + (size_t)t*HH)[tid];
  float4 y = reinterpret_cast<const float4*>(b + (size_t)t*HH)[tid];
  x.x += y.x; x.y += y.y; x.z += y.z; x.w += y.w;
  float ss = x.x*x.x + x.y*x.y + x.z*x.z + x.w*x.w;
  #pragma unroll
  for (int off = 1; off < 64; off <<= 1) ss += __shfl_xor(ss, off);
  __shared__ float wsum[4];
  int wid = tid >> 6, lane = tid & 63;
  if (lane == 0) wsum[wid] = ss;
  __syncthreads();
  float tot = wsum[0] + wsum[1] + wsum[2] + wsum[3];
  float r = rsqrtf(tot * (1.0f/HH) + EPS_);
  reinterpret_cast<float4*>(sum_out + (size_t)t*HH)[tid] = x;
  float4 wl = reinterpret_cast<const float4*>(w)[tid];
  float4 o = make_float4(x.x*r*wl.x, x.y*r*wl.y, x.z*r*wl.z, x.w*r*wl.w);
  reinterpret_cast<float4*>(ln_out + (size_t)t*HH)[tid] = o;
}

// =====================================================================
// per-(t,head) QK RMSNorm + RoPE, in-place
// =====================================================================
__global__ __launch_bounds__(256) void qk_norm_rope_kernel(
    float* __restrict__ qkv, const float* __restrict__ qw,
    const float* __restrict__ kw, const int* __restrict__ pos) {
  int t = blockIdx.x;
  int hh = blockIdx.y * 4 + (threadIdx.x >> 6);
  int lane = threadIdx.x & 63;
  float* p = qkv + (size_t)t * QKV_W + hh * HDIM;
  float x = p[lane];
  float ss = x * x;
  #pragma unroll
  for (int off = 1; off < 64; off <<= 1) ss += __shfl_xor(ss, off);
  float r = rsqrtf(ss * (1.0f/HDIM) + EPS_);
  float wv = (hh < NHEADS ? qw : kw)[lane];
  float xn = x * r * wv;
  float partner = __shfl_xor(xn, 16);
  float out = xn;
  if (lane < 32) {
    int i = lane & 15;
    float inv = powf(10000.0f, -(float)i / 16.0f);
    float ang = (float)pos[t] * inv;
    float cv = cosf(ang), sv = sinf(ang);
    out = (lane < 16) ? (xn * cv - partner * sv) : (partner * sv + xn * cv);
  }
  p[lane] = out;
}

// =====================================================================
// MFMA flash attention (verified round 5). grid (T/64, NH), 4 waves.
// =====================================================================
__global__ __launch_bounds__(256) void attn_mfma_kernel(
    const float* __restrict__ qkv, float* __restrict__ o) {
  __shared__ ushort Ks[2048];
  __shared__ ushort Vs[2048];
  int tid = threadIdx.x;
  int wid = tid >> 6, lane = tid & 63;
  int lg = lane >> 4, lr = lane & 15;
  int h = blockIdx.y, kvh = h >> 2;
  int q0 = blockIdx.x * 64 + wid * 16;
  int qg = q0 + lr;

  const float* qrow = qkv + (size_t)qg * QKV_W + h * HDIM;
  short8 qb[2];
  #pragma unroll
  for (int c = 0; c < 2; ++c) {
    float4 a = *(const float4*)(qrow + 32*c + 4*lg);
    float4 b = *(const float4*)(qrow + 32*c + 4*lg + 16);
    short8 v;
    v[0]=(short)f2bf(a.x); v[1]=(short)f2bf(a.y); v[2]=(short)f2bf(a.z); v[3]=(short)f2bf(a.w);
    v[4]=(short)f2bf(b.x); v[5]=(short)f2bf(b.y); v[6]=(short)f2bf(b.z); v[7]=(short)f2bf(b.w);
    qb[c] = v;
  }

  f32x4 o_acc[4] = {};
  float m_st = -1e30f, l_st = 0.f;
  int kv_end = blockIdx.x * 64 + 64;

  for (int kb = 0; kb * 32 < kv_end; ++kb) {
    {
      int c = tid >> 7, t2 = tid & 127;
      int g = t2 & 3, r = t2 >> 2;
      const float* kp = qkv + (size_t)(kb*32 + r) * QKV_W + NHEADS*HDIM + kvh*HDIM + 32*c + 4*g;
      float4 h0 = *(const float4*)kp;
      float4 h1 = *(const float4*)(kp + 16);
      short8 v;
      v[0]=(short)f2bf(h0.x); v[1]=(short)f2bf(h0.y); v[2]=(short)f2bf(h0.z); v[3]=(short)f2bf(h0.w);
      v[4]=(short)f2bf(h1.x); v[5]=(short)f2bf(h1.y); v[6]=(short)f2bf(h1.z); v[7]=(short)f2bf(h1.w);
      *(short8*)(Ks + c*1024 + (g*32 + (r^g))*8) = v;
    }
    stage_B_tile(qkv + (size_t)(NHEADS+NKVH)*HDIM + (size_t)kvh*HDIM, QKV_W, kb*32, 0, Vs, tid);
    __syncthreads();

    if (kb * 32 <= q0 + 15) {
      f32x4 st[2];
      #pragma unroll
      for (int n = 0; n < 2; ++n) {
        short8 kf0 = *(const short8*)(Ks + 0    + (lg*32 + ((16*n + lr) ^ lg))*8);
        short8 kf1 = *(const short8*)(Ks + 1024 + (lg*32 + ((16*n + lr) ^ lg))*8);
        f32x4 z = {};
        z = __builtin_amdgcn_mfma_f32_16x16x32_bf16(kf0, qb[0], z, 0, 0, 0);
        st[n] = __builtin_amdgcn_mfma_f32_16x16x32_bf16(kf1, qb[1], z, 0, 0, 0);
      }
      float s[2][4], tmax = -1e30f;
      #pragma unroll
      for (int n = 0; n < 2; ++n)
        #pragma unroll
        for (int i = 0; i < 4; ++i) {
          int kvg = kb*32 + 16*n + 4*lg + i;
          float sv = st[n][i] * 0.125f;
          if (kvg > qg) sv = -1e30f;
          s[n][i] = sv;
          tmax = fmaxf(tmax, sv);
        }
      tmax = fmaxf(tmax, __shfl_xor(tmax, 16));
      tmax = fmaxf(tmax, __shfl_xor(tmax, 32));
      float m_new = fmaxf(m_st, tmax);
      float corr = __expf(m_st - m_new);
      float p[2][4], psum = 0.f;
      #pragma unroll
      for (int n = 0; n < 2; ++n)
        #pragma unroll
        for (int i = 0; i < 4; ++i) {
          float pv = __expf(s[n][i] - m_new);
          p[n][i] = pv; psum += pv;
        }
      psum += __shfl_xor(psum, 16);
      psum += __shfl_xor(psum, 32);
      l_st = l_st * corr + psum;
      m_st = m_new;
      #pragma unroll
      for (int i = 0; i < 4; ++i) {
        float oc = __shfl(corr, 4*lg + i);
        #pragma unroll
        for (int nd = 0; nd < 4; ++nd) o_acc[nd][i] *= oc;
      }
      short8 pa;
      pa[0]=(short)f2bf(p[0][0]); pa[1]=(short)f2bf(p[0][1]);
      pa[2]=(short)f2bf(p[0][2]); pa[3]=(short)f2bf(p[0][3]);
      pa[4]=(short)f2bf(p[1][0]); pa[5]=(short)f2bf(p[1][1]);
      pa[6]=(short)f2bf(p[1][2]); pa[7]=(short)f2bf(p[1][3]);
      #pragma unroll
      for (int nd = 0; nd < 4; ++nd) {
        short8 vf = read_b_frag(Vs, lg, 16*nd + lr);
        o_acc[nd] = __builtin_amdgcn_mfma_f32_16x16x32_bf16(pa, vf, o_acc[nd], 0, 0, 0);
      }
    }
    __syncthreads();
  }

  #pragma unroll
  for (int i = 0; i < 4; ++i) {
    float lrow = __shfl(l_st, 4*lg + i);
    float inv = 1.0f / lrow;
    int row = q0 + 4*lg + i;
    float* op = o + (size_t)row * (NHEADS*HDIM) + h * HDIM;
    #pragma unroll
    for (int nd = 0; nd < 4; ++nd)
      op[16*nd + lr] = o_acc[nd][i] * inv;
  }
}

// =====================================================================
// router (f32, exact) + grouping
// =====================================================================
__global__ __launch_bounds__(256) void router_kernel(
    const float* __restrict__ hln, const float* __restrict__ Wg,
    const float* __restrict__ bias, int* __restrict__ sel_e,
    float* __restrict__ sel_w, int* __restrict__ counts) {
  int t = blockIdx.x, tid = threadIdx.x;
  __shared__ float hid[HH];
  reinterpret_cast<float4*>(hid)[tid] =
      reinterpret_cast<const float4*>(hln + (size_t)t*HH)[tid];
  __syncthreads();
  int e = tid & 31, ch = tid >> 5;
  float p = 0.f;
  for (int hrow = ch * 128; hrow < ch * 128 + 128; ++hrow)
    p += hid[hrow] * Wg[(size_t)hrow * NEXP + e];
  __shared__ float part[8][32];
  part[ch][e] = p;
  __syncthreads();
  __shared__ float scr_s[32], sfc_s[32];
  if (tid < 32) {
    float lg = 0.f;
    #pragma unroll
    for (int c = 0; c < 8; ++c) lg += part[c][tid];
    float sc = 1.0f / (1.0f + expf(-lg));
    scr_s[tid] = sc;
    sfc_s[tid] = sc + bias[tid];
  }
  __syncthreads();
  if (tid == 0) {
    float gs[NGRP];
    for (int g = 0; g < NGRP; ++g) {
      float m1 = -1e30f, m2 = -1e30f;
      for (int j = 0; j < 8; ++j) {
        float v = sfc_s[g*8 + j];
        if (v > m1) { m2 = m1; m1 = v; } else if (v > m2) m2 = v;
      }
      gs[g] = m1 + m2;
    }
    int g1 = 0;
    for (int g = 1; g < NGRP; ++g) if (gs[g] > gs[g1]) g1 = g;
    int g2 = -1;
    for (int g = 0; g < NGRP; ++g) {
      if (g == g1) continue;
      if (g2 < 0 || gs[g] > gs[g2]) g2 = g;
    }
    bool chosen[NEXP] = {};
    int ids[TOPK_]; float wv[TOPK_]; float wsum = 0.f;
    for (int s = 0; s < TOPK_; ++s) {
      int best = -1; float bv = -1e30f;
      for (int e2 = 0; e2 < NEXP; ++e2) {
        int g = e2 >> 3;
        if (g != g1 && g != g2) continue;
        if (chosen[e2]) continue;
        if (sfc_s[e2] > bv) { bv = sfc_s[e2]; best = e2; }
      }
      chosen[best] = true; ids[s] = best;
      wv[s] = scr_s[best]; wsum += wv[s];
    }
    for (int s = 0; s < TOPK_; ++s) {
      sel_e[t*TOPK_ + s] = ids[s];
      sel_w[t*TOPK_ + s] = wv[s] / wsum;
      atomicAdd(&counts[ids[s]], 1);
    }
  }
}

__global__ void scan_kernel(const int* __restrict__ counts,
                            int* __restrict__ offs, int* __restrict__ cursor) {
  if (threadIdx.x == 0) {
    int acc = 0;
    for (int e = 0; e < NEXP; ++e) { offs[e] = acc; cursor[e] = acc; acc += counts[e]; }
  }
}

__global__ void scatter_kernel(const int* __restrict__ sel_e,
                               int* __restrict__ cursor, int* __restrict__ perm,
                               int* __restrict__ ipos) {
  int i = blockIdx.x * 256 + threadIdx.x;
  if (i < TT * TOPK_) {
    int e = sel_e[i];
    int pos = atomicAdd(&cursor[e], 1);
    perm[pos] = i;
    ipos[i] = pos;
  }
}

// =====================================================================
// shared-expert SiLU*mul
// =====================================================================
__global__ void silu_shared_kernel(const float* __restrict__ gus,
                                   float* __restrict__ shs) {
  int i = blockIdx.x * 256 + threadIdx.x;
  if (i < TT * ISHARED) {
    int t = i / ISHARED, c = i % ISHARED;
    float g = gus[(size_t)t * (2*ISHARED) + c];
    float u = gus[(size_t)t * (2*ISHARED) + c + ISHARED];
    shs[i] = g / (1.f + expf(-g)) * u;
  }
}

// =====================================================================
// final combine (bf16 partial)
// =====================================================================
__global__ __launch_bounds__(256) void final_combine_kernel(
    const ushort* __restrict__ partialb, const float* __restrict__ sel_w,
    const int* __restrict__ ipos, const float* __restrict__ shared_out,
    float* __restrict__ out_hidden) {
  int t = blockIdx.x, tid = threadIdx.x;
  float w0 = sel_w[t*4], w1 = sel_w[t*4+1], w2 = sel_w[t*4+2], w3 = sel_w[t*4+3];
  int p0 = ipos[t*4], p1 = ipos[t*4+1], p2 = ipos[t*4+2], p3 = ipos[t*4+3];
  ushort4 a0 = *(const ushort4*)(partialb + (size_t)p0*HH + tid*4);
  ushort4 a1 = *(const ushort4*)(partialb + (size_t)p1*HH + tid*4);
  ushort4 a2 = *(const ushort4*)(partialb + (size_t)p2*HH + tid*4);
  ushort4 a3 = *(const ushort4*)(partialb + (size_t)p3*HH + tid*4);
  float4 sh = reinterpret_cast<const float4*>(shared_out + (size_t)t*HH)[tid];
  float4 r;
  r.x = (w0*bf2f(a0.x) + w1*bf2f(a1.x) + w2*bf2f(a2.x) + w3*bf2f(a3.x)) + sh.x;
  r.y = (w0*bf2f(a0.y) + w1*bf2f(a1.y) + w2*bf2f(a2.y) + w3*bf2f(a3.y)) + sh.y;
  r.z = (w0*bf2f(a0.z) + w1*bf2f(a1.z) + w2*bf2f(a2.z) + w3*bf2f(a3.z)) + sh.z;
  r.w = (w0*bf2f(a0.w) + w1*bf2f(a1.w) + w2*bf2f(a2.w) + w3*bf2f(a3.w)) + sh.w;
  reinterpret_cast<float4*>(out_hidden + (size_t)t*HH)[tid] = r;
}

// =====================================================================
extern "C" void kernel_launch(void* const* d_in, const int* in_sizes, int n_in,
                              void* d_out, int out_size, void* d_ws, size_t ws_size,
                              hipStream_t stream) {
  const float* hidden   = (const float*)d_in[0];
  const float* residual = (const float*)d_in[1];
  const float* in_ln_w  = (const float*)d_in[2];
  const float* post_ln_w= (const float*)d_in[3];
  const float* q_norm_w = (const float*)d_in[4];
  const float* k_norm_w = (const float*)d_in[5];
  const float* Wqkv     = (const float*)d_in[6];
  const float* Wo       = (const float*)d_in[7];
  const float* Wg       = (const float*)d_in[8];
  const float* gate_bias= (const float*)d_in[9];
  const float* Wgu      = (const float*)d_in[10];
  const float* Wd       = (const float*)d_in[11];
  const float* Wgu_sh   = (const float*)d_in[12];
  const float* Wd_sh    = (const float*)d_in[13];
  const int*   positions= (const int*)d_in[14];
  float* out = (float*)d_out;

  float* f = (float*)d_ws;
  size_t off = 0;
  float* R_A   = f + off; off += (size_t)TT*HH;
  float* HLN   = f + off; off += (size_t)TT*HH;
  float* QKV   = f + off; off += (size_t)TT*QKV_W;        // reused as gus
  float* OATT  = f + off; off += (size_t)TT*HH;           // reused as shared_out
  float* HLN2  = f + off; off += (size_t)TT*HH;
  float* SHS   = f + off; off += (size_t)TT*ISHARED;
  float* SELW  = f + off; off += (size_t)TT*TOPK_;
  // bf16 regions (counts are even -> float offsets stay aligned)
  ushort* ACTB  = (ushort*)(f + off); off += (size_t)(TT*TOPK_ + 128)*IMID/2;
  ushort* PARTB = (ushort*)(f + off); off += (size_t)TT*TOPK_*HH/2;
  ushort* PK_QKV = (ushort*)(f + off); off += (size_t)HH*QKV_W/2;
  ushort* PK_WO  = (ushort*)(f + off); off += (size_t)HH*HH/2;
  ushort* PK_WGU = (ushort*)(f + off); off += (size_t)NEXP*HH*(2*IMID)/2;
  ushort* PK_WD  = (ushort*)(f + off); off += (size_t)NEXP*IMID*HH/2;
  ushort* PK_GUSH= (ushort*)(f + off); off += (size_t)HH*(2*ISHARED)/2;
  ushort* PK_DSH = (ushort*)(f + off); off += (size_t)ISHARED*HH/2;
  int* ibase   = (int*)(f + off);
  int* SELE    = ibase;
  int* PERM    = ibase + TT*TOPK_;
  int* IPOS    = ibase + 2*TT*TOPK_;
  int* COUNTS  = ibase + 3*TT*TOPK_;
  int* OFFS    = COUNTS + NEXP;
  int* CURSOR  = OFFS + NEXP;

  // 0. pack all weights to bf16 tile images (independent of pipeline)
  pack_B_kernel<<<dim3(QKV_W/64, HH/32), 256, 0, stream>>>(Wqkv, PK_QKV, QKV_W);
  pack_B_kernel<<<dim3(HH/64, HH/32), 256, 0, stream>>>(Wo, PK_WO, HH);
  pack_B_kernel<<<dim3((2*IMID)/64, NEXP*HH/32), 256, 0, stream>>>(Wgu, PK_WGU, 2*IMID);
  pack_B_kernel<<<dim3(HH/64, NEXP*IMID/32), 256, 0, stream>>>(Wd, PK_WD, HH);
  pack_B_kernel<<<dim3((2*ISHARED)/64, HH/32), 256, 0, stream>>>(Wgu_sh, PK_GUSH, 2*ISHARED);
  pack_B_kernel<<<dim3(HH/64, ISHARED/32), 256, 0, stream>>>(Wd_sh, PK_DSH, HH);

  // 1. pipeline
  add_rms_kernel<<<TT, 256, 0, stream>>>(hidden, residual, in_ln_w, R_A, HLN);
  gemm128_pk<<<dim3(QKV_W/64, TT/128), 256, 0, stream>>>(HLN, PK_QKV, QKV, TT, QKV_W, HH);
  qk_norm_rope_kernel<<<dim3(TT, 5), 256, 0, stream>>>(QKV, q_norm_w, k_norm_w, positions);
  attn_mfma_kernel<<<dim3(TT/64, NHEADS), 256, 0, stream>>>(QKV, OATT);
  gemm128_pk<<<dim3(HH/64, TT/128), 256, 0, stream>>>(OATT, PK_WO, HLN, TT, HH, HH);
  add_rms_kernel<<<TT, 256, 0, stream>>>(HLN, R_A, post_ln_w, out + (size_t)TT*HH, HLN2);
  hipMemsetAsync(COUNTS, 0, NEXP * sizeof(int), stream);
  router_kernel<<<TT, 256, 0, stream>>>(HLN2, Wg, gate_bias, SELE, SELW, COUNTS);
  scan_kernel<<<1, 64, 0, stream>>>(COUNTS, OFFS, CURSOR);
  scatter_kernel<<<(TT*TOPK_ + 255)/256, 256, 0, stream>>>(SELE, CURSOR, PERM, IPOS);
  moe_up_pk<<<dim3(NEXP, 16, IMID/64), 256, 0, stream>>>(HLN2, PK_WGU, PERM, OFFS, COUNTS, ACTB);
  moe_down_pk<<<dim3(NEXP, 16, HH/64), 256, 0, stream>>>(ACTB, PK_WD, OFFS, COUNTS, PARTB);
  gemm128_pk<<<dim3((2*ISHARED)/64, TT/128), 256, 0, stream>>>(HLN2, PK_GUSH, QKV, TT, 2*ISHARED, HH);
  silu_shared_kernel<<<(TT*ISHARED + 255)/256, 256, 0, stream>>>(QKV, SHS);
  gemm128_pk<<<dim3(HH/64, TT/128), 256, 0, stream>>>(SHS, PK_DSH, OATT, TT, HH, ISHARED);
  final_combine_kernel<<<TT, 256, 0, stream>>>(PARTB, SELW, IPOS, OATT, out);
}

// Round 8
// 434.054 us; speedup vs baseline: 1.1123x; 1.1123x over previous
//
#include <hip/hip_runtime.h>
#include <math.h>

// ---- problem constants ----
#define TT 2048
#define HH 1024
#define NHEADS 16
#define NKVH 4
#define HDIM 64
#define NEXP 32
#define TOPK_ 4
#define NGRP 4
#define IMID 384
#define ISHARED 384
#define QKV_W (24*64)   // 1536
#define EPS_ 1e-5f

typedef __attribute__((ext_vector_type(8))) short short8;
typedef __attribute__((ext_vector_type(4))) float f32x4;

__device__ __forceinline__ ushort f2bf(float x) {
  union { float f; unsigned u; } v; v.f = x;
  unsigned r = v.u + 0x7fffu + ((v.u >> 16) & 1u);
  return (ushort)(r >> 16);
}
__device__ __forceinline__ float bf2f(ushort u) {
  union { unsigned i; float f; } v; v.i = (unsigned)u << 16; return v.f;
}

// async global->LDS, 16B per lane; lds dst = wave-uniform base + lane*16
__device__ __forceinline__ void gload16(const void* g, void* l) {
  __builtin_amdgcn_global_load_lds(
      (const __attribute__((address_space(1))) unsigned int*)g,
      (__attribute__((address_space(3))) unsigned int*)l, 16, 0, 0);
}

// =====================================================================
// MFMA fragment layouts (16x16x32 bf16), verified rounds 1-7:
//   A-frag lane l: A[row=l&15][k in {4g+j, 16+4g+j}], g=l>>4
//   B-frag lane l: B[k in {4g+j, 16+4g+j}][col=l&15]
//   C lane l: C[row=(l>>4)*4+i][col=l&15]
// A LDS plane: [g][128 rows][8] with row^g swizzle (8 KB / buffer).
// B LDS plane: 4 planes x 1024B, 16B-granular column XOR swizzle (4 KB).
// Permuted activation row layout (bf16): within each 32-col block,
// position g*8 + hi*4 + j holds original col 4g + 16*hi + j. A lane's
// A-frag (g fixed) is then 16 CONTIGUOUS bytes -> global_load_lds-able.
// =====================================================================
__device__ __forceinline__ void write_A_regs(ushort* As, int g, int row,
                                             float4 h0, float4 h1) {
  short8 v;
  v[0]=(short)f2bf(h0.x); v[1]=(short)f2bf(h0.y); v[2]=(short)f2bf(h0.z); v[3]=(short)f2bf(h0.w);
  v[4]=(short)f2bf(h1.x); v[5]=(short)f2bf(h1.y); v[6]=(short)f2bf(h1.z); v[7]=(short)f2bf(h1.w);
  *(short8*)(As + ((g * 128 + (row ^ g)) * 8)) = v;
}
__device__ __forceinline__ short8 read_a_frag128(const ushort* As, int lg, int row) {
  return *(const short8*)(As + ((lg * 128 + (row ^ lg)) * 8));
}
__device__ __forceinline__ short8 read_b_frag(const ushort* Bs, int lg, int col) {
  int boff = (col * 16) ^ (((col >> 3) & 7) << 4);
  return *(const short8*)((const char*)Bs + lg * 1024 + boff);
}

// B-tile staging from f32 (used by pack kernel and attention V)
__device__ __forceinline__ void stage_B_tile(const float* __restrict__ B, int ldb,
                                             int k0, int col0, ushort* Bs, int tid) {
  int a = tid >> 4;
  int cG = tid & 15;
  int k = 2 * a;
  const float* p0 = B + (size_t)(k0 + k) * ldb + col0 + cG * 4;
  const float* p1 = p0 + ldb;
  float4 r0 = *(const float4*)p0;
  float4 r1 = *(const float4*)p1;
  int gg = (k & 15) >> 2;
  int slot = (k & 3) + ((k >> 4) << 2);
  float v0[4] = {r0.x, r0.y, r0.z, r0.w};
  float v1[4] = {r1.x, r1.y, r1.z, r1.w};
  char* plane = (char*)Bs + gg * 1024;
  #pragma unroll
  for (int j = 0; j < 4; ++j) {
    int c = cG * 4 + j;
    unsigned pk = (unsigned)f2bf(v0[j]) | ((unsigned)f2bf(v1[j]) << 16);
    int boff = ((c * 16) ^ (((c >> 3) & 7) << 4)) + slot * 2;
    *(unsigned*)(plane + boff) = pk;
  }
}

// ---------------------------------------------------------------------
// Pack kernel: f32 KxN matrix -> bf16 pre-swizzled B-tile images.
// ---------------------------------------------------------------------
__global__ __launch_bounds__(256) void pack_B_kernel(
    const float* __restrict__ src, ushort* __restrict__ dst, int N) {
  __shared__ ushort tileB[2048];
  int tid = threadIdx.x;
  stage_B_tile(src, N, blockIdx.y * 32, blockIdx.x * 64, tileB, tid);
  __syncthreads();
  size_t toff = ((size_t)blockIdx.y * gridDim.x + blockIdx.x) * 2048;
  *(short8*)(dst + toff + tid * 8) = *(const short8*)(tileB + tid * 8);
}

// ---------------------------------------------------------------------
// Dense GEMM, packed B (r7 structure, unchanged): BM=128, BN=64.
// ---------------------------------------------------------------------
__global__ __launch_bounds__(256) void gemm128_pk(
    const float* __restrict__ A, const ushort* __restrict__ Bpk,
    float* __restrict__ C, int M, int N, int K) {
  __shared__ ushort As[2][4096];
  __shared__ ushort Bs[2][2048];
  int tid = threadIdx.x;
  int row0 = blockIdx.y * 128, col0 = blockIdx.x * 64;
  int g = tid & 3, r = tid >> 2;
  const float* arow0 = A + (size_t)(row0 + r) * K + 4 * g;
  const float* arow1 = arow0 + (size_t)64 * K;
  int ntn = N >> 6;
  const ushort* bt0 = Bpk + (size_t)blockIdx.x * 2048;
  int wid = tid >> 6, lane = tid & 63;
  int lg = lane >> 4, lr = lane & 15;
  int wrow = wid * 32;
  int lbase = (tid & 192) * 8;
  int NT = K >> 5;
  f32x4 acc[2][4] = {};
  float4 a00 = *(const float4*)(arow0);
  float4 a01 = *(const float4*)(arow0 + 16);
  float4 a10 = *(const float4*)(arow1);
  float4 a11 = *(const float4*)(arow1 + 16);
  gload16(bt0 + tid * 8, &Bs[0][lbase]);
  write_A_regs(&As[0][0], g, r, a00, a01);
  write_A_regs(&As[0][0], g, r + 64, a10, a11);
  __syncthreads();
  int cur = 0;
  for (int t = 0; t < NT; ++t) {
    bool more = (t + 1 < NT);
    if (more) {
      gload16(bt0 + (size_t)(t + 1) * ntn * 2048 + tid * 8, &Bs[cur ^ 1][lbase]);
      int k0 = (t + 1) << 5;
      a00 = *(const float4*)(arow0 + k0);
      a01 = *(const float4*)(arow0 + k0 + 16);
      a10 = *(const float4*)(arow1 + k0);
      a11 = *(const float4*)(arow1 + k0 + 16);
    }
    short8 af0 = read_a_frag128(&As[cur][0], lg, wrow + lr);
    short8 af1 = read_a_frag128(&As[cur][0], lg, wrow + 16 + lr);
    #pragma unroll
    for (int nn = 0; nn < 4; ++nn) {
      short8 bf_ = read_b_frag(&Bs[cur][0], lg, nn * 16 + lr);
      acc[0][nn] = __builtin_amdgcn_mfma_f32_16x16x32_bf16(af0, bf_, acc[0][nn], 0, 0, 0);
      acc[1][nn] = __builtin_amdgcn_mfma_f32_16x16x32_bf16(af1, bf_, acc[1][nn], 0, 0, 0);
    }
    if (more) {
      write_A_regs(&As[cur ^ 1][0], g, r, a00, a01);
      write_A_regs(&As[cur ^ 1][0], g, r + 64, a10, a11);
    }
    __syncthreads();
    cur ^= 1;
  }
  #pragma unroll
  for (int mm = 0; mm < 2; ++mm)
    #pragma unroll
    for (int nn = 0; nn < 4; ++nn) {
      int row = row0 + wrow + mm * 16 + lg * 4;
      int col = col0 + nn * 16 + lr;
      #pragma unroll
      for (int i = 0; i < 4; ++i)
        C[(size_t)(row + i) * N + col] = acc[mm][nn][i];
    }
}

// ---------------------------------------------------------------------
// MoE up-proj: all staging via global_load_lds, ring-3 counted-vmcnt
// pipeline (prefetch distance 2, steady-state vmcnt(4), never 0).
// A from permuted-bf16 HLN2B (gathered rows). Writes ACT permuted bf16.
// grid (NEXP, 16, IMID/64)
// ---------------------------------------------------------------------
__global__ __launch_bounds__(256) void moe_up_pk(
    const ushort* __restrict__ hln2b, const ushort* __restrict__ Wpk,
    const int* __restrict__ perm, const int* __restrict__ offs,
    const int* __restrict__ counts, ushort* __restrict__ actb) {
  int e = blockIdx.x;
  int cnt = counts[e];
  int base = blockIdx.y * 128;
  if (base >= cnt) return;
  int start = offs[e];
  int nt = min(128, cnt - base);
  __shared__ int tokmap[128];
  int tid = threadIdx.x;
  if (tid < 128) {
    int idx = start + base + ((tid < nt) ? tid : 0);
    tokmap[tid] = perm[idx] >> 2;
  }
  __shared__ ushort As[3][4096];
  __shared__ ushort Bg[3][2048];
  __shared__ ushort Bu[3][2048];
  __syncthreads();
  int bz = blockIdx.z, col0 = bz * 64;
  const ushort* bgt = Wpk + ((size_t)(e * 32) * 12 + bz) * 2048;
  const ushort* but = bgt + (size_t)6 * 2048;
  int wid = tid >> 6, lane = tid & 63;
  int lg = lane >> 4, lr = lane & 15;
  int wrow = wid * 32;
  // per-lane A sources (pre-swizzled row, permuted col chunk g=wid)
  int rowq0 = lane ^ wid;
  int rowq1 = (64 + lane) ^ wid;
  const ushort* asrc0 = hln2b + (size_t)tokmap[rowq0] * HH + wid * 8;
  const ushort* asrc1 = hln2b + (size_t)tokmap[rowq1] * HH + wid * 8;
  const int NT = HH >> 5;   // 32
  f32x4 accg[2][4] = {}, accu[2][4] = {};

  auto issue = [&](int tt) {
    int b = tt % 3;
    gload16(asrc0 + tt * 32, &As[b][wid * 1024]);
    gload16(asrc1 + tt * 32, &As[b][wid * 1024 + 512]);
    gload16(bgt + (size_t)tt * 12 * 2048 + tid * 8, &Bg[b][wid * 512]);
    gload16(but + (size_t)tt * 12 * 2048 + tid * 8, &Bu[b][wid * 512]);
  };
  issue(0);
  issue(1);
  for (int t = 0; t < NT; ++t) {
    if (t < NT - 1) asm volatile("s_waitcnt vmcnt(4)" ::: "memory");
    else            asm volatile("s_waitcnt vmcnt(0)" ::: "memory");
    __builtin_amdgcn_s_barrier();
    if (t + 2 < NT) issue(t + 2);
    int cb = t % 3;
    short8 af0 = read_a_frag128(&As[cb][0], lg, wrow + lr);
    short8 af1 = read_a_frag128(&As[cb][0], lg, wrow + 16 + lr);
    #pragma unroll
    for (int nn = 0; nn < 4; ++nn) {
      short8 bgf = read_b_frag(&Bg[cb][0], lg, nn * 16 + lr);
      short8 buf_ = read_b_frag(&Bu[cb][0], lg, nn * 16 + lr);
      accg[0][nn] = __builtin_amdgcn_mfma_f32_16x16x32_bf16(af0, bgf, accg[0][nn], 0, 0, 0);
      accg[1][nn] = __builtin_amdgcn_mfma_f32_16x16x32_bf16(af1, bgf, accg[1][nn], 0, 0, 0);
      accu[0][nn] = __builtin_amdgcn_mfma_f32_16x16x32_bf16(af0, buf_, accu[0][nn], 0, 0, 0);
      accu[1][nn] = __builtin_amdgcn_mfma_f32_16x16x32_bf16(af1, buf_, accu[1][nn], 0, 0, 0);
    }
  }
  // epilogue: SiLU*mul, write ACT in permuted bf16 layout
  #pragma unroll
  for (int mm = 0; mm < 2; ++mm)
    #pragma unroll
    for (int nn = 0; nn < 4; ++nn) {
      // permuted dst element for col = col0 + nn*16 + lr
      int pcol = col0 + ((nn >> 1) << 5) + ((lr >> 2) << 3) + ((nn & 1) << 2) + (lr & 3);
      #pragma unroll
      for (int i = 0; i < 4; ++i) {
        int rr = wrow + mm * 16 + lg * 4 + i;
        if (rr < nt) {
          float gv = accg[mm][nn][i], uv = accu[mm][nn][i];
          float av = gv / (1.f + expf(-gv)) * uv;
          actb[(size_t)(start + base + rr) * IMID + pcol] = f2bf(av);
        }
      }
    }
}

// ---------------------------------------------------------------------
// MoE down-proj: ring-3 counted-vmcnt, A via gload from permuted ACT.
// grid (NEXP, 16, HH/64). Writes PARTIAL bf16 (normal layout).
// ---------------------------------------------------------------------
__global__ __launch_bounds__(256) void moe_down_pk(
    const ushort* __restrict__ actb, const ushort* __restrict__ Wpk,
    const int* __restrict__ offs, const int* __restrict__ counts,
    ushort* __restrict__ partialb) {
  int e = blockIdx.x;
  int cnt = counts[e];
  int base = blockIdx.y * 128;
  if (base >= cnt) return;
  int start = offs[e];
  int nt = min(128, cnt - base);
  __shared__ ushort As[3][4096];
  __shared__ ushort Bs[3][2048];
  int tid = threadIdx.x;
  int bz = blockIdx.z, col0 = bz * 64;
  const ushort* bt0 = Wpk + ((size_t)(e * 12) * 16 + bz) * 2048;
  int wid = tid >> 6, lane = tid & 63;
  int lg = lane >> 4, lr = lane & 15;
  int wrow = wid * 32;
  const ushort* asrc0 = actb + (size_t)(start + base + (lane ^ wid)) * IMID + wid * 8;
  const ushort* asrc1 = actb + (size_t)(start + base + ((64 + lane) ^ wid)) * IMID + wid * 8;
  const int NT = IMID >> 5;   // 12
  f32x4 acc[2][4] = {};

  auto issue = [&](int tt) {
    int b = tt % 3;
    gload16(asrc0 + tt * 32, &As[b][wid * 1024]);
    gload16(asrc1 + tt * 32, &As[b][wid * 1024 + 512]);
    gload16(bt0 + (size_t)tt * 16 * 2048 + tid * 8, &Bs[b][wid * 512]);
  };
  issue(0);
  issue(1);
  for (int t = 0; t < NT; ++t) {
    if (t < NT - 1) asm volatile("s_waitcnt vmcnt(3)" ::: "memory");
    else            asm volatile("s_waitcnt vmcnt(0)" ::: "memory");
    __builtin_amdgcn_s_barrier();
    if (t + 2 < NT) issue(t + 2);
    int cb = t % 3;
    short8 af0 = read_a_frag128(&As[cb][0], lg, wrow + lr);
    short8 af1 = read_a_frag128(&As[cb][0], lg, wrow + 16 + lr);
    #pragma unroll
    for (int nn = 0; nn < 4; ++nn) {
      short8 bf_ = read_b_frag(&Bs[cb][0], lg, nn * 16 + lr);
      acc[0][nn] = __builtin_amdgcn_mfma_f32_16x16x32_bf16(af0, bf_, acc[0][nn], 0, 0, 0);
      acc[1][nn] = __builtin_amdgcn_mfma_f32_16x16x32_bf16(af1, bf_, acc[1][nn], 0, 0, 0);
    }
  }
  #pragma unroll
  for (int mm = 0; mm < 2; ++mm)
    #pragma unroll
    for (int nn = 0; nn < 4; ++nn)
      #pragma unroll
      for (int i = 0; i < 4; ++i) {
        int rr = wrow + mm * 16 + lg * 4 + i;
        if (rr < nt)
          partialb[(size_t)(start + base + rr) * HH + col0 + nn * 16 + lr] = f2bf(acc[mm][nn][i]);
      }
}

// =====================================================================
// residual add + RMSNorm. sum_out f32, ln_out f32, optional permuted
// bf16 copy of ln (for global_load_lds consumers).
// =====================================================================
__global__ __launch_bounds__(256) void add_rms_kernel(
    const float* __restrict__ a, const float* __restrict__ b,
    const float* __restrict__ w, float* __restrict__ sum_out,
    float* __restrict__ ln_out, ushort* __restrict__ lnb) {
  int t = blockIdx.x, tid = threadIdx.x;
  float4 x = reinterpret_cast<const float4*>(a + (size_t)t*HH)[tid];
  float4 y = reinterpret_cast<const float4*>(b + (size_t)t*HH)[tid];
  x.x += y.x; x.y += y.y; x.z += y.z; x.w += y.w;
  float ss = x.x*x.x + x.y*x.y + x.z*x.z + x.w*x.w;
  #pragma unroll
  for (int off = 1; off < 64; off <<= 1) ss += __shfl_xor(ss, off);
  __shared__ float wsum[4];
  int wid = tid >> 6, lane = tid & 63;
  if (lane == 0) wsum[wid] = ss;
  __syncthreads();
  float tot = wsum[0] + wsum[1] + wsum[2] + wsum[3];
  float r = rsqrtf(tot * (1.0f/HH) + EPS_);
  reinterpret_cast<float4*>(sum_out + (size_t)t*HH)[tid] = x;
  float4 wl = reinterpret_cast<const float4*>(w)[tid];
  float4 o = make_float4(x.x*r*wl.x, x.y*r*wl.y, x.z*r*wl.z, x.w*r*wl.w);
  reinterpret_cast<float4*>(ln_out + (size_t)t*HH)[tid] = o;
  if (lnb) {
    ushort4 ub;
    ub.x = f2bf(o.x); ub.y = f2bf(o.y); ub.z = f2bf(o.z); ub.w = f2bf(o.w);
    // permuted position: cols 4*tid..4*tid+3 -> block (tid>>3), g=tid&3, hi=(tid>>2)&1
    int dst = ((tid >> 3) << 5) + ((tid & 3) << 3) + (((tid >> 2) & 1) << 2);
    *(ushort4*)(lnb + (size_t)t * HH + dst) = ub;
  }
}

// =====================================================================
// per-(t,head) QK RMSNorm + RoPE, in-place
// =====================================================================
__global__ __launch_bounds__(256) void qk_norm_rope_kernel(
    float* __restrict__ qkv, const float* __restrict__ qw,
    const float* __restrict__ kw, const int* __restrict__ pos) {
  int t = blockIdx.x;
  int hh = blockIdx.y * 4 + (threadIdx.x >> 6);
  int lane = threadIdx.x & 63;
  float* p = qkv + (size_t)t * QKV_W + hh * HDIM;
  float x = p[lane];
  float ss = x * x;
  #pragma unroll
  for (int off = 1; off < 64; off <<= 1) ss += __shfl_xor(ss, off);
  float r = rsqrtf(ss * (1.0f/HDIM) + EPS_);
  float wv = (hh < NHEADS ? qw : kw)[lane];
  float xn = x * r * wv;
  float partner = __shfl_xor(xn, 16);
  float out = xn;
  if (lane < 32) {
    int i = lane & 15;
    float inv = powf(10000.0f, -(float)i / 16.0f);
    float ang = (float)pos[t] * inv;
    float cv = cosf(ang), sv = sinf(ang);
    out = (lane < 16) ? (xn * cv - partner * sv) : (partner * sv + xn * cv);
  }
  p[lane] = out;
}

// =====================================================================
// MFMA flash attention (verified round 5). grid (T/64, NH), 4 waves.
// =====================================================================
__global__ __launch_bounds__(256) void attn_mfma_kernel(
    const float* __restrict__ qkv, float* __restrict__ o) {
  __shared__ ushort Ks[2048];
  __shared__ ushort Vs[2048];
  int tid = threadIdx.x;
  int wid = tid >> 6, lane = tid & 63;
  int lg = lane >> 4, lr = lane & 15;
  int h = blockIdx.y, kvh = h >> 2;
  int q0 = blockIdx.x * 64 + wid * 16;
  int qg = q0 + lr;

  const float* qrow = qkv + (size_t)qg * QKV_W + h * HDIM;
  short8 qb[2];
  #pragma unroll
  for (int c = 0; c < 2; ++c) {
    float4 a = *(const float4*)(qrow + 32*c + 4*lg);
    float4 b = *(const float4*)(qrow + 32*c + 4*lg + 16);
    short8 v;
    v[0]=(short)f2bf(a.x); v[1]=(short)f2bf(a.y); v[2]=(short)f2bf(a.z); v[3]=(short)f2bf(a.w);
    v[4]=(short)f2bf(b.x); v[5]=(short)f2bf(b.y); v[6]=(short)f2bf(b.z); v[7]=(short)f2bf(b.w);
    qb[c] = v;
  }

  f32x4 o_acc[4] = {};
  float m_st = -1e30f, l_st = 0.f;
  int kv_end = blockIdx.x * 64 + 64;

  for (int kb = 0; kb * 32 < kv_end; ++kb) {
    {
      int c = tid >> 7, t2 = tid & 127;
      int g = t2 & 3, r = t2 >> 2;
      const float* kp = qkv + (size_t)(kb*32 + r) * QKV_W + NHEADS*HDIM + kvh*HDIM + 32*c + 4*g;
      float4 h0 = *(const float4*)kp;
      float4 h1 = *(const float4*)(kp + 16);
      short8 v;
      v[0]=(short)f2bf(h0.x); v[1]=(short)f2bf(h0.y); v[2]=(short)f2bf(h0.z); v[3]=(short)f2bf(h0.w);
      v[4]=(short)f2bf(h1.x); v[5]=(short)f2bf(h1.y); v[6]=(short)f2bf(h1.z); v[7]=(short)f2bf(h1.w);
      *(short8*)(Ks + c*1024 + (g*32 + (r^g))*8) = v;
    }
    stage_B_tile(qkv + (size_t)(NHEADS+NKVH)*HDIM + (size_t)kvh*HDIM, QKV_W, kb*32, 0, Vs, tid);
    __syncthreads();

    if (kb * 32 <= q0 + 15) {
      f32x4 st[2];
      #pragma unroll
      for (int n = 0; n < 2; ++n) {
        short8 kf0 = *(const short8*)(Ks + 0    + (lg*32 + ((16*n + lr) ^ lg))*8);
        short8 kf1 = *(const short8*)(Ks + 1024 + (lg*32 + ((16*n + lr) ^ lg))*8);
        f32x4 z = {};
        z = __builtin_amdgcn_mfma_f32_16x16x32_bf16(kf0, qb[0], z, 0, 0, 0);
        st[n] = __builtin_amdgcn_mfma_f32_16x16x32_bf16(kf1, qb[1], z, 0, 0, 0);
      }
      float s[2][4], tmax = -1e30f;
      #pragma unroll
      for (int n = 0; n < 2; ++n)
        #pragma unroll
        for (int i = 0; i < 4; ++i) {
          int kvg = kb*32 + 16*n + 4*lg + i;
          float sv = st[n][i] * 0.125f;
          if (kvg > qg) sv = -1e30f;
          s[n][i] = sv;
          tmax = fmaxf(tmax, sv);
        }
      tmax = fmaxf(tmax, __shfl_xor(tmax, 16));
      tmax = fmaxf(tmax, __shfl_xor(tmax, 32));
      float m_new = fmaxf(m_st, tmax);
      float corr = __expf(m_st - m_new);
      float p[2][4], psum = 0.f;
      #pragma unroll
      for (int n = 0; n < 2; ++n)
        #pragma unroll
        for (int i = 0; i < 4; ++i) {
          float pv = __expf(s[n][i] - m_new);
          p[n][i] = pv; psum += pv;
        }
      psum += __shfl_xor(psum, 16);
      psum += __shfl_xor(psum, 32);
      l_st = l_st * corr + psum;
      m_st = m_new;
      #pragma unroll
      for (int i = 0; i < 4; ++i) {
        float oc = __shfl(corr, 4*lg + i);
        #pragma unroll
        for (int nd = 0; nd < 4; ++nd) o_acc[nd][i] *= oc;
      }
      short8 pa;
      pa[0]=(short)f2bf(p[0][0]); pa[1]=(short)f2bf(p[0][1]);
      pa[2]=(short)f2bf(p[0][2]); pa[3]=(short)f2bf(p[0][3]);
      pa[4]=(short)f2bf(p[1][0]); pa[5]=(short)f2bf(p[1][1]);
      pa[6]=(short)f2bf(p[1][2]); pa[7]=(short)f2bf(p[1][3]);
      #pragma unroll
      for (int nd = 0; nd < 4; ++nd) {
        short8 vf = read_b_frag(Vs, lg, 16*nd + lr);
        o_acc[nd] = __builtin_amdgcn_mfma_f32_16x16x32_bf16(pa, vf, o_acc[nd], 0, 0, 0);
      }
    }
    __syncthreads();
  }

  #pragma unroll
  for (int i = 0; i < 4; ++i) {
    float lrow = __shfl(l_st, 4*lg + i);
    float inv = 1.0f / lrow;
    int row = q0 + 4*lg + i;
    float* op = o + (size_t)row * (NHEADS*HDIM) + h * HDIM;
    #pragma unroll
    for (int nd = 0; nd < 4; ++nd)
      op[16*nd + lr] = o_acc[nd][i] * inv;
  }
}

// =====================================================================
// router: wave-parallel (1 wave = 1 token), no atomics, no serial tail.
// grid TT/4 blocks x 256 threads.
// =====================================================================
__global__ __launch_bounds__(256) void router_kernel(
    const float* __restrict__ hln, const float* __restrict__ Wg,
    const float* __restrict__ bias, int* __restrict__ sel_e,
    float* __restrict__ sel_w) {
  __shared__ float hid[4][HH];
  int tid = threadIdx.x, wid = tid >> 6, lane = tid & 63;
  int t = blockIdx.x * 4 + wid;
  const float4* src = (const float4*)(hln + (size_t)t * HH);
  float4* dst = (float4*)hid[wid];
  #pragma unroll
  for (int j = 0; j < 4; ++j) dst[j * 64 + lane] = src[j * 64 + lane];
  int e = lane & 31, half = lane >> 5;
  const float* wp = Wg + (size_t)(half * 512) * NEXP + e;
  const float* hp = hid[wid] + half * 512;
  float p = 0.f;
  #pragma unroll 8
  for (int h = 0; h < 512; ++h) p += hp[h] * wp[(size_t)h * NEXP];
  p += __shfl_xor(p, 32);
  float sc = 1.0f / (1.0f + expf(-p));
  float sfc = sc + bias[e];
  // group top-2 via shuffle merge (experts 8g..8g+7 = lanes 8g..8g+7)
  float m1 = sfc, m2 = -1e30f;
  #pragma unroll
  for (int off = 1; off <= 4; off <<= 1) {
    float om1 = __shfl_xor(m1, off), om2 = __shfl_xor(m2, off);
    float hi_ = fmaxf(m1, om1);
    float lo_ = fmaxf(fminf(m1, om1), fmaxf(m2, om2));
    m1 = hi_; m2 = lo_;
  }
  float gs = m1 + m2;
  float gv0 = __shfl(gs, 0), gv1 = __shfl(gs, 8), gv2 = __shfl(gs, 16), gv3 = __shfl(gs, 24);
  float gv[4] = {gv0, gv1, gv2, gv3};
  int g1 = 0; float b1 = gv[0];
  #pragma unroll
  for (int g = 1; g < 4; ++g) if (gv[g] > b1) { b1 = gv[g]; g1 = g; }
  int g2 = -1; float b2 = -1e30f;
  #pragma unroll
  for (int g = 0; g < 4; ++g) if (g != g1 && gv[g] > b2) { b2 = gv[g]; g2 = g; }
  bool keep = ((e >> 3) == g1) || ((e >> 3) == g2);
  float cand = keep ? sfc : -1e30f;
  int ids[4]; float wv[4]; float wsum = 0.f;
  #pragma unroll
  for (int s = 0; s < 4; ++s) {
    float v = cand; int ix = e;
    #pragma unroll
    for (int off = 1; off < 64; off <<= 1) {
      float ov = __shfl_xor(v, off); int oix = __shfl_xor(ix, off);
      if (ov > v || (ov == v && oix < ix)) { v = ov; ix = oix; }
    }
    ids[s] = ix;
    if (e == ix) cand = -1e30f;
    float w = __shfl(sc, ix);
    wv[s] = w; wsum += w;
  }
  if (lane == 0) {
    #pragma unroll
    for (int s = 0; s < 4; ++s) {
      sel_e[t * 4 + s] = ids[s];
      sel_w[t * 4 + s] = wv[s] / wsum;
    }
  }
}

// count (no atomics): block e counts its selections
__global__ __launch_bounds__(256) void count_kernel(
    const int* __restrict__ sel_e, int* __restrict__ counts) {
  int e = blockIdx.x, tid = threadIdx.x;
  int c = 0;
  for (int i = tid; i < TT * TOPK_; i += 256) c += (sel_e[i] == e);
  #pragma unroll
  for (int off = 1; off < 64; off <<= 1) c += __shfl_xor(c, off);
  __shared__ int wsum[4];
  if ((tid & 63) == 0) wsum[tid >> 6] = c;
  __syncthreads();
  if (tid == 0) counts[e] = wsum[0] + wsum[1] + wsum[2] + wsum[3];
}

__global__ void scan_kernel(const int* __restrict__ counts,
                            int* __restrict__ offs, int* __restrict__ cursor) {
  if (threadIdx.x == 0) {
    int acc = 0;
    for (int e = 0; e < NEXP; ++e) { offs[e] = acc; cursor[e] = acc; acc += counts[e]; }
  }
}

__global__ void scatter_kernel(const int* __restrict__ sel_e,
                               int* __restrict__ cursor, int* __restrict__ perm,
                               int* __restrict__ ipos) {
  int i = blockIdx.x * 256 + threadIdx.x;
  if (i < TT * TOPK_) {
    int e = sel_e[i];
    int pos = atomicAdd(&cursor[e], 1);
    perm[pos] = i;
    ipos[i] = pos;
  }
}

// =====================================================================
// shared-expert SiLU*mul
// =====================================================================
__global__ void silu_shared_kernel(const float* __restrict__ gus,
                                   float* __restrict__ shs) {
  int i = blockIdx.x * 256 + threadIdx.x;
  if (i < TT * ISHARED) {
    int t = i / ISHARED, c = i % ISHARED;
    float g = gus[(size_t)t * (2*ISHARED) + c];
    float u = gus[(size_t)t * (2*ISHARED) + c + ISHARED];
    shs[i] = g / (1.f + expf(-g)) * u;
  }
}

// =====================================================================
// final combine (bf16 partial)
// =====================================================================
__global__ __launch_bounds__(256) void final_combine_kernel(
    const ushort* __restrict__ partialb, const float* __restrict__ sel_w,
    const int* __restrict__ ipos, const float* __restrict__ shared_out,
    float* __restrict__ out_hidden) {
  int t = blockIdx.x, tid = threadIdx.x;
  float w0 = sel_w[t*4], w1 = sel_w[t*4+1], w2 = sel_w[t*4+2], w3 = sel_w[t*4+3];
  int p0 = ipos[t*4], p1 = ipos[t*4+1], p2 = ipos[t*4+2], p3 = ipos[t*4+3];
  ushort4 a0 = *(const ushort4*)(partialb + (size_t)p0*HH + tid*4);
  ushort4 a1 = *(const ushort4*)(partialb + (size_t)p1*HH + tid*4);
  ushort4 a2 = *(const ushort4*)(partialb + (size_t)p2*HH + tid*4);
  ushort4 a3 = *(const ushort4*)(partialb + (size_t)p3*HH + tid*4);
  float4 sh = reinterpret_cast<const float4*>(shared_out + (size_t)t*HH)[tid];
  float4 r;
  r.x = (w0*bf2f(a0.x) + w1*bf2f(a1.x) + w2*bf2f(a2.x) + w3*bf2f(a3.x)) + sh.x;
  r.y = (w0*bf2f(a0.y) + w1*bf2f(a1.y) + w2*bf2f(a2.y) + w3*bf2f(a3.y)) + sh.y;
  r.z = (w0*bf2f(a0.z) + w1*bf2f(a1.z) + w2*bf2f(a2.z) + w3*bf2f(a3.z)) + sh.z;
  r.w = (w0*bf2f(a0.w) + w1*bf2f(a1.w) + w2*bf2f(a2.w) + w3*bf2f(a3.w)) + sh.w;
  reinterpret_cast<float4*>(out_hidden + (size_t)t*HH)[tid] = r;
}

// =====================================================================
extern "C" void kernel_launch(void* const* d_in, const int* in_sizes, int n_in,
                              void* d_out, int out_size, void* d_ws, size_t ws_size,
                              hipStream_t stream) {
  const float* hidden   = (const float*)d_in[0];
  const float* residual = (const float*)d_in[1];
  const float* in_ln_w  = (const float*)d_in[2];
  const float* post_ln_w= (const float*)d_in[3];
  const float* q_norm_w = (const float*)d_in[4];
  const float* k_norm_w = (const float*)d_in[5];
  const float* Wqkv     = (const float*)d_in[6];
  const float* Wo       = (const float*)d_in[7];
  const float* Wg       = (const float*)d_in[8];
  const float* gate_bias= (const float*)d_in[9];
  const float* Wgu      = (const float*)d_in[10];
  const float* Wd       = (const float*)d_in[11];
  const float* Wgu_sh   = (const float*)d_in[12];
  const float* Wd_sh    = (const float*)d_in[13];
  const int*   positions= (const int*)d_in[14];
  float* out = (float*)d_out;

  float* f = (float*)d_ws;
  size_t off = 0;
  float* R_A   = f + off; off += (size_t)TT*HH;
  float* HLN   = f + off; off += (size_t)TT*HH;
  float* QKV   = f + off; off += (size_t)TT*QKV_W;        // reused as gus
  float* OATT  = f + off; off += (size_t)TT*HH;           // reused as shared_out
  float* HLN2  = f + off; off += (size_t)TT*HH;
  float* SHS   = f + off; off += (size_t)TT*ISHARED;
  float* SELW  = f + off; off += (size_t)TT*TOPK_;
  ushort* HLN2B = (ushort*)(f + off); off += (size_t)TT*HH/2;
  ushort* ACTB  = (ushort*)(f + off); off += (size_t)(TT*TOPK_ + 128)*IMID/2;
  ushort* PARTB = (ushort*)(f + off); off += (size_t)TT*TOPK_*HH/2;
  ushort* PK_QKV = (ushort*)(f + off); off += (size_t)HH*QKV_W/2;
  ushort* PK_WO  = (ushort*)(f + off); off += (size_t)HH*HH/2;
  ushort* PK_WGU = (ushort*)(f + off); off += (size_t)NEXP*HH*(2*IMID)/2;
  ushort* PK_WD  = (ushort*)(f + off); off += (size_t)NEXP*IMID*HH/2;
  ushort* PK_GUSH= (ushort*)(f + off); off += (size_t)HH*(2*ISHARED)/2;
  ushort* PK_DSH = (ushort*)(f + off); off += (size_t)ISHARED*HH/2;
  int* ibase   = (int*)(f + off);
  int* SELE    = ibase;
  int* PERM    = ibase + TT*TOPK_;
  int* IPOS    = ibase + 2*TT*TOPK_;
  int* COUNTS  = ibase + 3*TT*TOPK_;
  int* OFFS    = COUNTS + NEXP;
  int* CURSOR  = OFFS + NEXP;

  // 0. pack all weights to bf16 tile images
  pack_B_kernel<<<dim3(QKV_W/64, HH/32), 256, 0, stream>>>(Wqkv, PK_QKV, QKV_W);
  pack_B_kernel<<<dim3(HH/64, HH/32), 256, 0, stream>>>(Wo, PK_WO, HH);
  pack_B_kernel<<<dim3((2*IMID)/64, NEXP*HH/32), 256, 0, stream>>>(Wgu, PK_WGU, 2*IMID);
  pack_B_kernel<<<dim3(HH/64, NEXP*IMID/32), 256, 0, stream>>>(Wd, PK_WD, HH);
  pack_B_kernel<<<dim3((2*ISHARED)/64, HH/32), 256, 0, stream>>>(Wgu_sh, PK_GUSH, 2*ISHARED);
  pack_B_kernel<<<dim3(HH/64, ISHARED/32), 256, 0, stream>>>(Wd_sh, PK_DSH, HH);

  // 1. pipeline
  add_rms_kernel<<<TT, 256, 0, stream>>>(hidden, residual, in_ln_w, R_A, HLN, nullptr);
  gemm128_pk<<<dim3(QKV_W/64, TT/128), 256, 0, stream>>>(HLN, PK_QKV, QKV, TT, QKV_W, HH);
  qk_norm_rope_kernel<<<dim3(TT, 5), 256, 0, stream>>>(QKV, q_norm_w, k_norm_w, positions);
  attn_mfma_kernel<<<dim3(TT/64, NHEADS), 256, 0, stream>>>(QKV, OATT);
  gemm128_pk<<<dim3(HH/64, TT/128), 256, 0, stream>>>(OATT, PK_WO, HLN, TT, HH, HH);
  add_rms_kernel<<<TT, 256, 0, stream>>>(HLN, R_A, post_ln_w, out + (size_t)TT*HH, HLN2, HLN2B);
  router_kernel<<<TT/4, 256, 0, stream>>>(HLN2, Wg, gate_bias, SELE, SELW);
  count_kernel<<<NEXP, 256, 0, stream>>>(SELE, COUNTS);
  scan_kernel<<<1, 64, 0, stream>>>(COUNTS, OFFS, CURSOR);
  scatter_kernel<<<(TT*TOPK_ + 255)/256, 256, 0, stream>>>(SELE, CURSOR, PERM, IPOS);
  moe_up_pk<<<dim3(NEXP, 16, IMID/64), 256, 0, stream>>>(HLN2B, PK_WGU, PERM, OFFS, COUNTS, ACTB);
  moe_down_pk<<<dim3(NEXP, 16, HH/64), 256, 0, stream>>>(ACTB, PK_WD, OFFS, COUNTS, PARTB);
  gemm128_pk<<<dim3((2*ISHARED)/64, TT/128), 256, 0, stream>>>(HLN2, PK_GUSH, QKV, TT, 2*ISHARED, HH);
  silu_shared_kernel<<<(TT*ISHARED + 255)/256, 256, 0, stream>>>(QKV, SHS);
  gemm128_pk<<<dim3(HH/64, TT/128), 256, 0, stream>>>(SHS, PK_DSH, OATT, TT, HH, ISHARED);
  final_combine_kernel<<<TT, 256, 0, stream>>>(PARTB, SELW, IPOS, OATT, out);
}

// Round 9
// 416.056 us; speedup vs baseline: 1.1604x; 1.0433x over previous
//
#include <hip/hip_runtime.h>
#include <math.h>

// ---- problem constants ----
#define TT 2048
#define HH 1024
#define NHEADS 16
#define NKVH 4
#define HDIM 64
#define NEXP 32
#define TOPK_ 4
#define NGRP 4
#define IMID 384
#define ISHARED 384
#define QKV_W (24*64)   // 1536
#define EPS_ 1e-5f

typedef __attribute__((ext_vector_type(8))) short short8;
typedef __attribute__((ext_vector_type(4))) float f32x4;

__device__ __forceinline__ ushort f2bf(float x) {
  union { float f; unsigned u; } v; v.f = x;
  unsigned r = v.u + 0x7fffu + ((v.u >> 16) & 1u);
  return (ushort)(r >> 16);
}
__device__ __forceinline__ float bf2f(ushort u) {
  union { unsigned i; float f; } v; v.i = (unsigned)u << 16; return v.f;
}

// async global->LDS, 16B per lane; lds dst = wave-uniform base + lane*16
__device__ __forceinline__ void gload16(const void* g, void* l) {
  __builtin_amdgcn_global_load_lds(
      (const __attribute__((address_space(1))) unsigned int*)g,
      (__attribute__((address_space(3))) unsigned int*)l, 16, 0, 0);
}

// =====================================================================
// MFMA fragment layouts (16x16x32 bf16), verified rounds 1-8:
//   A-frag lane l: A[row=l&15][k in {4g+j, 16+4g+j}], g=l>>4
//   B-frag lane l: B[k in {4g+j, 16+4g+j}][col=l&15]
//   C lane l: C[row=(l>>4)*4+i][col=l&15]
// A LDS plane: [g][128 rows][8] with row^g swizzle (8 KB / buffer).
// B LDS plane: 4 planes x 1024B, 16B-granular column XOR swizzle (4 KB).
// Permuted activation row layout (bf16): within each 32-col block,
// position g*8 + hi*4 + j holds original col 4g + 16*hi + j. A lane's
// A-frag (g fixed) is 16 CONTIGUOUS bytes -> global_load_lds-able.
// =====================================================================
__device__ __forceinline__ short8 read_a_frag128(const ushort* As, int lg, int row) {
  return *(const short8*)(As + ((lg * 128 + (row ^ lg)) * 8));
}
__device__ __forceinline__ short8 read_b_frag(const ushort* Bs, int lg, int col) {
  int boff = (col * 16) ^ (((col >> 3) & 7) << 4);
  return *(const short8*)((const char*)Bs + lg * 1024 + boff);
}

// B-tile staging from f32 (pack kernels only)
__device__ __forceinline__ void stage_B_tile(const float* __restrict__ B, int ldb,
                                             int k0, int col0, ushort* Bs, int tid) {
  int a = tid >> 4;
  int cG = tid & 15;
  int k = 2 * a;
  const float* p0 = B + (size_t)(k0 + k) * ldb + col0 + cG * 4;
  const float* p1 = p0 + ldb;
  float4 r0 = *(const float4*)p0;
  float4 r1 = *(const float4*)p1;
  int gg = (k & 15) >> 2;
  int slot = (k & 3) + ((k >> 4) << 2);
  float v0[4] = {r0.x, r0.y, r0.z, r0.w};
  float v1[4] = {r1.x, r1.y, r1.z, r1.w};
  char* plane = (char*)Bs + gg * 1024;
  #pragma unroll
  for (int j = 0; j < 4; ++j) {
    int c = cG * 4 + j;
    unsigned pk = (unsigned)f2bf(v0[j]) | ((unsigned)f2bf(v1[j]) << 16);
    int boff = ((c * 16) ^ (((c >> 3) & 7) << 4)) + slot * 2;
    *(unsigned*)(plane + boff) = pk;
  }
}

// ---------------------------------------------------------------------
// Pack kernel: f32 KxN matrix -> bf16 pre-swizzled B-tile images.
// ---------------------------------------------------------------------
__global__ __launch_bounds__(256) void pack_B_kernel(
    const float* __restrict__ src, ushort* __restrict__ dst, int N) {
  __shared__ ushort tileB[2048];
  int tid = threadIdx.x;
  stage_B_tile(src, N, blockIdx.y * 32, blockIdx.x * 64, tileB, tid);
  __syncthreads();
  size_t toff = ((size_t)blockIdx.y * gridDim.x + blockIdx.x) * 2048;
  *(short8*)(dst + toff + tid * 8) = *(const short8*)(tileB + tid * 8);
}

// ---------------------------------------------------------------------
// Unified dense GEMM: C(MxN,f32) = Ab(permuted bf16, MxK) @ Bpk.
// BM=128, BN=64. Ring-3 counted-vmcnt pipeline (3 gloads/issue).
// ---------------------------------------------------------------------
__global__ __launch_bounds__(256) void gemm128_bb(
    const ushort* __restrict__ Ab, const ushort* __restrict__ Bpk,
    float* __restrict__ C, int M, int N, int K) {
  __shared__ ushort As[3][4096];
  __shared__ ushort Bs[3][2048];
  int tid = threadIdx.x;
  int row0 = blockIdx.y * 128, col0 = blockIdx.x * 64;
  int ntn = N >> 6;
  int wid = tid >> 6, lane = tid & 63;
  int lg = lane >> 4, lr = lane & 15;
  int wrow = wid * 32;
  const ushort* asrc0 = Ab + (size_t)(row0 + (lane ^ wid)) * K + wid * 8;
  const ushort* asrc1 = Ab + (size_t)(row0 + 64 + (lane ^ wid)) * K + wid * 8;
  const ushort* bt0 = Bpk + (size_t)blockIdx.x * 2048 + wid * 512 + lane * 8;
  const int NT = K >> 5;
  f32x4 acc[2][4] = {};

  auto issue = [&](int tt) {
    int b = tt % 3;
    gload16(asrc0 + tt * 32, &As[b][wid * 1024]);
    gload16(asrc1 + tt * 32, &As[b][wid * 1024 + 512]);
    gload16(bt0 + (size_t)tt * ntn * 2048, &Bs[b][wid * 512]);
  };
  issue(0);
  issue(1);
  for (int t = 0; t < NT; ++t) {
    if (t < NT - 1) asm volatile("s_waitcnt vmcnt(3)" ::: "memory");
    else            asm volatile("s_waitcnt vmcnt(0)" ::: "memory");
    __builtin_amdgcn_s_barrier();
    if (t + 2 < NT) issue(t + 2);
    int cb = t % 3;
    short8 af0 = read_a_frag128(&As[cb][0], lg, wrow + lr);
    short8 af1 = read_a_frag128(&As[cb][0], lg, wrow + 16 + lr);
    #pragma unroll
    for (int nn = 0; nn < 4; ++nn) {
      short8 bf_ = read_b_frag(&Bs[cb][0], lg, nn * 16 + lr);
      acc[0][nn] = __builtin_amdgcn_mfma_f32_16x16x32_bf16(af0, bf_, acc[0][nn], 0, 0, 0);
      acc[1][nn] = __builtin_amdgcn_mfma_f32_16x16x32_bf16(af1, bf_, acc[1][nn], 0, 0, 0);
    }
  }
  #pragma unroll
  for (int mm = 0; mm < 2; ++mm)
    #pragma unroll
    for (int nn = 0; nn < 4; ++nn) {
      int row = row0 + wrow + mm * 16 + lg * 4;
      int col = col0 + nn * 16 + lr;
      #pragma unroll
      for (int i = 0; i < 4; ++i)
        C[(size_t)(row + i) * N + col] = acc[mm][nn][i];
    }
}

// ---------------------------------------------------------------------
// MoE up-proj (r8 verified): ring-3 counted-vmcnt, permuted bf16 A.
// ---------------------------------------------------------------------
__global__ __launch_bounds__(256) void moe_up_pk(
    const ushort* __restrict__ hln2b, const ushort* __restrict__ Wpk,
    const int* __restrict__ perm, const int* __restrict__ offs,
    const int* __restrict__ counts, ushort* __restrict__ actb) {
  int e = blockIdx.x;
  int cnt = counts[e];
  int base = blockIdx.y * 128;
  if (base >= cnt) return;
  int start = offs[e];
  int nt = min(128, cnt - base);
  __shared__ int tokmap[128];
  int tid = threadIdx.x;
  if (tid < 128) {
    int idx = start + base + ((tid < nt) ? tid : 0);
    tokmap[tid] = perm[idx] >> 2;
  }
  __shared__ ushort As[3][4096];
  __shared__ ushort Bg[3][2048];
  __shared__ ushort Bu[3][2048];
  __syncthreads();
  int bz = blockIdx.z, col0 = bz * 64;
  const ushort* bgt = Wpk + ((size_t)(e * 32) * 12 + bz) * 2048;
  const ushort* but = bgt + (size_t)6 * 2048;
  int wid = tid >> 6, lane = tid & 63;
  int lg = lane >> 4, lr = lane & 15;
  int wrow = wid * 32;
  int rowq0 = lane ^ wid;
  int rowq1 = (64 + lane) ^ wid;
  const ushort* asrc0 = hln2b + (size_t)tokmap[rowq0] * HH + wid * 8;
  const ushort* asrc1 = hln2b + (size_t)tokmap[rowq1] * HH + wid * 8;
  const int NT = HH >> 5;
  f32x4 accg[2][4] = {}, accu[2][4] = {};

  auto issue = [&](int tt) {
    int b = tt % 3;
    gload16(asrc0 + tt * 32, &As[b][wid * 1024]);
    gload16(asrc1 + tt * 32, &As[b][wid * 1024 + 512]);
    gload16(bgt + (size_t)tt * 12 * 2048 + tid * 8, &Bg[b][wid * 512]);
    gload16(but + (size_t)tt * 12 * 2048 + tid * 8, &Bu[b][wid * 512]);
  };
  issue(0);
  issue(1);
  for (int t = 0; t < NT; ++t) {
    if (t < NT - 1) asm volatile("s_waitcnt vmcnt(4)" ::: "memory");
    else            asm volatile("s_waitcnt vmcnt(0)" ::: "memory");
    __builtin_amdgcn_s_barrier();
    if (t + 2 < NT) issue(t + 2);
    int cb = t % 3;
    short8 af0 = read_a_frag128(&As[cb][0], lg, wrow + lr);
    short8 af1 = read_a_frag128(&As[cb][0], lg, wrow + 16 + lr);
    #pragma unroll
    for (int nn = 0; nn < 4; ++nn) {
      short8 bgf = read_b_frag(&Bg[cb][0], lg, nn * 16 + lr);
      short8 buf_ = read_b_frag(&Bu[cb][0], lg, nn * 16 + lr);
      accg[0][nn] = __builtin_amdgcn_mfma_f32_16x16x32_bf16(af0, bgf, accg[0][nn], 0, 0, 0);
      accg[1][nn] = __builtin_amdgcn_mfma_f32_16x16x32_bf16(af1, bgf, accg[1][nn], 0, 0, 0);
      accu[0][nn] = __builtin_amdgcn_mfma_f32_16x16x32_bf16(af0, buf_, accu[0][nn], 0, 0, 0);
      accu[1][nn] = __builtin_amdgcn_mfma_f32_16x16x32_bf16(af1, buf_, accu[1][nn], 0, 0, 0);
    }
  }
  #pragma unroll
  for (int mm = 0; mm < 2; ++mm)
    #pragma unroll
    for (int nn = 0; nn < 4; ++nn) {
      int pcol = col0 + ((nn >> 1) << 5) + ((lr >> 2) << 3) + ((nn & 1) << 2) + (lr & 3);
      #pragma unroll
      for (int i = 0; i < 4; ++i) {
        int rr = wrow + mm * 16 + lg * 4 + i;
        if (rr < nt) {
          float gv = accg[mm][nn][i], uv = accu[mm][nn][i];
          float av = gv / (1.f + expf(-gv)) * uv;
          actb[(size_t)(start + base + rr) * IMID + pcol] = f2bf(av);
        }
      }
    }
}

// ---------------------------------------------------------------------
// MoE down-proj (r8 verified): ring-3 counted-vmcnt.
// ---------------------------------------------------------------------
__global__ __launch_bounds__(256) void moe_down_pk(
    const ushort* __restrict__ actb, const ushort* __restrict__ Wpk,
    const int* __restrict__ offs, const int* __restrict__ counts,
    ushort* __restrict__ partialb) {
  int e = blockIdx.x;
  int cnt = counts[e];
  int base = blockIdx.y * 128;
  if (base >= cnt) return;
  int start = offs[e];
  int nt = min(128, cnt - base);
  __shared__ ushort As[3][4096];
  __shared__ ushort Bs[3][2048];
  int tid = threadIdx.x;
  int bz = blockIdx.z, col0 = bz * 64;
  const ushort* bt0 = Wpk + ((size_t)(e * 12) * 16 + bz) * 2048;
  int wid = tid >> 6, lane = tid & 63;
  int lg = lane >> 4, lr = lane & 15;
  int wrow = wid * 32;
  const ushort* asrc0 = actb + (size_t)(start + base + (lane ^ wid)) * IMID + wid * 8;
  const ushort* asrc1 = actb + (size_t)(start + base + ((64 + lane) ^ wid)) * IMID + wid * 8;
  const int NT = IMID >> 5;
  f32x4 acc[2][4] = {};

  auto issue = [&](int tt) {
    int b = tt % 3;
    gload16(asrc0 + tt * 32, &As[b][wid * 1024]);
    gload16(asrc1 + tt * 32, &As[b][wid * 1024 + 512]);
    gload16(bt0 + (size_t)tt * 16 * 2048 + tid * 8, &Bs[b][wid * 512]);
  };
  issue(0);
  issue(1);
  for (int t = 0; t < NT; ++t) {
    if (t < NT - 1) asm volatile("s_waitcnt vmcnt(3)" ::: "memory");
    else            asm volatile("s_waitcnt vmcnt(0)" ::: "memory");
    __builtin_amdgcn_s_barrier();
    if (t + 2 < NT) issue(t + 2);
    int cb = t % 3;
    short8 af0 = read_a_frag128(&As[cb][0], lg, wrow + lr);
    short8 af1 = read_a_frag128(&As[cb][0], lg, wrow + 16 + lr);
    #pragma unroll
    for (int nn = 0; nn < 4; ++nn) {
      short8 bf_ = read_b_frag(&Bs[cb][0], lg, nn * 16 + lr);
      acc[0][nn] = __builtin_amdgcn_mfma_f32_16x16x32_bf16(af0, bf_, acc[0][nn], 0, 0, 0);
      acc[1][nn] = __builtin_amdgcn_mfma_f32_16x16x32_bf16(af1, bf_, acc[1][nn], 0, 0, 0);
    }
  }
  #pragma unroll
  for (int mm = 0; mm < 2; ++mm)
    #pragma unroll
    for (int nn = 0; nn < 4; ++nn)
      #pragma unroll
      for (int i = 0; i < 4; ++i) {
        int rr = wrow + mm * 16 + lg * 4 + i;
        if (rr < nt)
          partialb[(size_t)(start + base + rr) * HH + col0 + nn * 16 + lr] = f2bf(acc[mm][nn][i]);
      }
}

// =====================================================================
// residual add + RMSNorm; emits f32 sum, f32 ln, permuted bf16 ln.
// =====================================================================
__global__ __launch_bounds__(256) void add_rms_kernel(
    const float* __restrict__ a, const float* __restrict__ b,
    const float* __restrict__ w, float* __restrict__ sum_out,
    float* __restrict__ ln_out, ushort* __restrict__ lnb) {
  int t = blockIdx.x, tid = threadIdx.x;
  float4 x = reinterpret_cast<const float4*>(a + (size_t)t*HH)[tid];
  float4 y = reinterpret_cast<const float4*>(b + (size_t)t*HH)[tid];
  x.x += y.x; x.y += y.y; x.z += y.z; x.w += y.w;
  float ss = x.x*x.x + x.y*x.y + x.z*x.z + x.w*x.w;
  #pragma unroll
  for (int off = 1; off < 64; off <<= 1) ss += __shfl_xor(ss, off);
  __shared__ float wsum[4];
  int wid = tid >> 6, lane = tid & 63;
  if (lane == 0) wsum[wid] = ss;
  __syncthreads();
  float tot = wsum[0] + wsum[1] + wsum[2] + wsum[3];
  float r = rsqrtf(tot * (1.0f/HH) + EPS_);
  reinterpret_cast<float4*>(sum_out + (size_t)t*HH)[tid] = x;
  float4 wl = reinterpret_cast<const float4*>(w)[tid];
  float4 o = make_float4(x.x*r*wl.x, x.y*r*wl.y, x.z*r*wl.z, x.w*r*wl.w);
  reinterpret_cast<float4*>(ln_out + (size_t)t*HH)[tid] = o;
  ushort4 ub;
  ub.x = f2bf(o.x); ub.y = f2bf(o.y); ub.z = f2bf(o.z); ub.w = f2bf(o.w);
  int dst = ((tid >> 3) << 5) + ((tid & 3) << 3) + (((tid >> 2) & 1) << 2);
  *(ushort4*)(lnb + (size_t)t * HH + dst) = ub;
}

// =====================================================================
// per-(t,head) QK RMSNorm + RoPE, in-place (f32)
// =====================================================================
__global__ __launch_bounds__(256) void qk_norm_rope_kernel(
    float* __restrict__ qkv, const float* __restrict__ qw,
    const float* __restrict__ kw, const int* __restrict__ pos) {
  int t = blockIdx.x;
  int hh = blockIdx.y * 4 + (threadIdx.x >> 6);
  int lane = threadIdx.x & 63;
  float* p = qkv + (size_t)t * QKV_W + hh * HDIM;
  float x = p[lane];
  float ss = x * x;
  #pragma unroll
  for (int off = 1; off < 64; off <<= 1) ss += __shfl_xor(ss, off);
  float r = rsqrtf(ss * (1.0f/HDIM) + EPS_);
  float wv = (hh < NHEADS ? qw : kw)[lane];
  float xn = x * r * wv;
  float partner = __shfl_xor(xn, 16);
  float out = xn;
  if (lane < 32) {
    int i = lane & 15;
    float inv = powf(10000.0f, -(float)i / 16.0f);
    float ang = (float)pos[t] * inv;
    float cv = cosf(ang), sv = sinf(ang);
    out = (lane < 16) ? (xn * cv - partner * sv) : (partner * sv + xn * cv);
  }
  p[lane] = out;
}

// =====================================================================
// pack_KV: rope'd K -> A-tile images; V -> B-tile images. grid (T/32, NKVH)
// =====================================================================
__global__ __launch_bounds__(256) void pack_KV_kernel(
    const float* __restrict__ qkv, ushort* __restrict__ Kpk,
    ushort* __restrict__ Vpk) {
  __shared__ ushort kimg[2048];
  __shared__ ushort vimg[2048];
  int tid = threadIdx.x;
  int kt = blockIdx.x, kvh = blockIdx.y;
  {
    int c = tid >> 7, t2 = tid & 127;
    int g = t2 & 3, r = t2 >> 2;
    const float* kp = qkv + (size_t)(kt*32 + r) * QKV_W + NHEADS*HDIM + kvh*HDIM + 32*c + 4*g;
    float4 h0 = *(const float4*)kp;
    float4 h1 = *(const float4*)(kp + 16);
    short8 v;
    v[0]=(short)f2bf(h0.x); v[1]=(short)f2bf(h0.y); v[2]=(short)f2bf(h0.z); v[3]=(short)f2bf(h0.w);
    v[4]=(short)f2bf(h1.x); v[5]=(short)f2bf(h1.y); v[6]=(short)f2bf(h1.z); v[7]=(short)f2bf(h1.w);
    *(short8*)(kimg + c*1024 + (g*32 + (r^g))*8) = v;
  }
  stage_B_tile(qkv + (size_t)(NHEADS+NKVH)*HDIM + (size_t)kvh*HDIM, QKV_W, kt*32, 0, vimg, tid);
  __syncthreads();
  size_t toff = ((size_t)(kvh * (TT/32) + kt)) * 2048;
  *(short8*)(Kpk + toff + tid * 8) = *(const short8*)(kimg + tid * 8);
  *(short8*)(Vpk + toff + tid * 8) = *(const short8*)(vimg + tid * 8);
}

// =====================================================================
// Attention v2: packed K/V, ring-3 gload pipeline, log2 softmax with
// pre-scaled Q, diagonal-only masking, defer-max. grid (NHEADS, 32).
// Writes output directly in permuted bf16 (for Wo gemm).
// =====================================================================
__global__ __launch_bounds__(256) void attn_v2_kernel(
    const float* __restrict__ qkv, const ushort* __restrict__ Kpk,
    const ushort* __restrict__ Vpk, ushort* __restrict__ ob) {
  __shared__ ushort Ks[3][2048];
  __shared__ ushort Vs[3][2048];
  int tid = threadIdx.x;
  int wid = tid >> 6, lane = tid & 63;
  int lg = lane >> 4, lr = lane & 15;
  int h = blockIdx.x;
  int qbr = blockIdx.y;
  int qb = (qbr < 16) ? qbr : 47 - qbr;   // work-balanced remap
  int kvh = h >> 2;
  int q0 = qb * 64 + wid * 16;
  int qg = q0 + lr;
  const float SCL = 0.125f * 1.44269504f;   // 1/8 * log2(e): scores in log2 domain

  const float* qrow = qkv + (size_t)qg * QKV_W + h * HDIM;
  short8 qfr[2];
  #pragma unroll
  for (int c = 0; c < 2; ++c) {
    float4 a = *(const float4*)(qrow + 32*c + 4*lg);
    float4 b = *(const float4*)(qrow + 32*c + 4*lg + 16);
    short8 v;
    v[0]=(short)f2bf(a.x*SCL); v[1]=(short)f2bf(a.y*SCL); v[2]=(short)f2bf(a.z*SCL); v[3]=(short)f2bf(a.w*SCL);
    v[4]=(short)f2bf(b.x*SCL); v[5]=(short)f2bf(b.y*SCL); v[6]=(short)f2bf(b.z*SCL); v[7]=(short)f2bf(b.w*SCL);
    qfr[c] = v;
  }

  int nkv = qb * 2 + 2;
  const ushort* ksrc = Kpk + (size_t)(kvh * (TT/32)) * 2048 + wid * 512 + lane * 8;
  const ushort* vsrc = Vpk + (size_t)(kvh * (TT/32)) * 2048 + wid * 512 + lane * 8;

  f32x4 o_acc[4] = {};
  float m_st = -1e30f, l_st = 0.f;

  auto issue = [&](int tt) {
    int b = tt % 3;
    gload16(ksrc + (size_t)tt * 2048, &Ks[b][wid * 512]);
    gload16(vsrc + (size_t)tt * 2048, &Vs[b][wid * 512]);
  };
  issue(0);
  issue(1);
  for (int t = 0; t < nkv; ++t) {
    if (t < nkv - 1) asm volatile("s_waitcnt vmcnt(2)" ::: "memory");
    else             asm volatile("s_waitcnt vmcnt(0)" ::: "memory");
    __builtin_amdgcn_s_barrier();
    if (t + 2 < nkv) issue(t + 2);
    if (t * 32 > q0 + 15) continue;   // fully masked for this wave
    int cb = t % 3;
    f32x4 st[2];
    #pragma unroll
    for (int n = 0; n < 2; ++n) {
      short8 kf0 = *(const short8*)(&Ks[cb][(lg*32 + ((16*n + lr) ^ lg)) * 8]);
      short8 kf1 = *(const short8*)(&Ks[cb][1024 + (lg*32 + ((16*n + lr) ^ lg)) * 8]);
      f32x4 z = {};
      z = __builtin_amdgcn_mfma_f32_16x16x32_bf16(kf0, qfr[0], z, 0, 0, 0);
      st[n] = __builtin_amdgcn_mfma_f32_16x16x32_bf16(kf1, qfr[1], z, 0, 0, 0);
    }
    float s[2][4];
    if (t * 32 + 31 <= q0) {          // fully unmasked tile (common case)
      #pragma unroll
      for (int n = 0; n < 2; ++n)
        #pragma unroll
        for (int i = 0; i < 4; ++i) s[n][i] = st[n][i];
    } else {                          // diagonal tile
      #pragma unroll
      for (int n = 0; n < 2; ++n)
        #pragma unroll
        for (int i = 0; i < 4; ++i) {
          int kvg = t*32 + 16*n + 4*lg + i;
          s[n][i] = (kvg <= qg) ? st[n][i] : -1e30f;
        }
    }
    float tmax = s[0][0];
    #pragma unroll
    for (int n = 0; n < 2; ++n)
      #pragma unroll
      for (int i = 0; i < 4; ++i) tmax = fmaxf(tmax, s[n][i]);
    tmax = fmaxf(tmax, __shfl_xor(tmax, 16));
    tmax = fmaxf(tmax, __shfl_xor(tmax, 32));
    float p[2][4];
    if (__all(tmax - m_st <= 12.0f)) {   // defer-max: skip rescale
      float psum = 0.f;
      #pragma unroll
      for (int n = 0; n < 2; ++n)
        #pragma unroll
        for (int i = 0; i < 4; ++i) { float pv = exp2f(s[n][i] - m_st); p[n][i] = pv; psum += pv; }
      psum += __shfl_xor(psum, 16);
      psum += __shfl_xor(psum, 32);
      l_st += psum;
    } else {
      float m_new = fmaxf(m_st, tmax);
      float corr = exp2f(m_st - m_new);
      float psum = 0.f;
      #pragma unroll
      for (int n = 0; n < 2; ++n)
        #pragma unroll
        for (int i = 0; i < 4; ++i) { float pv = exp2f(s[n][i] - m_new); p[n][i] = pv; psum += pv; }
      psum += __shfl_xor(psum, 16);
      psum += __shfl_xor(psum, 32);
      l_st = l_st * corr + psum;
      m_st = m_new;
      #pragma unroll
      for (int i = 0; i < 4; ++i) {
        float oc = __shfl(corr, 4*lg + i);
        #pragma unroll
        for (int nd = 0; nd < 4; ++nd) o_acc[nd][i] *= oc;
      }
    }
    union { unsigned u[4]; short8 s8; } pu;
    asm volatile("v_cvt_pk_bf16_f32 %0, %1, %2" : "=v"(pu.u[0]) : "v"(p[0][0]), "v"(p[0][1]));
    asm volatile("v_cvt_pk_bf16_f32 %0, %1, %2" : "=v"(pu.u[1]) : "v"(p[0][2]), "v"(p[0][3]));
    asm volatile("v_cvt_pk_bf16_f32 %0, %1, %2" : "=v"(pu.u[2]) : "v"(p[1][0]), "v"(p[1][1]));
    asm volatile("v_cvt_pk_bf16_f32 %0, %1, %2" : "=v"(pu.u[3]) : "v"(p[1][2]), "v"(p[1][3]));
    short8 pa = pu.s8;
    #pragma unroll
    for (int nd = 0; nd < 4; ++nd) {
      short8 vf = read_b_frag(&Vs[cb][0], lg, 16*nd + lr);
      o_acc[nd] = __builtin_amdgcn_mfma_f32_16x16x32_bf16(pa, vf, o_acc[nd], 0, 0, 0);
    }
  }

  // epilogue: divide by l, write permuted bf16
  #pragma unroll
  for (int i = 0; i < 4; ++i) {
    float lrow = __shfl(l_st, 4*lg + i);
    float inv = 1.0f / lrow;
    int row = q0 + 4*lg + i;
    ushort* op = ob + (size_t)row * (NHEADS*HDIM) + h * HDIM;
    #pragma unroll
    for (int nd = 0; nd < 4; ++nd) {
      int pcol = ((nd >> 1) << 5) + ((lr >> 2) << 3) + ((nd & 1) << 2) + (lr & 3);
      op[pcol] = f2bf(o_acc[nd][i] * inv);
    }
  }
}

// =====================================================================
// router: wave-parallel (r8 verified)
// =====================================================================
__global__ __launch_bounds__(256) void router_kernel(
    const float* __restrict__ hln, const float* __restrict__ Wg,
    const float* __restrict__ bias, int* __restrict__ sel_e,
    float* __restrict__ sel_w) {
  __shared__ float hid[4][HH];
  int tid = threadIdx.x, wid = tid >> 6, lane = tid & 63;
  int t = blockIdx.x * 4 + wid;
  const float4* src = (const float4*)(hln + (size_t)t * HH);
  float4* dst = (float4*)hid[wid];
  #pragma unroll
  for (int j = 0; j < 4; ++j) dst[j * 64 + lane] = src[j * 64 + lane];
  int e = lane & 31, half = lane >> 5;
  const float* wp = Wg + (size_t)(half * 512) * NEXP + e;
  const float* hp = hid[wid] + half * 512;
  float p = 0.f;
  #pragma unroll 8
  for (int h = 0; h < 512; ++h) p += hp[h] * wp[(size_t)h * NEXP];
  p += __shfl_xor(p, 32);
  float sc = 1.0f / (1.0f + expf(-p));
  float sfc = sc + bias[e];
  float m1 = sfc, m2 = -1e30f;
  #pragma unroll
  for (int off = 1; off <= 4; off <<= 1) {
    float om1 = __shfl_xor(m1, off), om2 = __shfl_xor(m2, off);
    float hi_ = fmaxf(m1, om1);
    float lo_ = fmaxf(fminf(m1, om1), fmaxf(m2, om2));
    m1 = hi_; m2 = lo_;
  }
  float gs = m1 + m2;
  float gv[4] = {__shfl(gs, 0), __shfl(gs, 8), __shfl(gs, 16), __shfl(gs, 24)};
  int g1 = 0; float b1 = gv[0];
  #pragma unroll
  for (int g = 1; g < 4; ++g) if (gv[g] > b1) { b1 = gv[g]; g1 = g; }
  int g2 = -1; float b2 = -1e30f;
  #pragma unroll
  for (int g = 0; g < 4; ++g) if (g != g1 && gv[g] > b2) { b2 = gv[g]; g2 = g; }
  bool keep = ((e >> 3) == g1) || ((e >> 3) == g2);
  float cand = keep ? sfc : -1e30f;
  int ids[4]; float wv[4]; float wsum = 0.f;
  #pragma unroll
  for (int s = 0; s < 4; ++s) {
    float v = cand; int ix = e;
    #pragma unroll
    for (int off = 1; off < 64; off <<= 1) {
      float ov = __shfl_xor(v, off); int oix = __shfl_xor(ix, off);
      if (ov > v || (ov == v && oix < ix)) { v = ov; ix = oix; }
    }
    ids[s] = ix;
    if (e == ix) cand = -1e30f;
    float w = __shfl(sc, ix);
    wv[s] = w; wsum += w;
  }
  if (lane == 0) {
    #pragma unroll
    for (int s = 0; s < 4; ++s) {
      sel_e[t * 4 + s] = ids[s];
      sel_w[t * 4 + s] = wv[s] / wsum;
    }
  }
}

__global__ __launch_bounds__(256) void count_kernel(
    const int* __restrict__ sel_e, int* __restrict__ counts) {
  int e = blockIdx.x, tid = threadIdx.x;
  int c = 0;
  for (int i = tid; i < TT * TOPK_; i += 256) c += (sel_e[i] == e);
  #pragma unroll
  for (int off = 1; off < 64; off <<= 1) c += __shfl_xor(c, off);
  __shared__ int wsum[4];
  if ((tid & 63) == 0) wsum[tid >> 6] = c;
  __syncthreads();
  if (tid == 0) counts[e] = wsum[0] + wsum[1] + wsum[2] + wsum[3];
}

__global__ void scan_kernel(const int* __restrict__ counts,
                            int* __restrict__ offs, int* __restrict__ cursor) {
  if (threadIdx.x == 0) {
    int acc = 0;
    for (int e = 0; e < NEXP; ++e) { offs[e] = acc; cursor[e] = acc; acc += counts[e]; }
  }
}

__global__ void scatter_kernel(const int* __restrict__ sel_e,
                               int* __restrict__ cursor, int* __restrict__ perm,
                               int* __restrict__ ipos) {
  int i = blockIdx.x * 256 + threadIdx.x;
  if (i < TT * TOPK_) {
    int e = sel_e[i];
    int pos = atomicAdd(&cursor[e], 1);
    perm[pos] = i;
    ipos[i] = pos;
  }
}

// =====================================================================
// shared-expert SiLU*mul -> permuted bf16 (4 cols/thread)
// =====================================================================
__global__ __launch_bounds__(256) void silu_shared_kernel(
    const float* __restrict__ gus, ushort* __restrict__ shsb) {
  int i = blockIdx.x * 256 + threadIdx.x;
  if (i < TT * (ISHARED/4)) {
    int t = i / (ISHARED/4), k = i % (ISHARED/4);
    const float* gp = gus + (size_t)t * (2*ISHARED) + k * 4;
    float4 g4 = *(const float4*)gp;
    float4 u4 = *(const float4*)(gp + ISHARED);
    ushort4 r;
    r.x = f2bf(g4.x / (1.f + expf(-g4.x)) * u4.x);
    r.y = f2bf(g4.y / (1.f + expf(-g4.y)) * u4.y);
    r.z = f2bf(g4.z / (1.f + expf(-g4.z)) * u4.z);
    r.w = f2bf(g4.w / (1.f + expf(-g4.w)) * u4.w);
    int pdst = ((k >> 3) << 5) + ((k & 3) << 3) + (((k >> 2) & 1) << 2);
    *(ushort4*)(shsb + (size_t)t * ISHARED + pdst) = r;
  }
}

// =====================================================================
// final combine (bf16 partial)
// =====================================================================
__global__ __launch_bounds__(256) void final_combine_kernel(
    const ushort* __restrict__ partialb, const float* __restrict__ sel_w,
    const int* __restrict__ ipos, const float* __restrict__ shared_out,
    float* __restrict__ out_hidden) {
  int t = blockIdx.x, tid = threadIdx.x;
  float w0 = sel_w[t*4], w1 = sel_w[t*4+1], w2 = sel_w[t*4+2], w3 = sel_w[t*4+3];
  int p0 = ipos[t*4], p1 = ipos[t*4+1], p2 = ipos[t*4+2], p3 = ipos[t*4+3];
  ushort4 a0 = *(const ushort4*)(partialb + (size_t)p0*HH + tid*4);
  ushort4 a1 = *(const ushort4*)(partialb + (size_t)p1*HH + tid*4);
  ushort4 a2 = *(const ushort4*)(partialb + (size_t)p2*HH + tid*4);
  ushort4 a3 = *(const ushort4*)(partialb + (size_t)p3*HH + tid*4);
  float4 sh = reinterpret_cast<const float4*>(shared_out + (size_t)t*HH)[tid];
  float4 r;
  r.x = (w0*bf2f(a0.x) + w1*bf2f(a1.x) + w2*bf2f(a2.x) + w3*bf2f(a3.x)) + sh.x;
  r.y = (w0*bf2f(a0.y) + w1*bf2f(a1.y) + w2*bf2f(a2.y) + w3*bf2f(a3.y)) + sh.y;
  r.z = (w0*bf2f(a0.z) + w1*bf2f(a1.z) + w2*bf2f(a2.z) + w3*bf2f(a3.z)) + sh.z;
  r.w = (w0*bf2f(a0.w) + w1*bf2f(a1.w) + w2*bf2f(a2.w) + w3*bf2f(a3.w)) + sh.w;
  reinterpret_cast<float4*>(out_hidden + (size_t)t*HH)[tid] = r;
}

// =====================================================================
extern "C" void kernel_launch(void* const* d_in, const int* in_sizes, int n_in,
                              void* d_out, int out_size, void* d_ws, size_t ws_size,
                              hipStream_t stream) {
  const float* hidden   = (const float*)d_in[0];
  const float* residual = (const float*)d_in[1];
  const float* in_ln_w  = (const float*)d_in[2];
  const float* post_ln_w= (const float*)d_in[3];
  const float* q_norm_w = (const float*)d_in[4];
  const float* k_norm_w = (const float*)d_in[5];
  const float* Wqkv     = (const float*)d_in[6];
  const float* Wo       = (const float*)d_in[7];
  const float* Wg       = (const float*)d_in[8];
  const float* gate_bias= (const float*)d_in[9];
  const float* Wgu      = (const float*)d_in[10];
  const float* Wd       = (const float*)d_in[11];
  const float* Wgu_sh   = (const float*)d_in[12];
  const float* Wd_sh    = (const float*)d_in[13];
  const int*   positions= (const int*)d_in[14];
  float* out = (float*)d_out;

  float* f = (float*)d_ws;
  size_t off = 0;
  float* R_A   = f + off; off += (size_t)TT*HH;
  float* HLN   = f + off; off += (size_t)TT*HH;
  float* QKV   = f + off; off += (size_t)TT*QKV_W;        // reused as gus
  float* OATT  = f + off; off += (size_t)TT*HH;           // DSH output (shared_out)
  float* HLN2  = f + off; off += (size_t)TT*HH;
  float* SELW  = f + off; off += (size_t)TT*TOPK_;
  ushort* HLNB  = (ushort*)(f + off); off += (size_t)TT*HH/2;
  ushort* HLN2B = (ushort*)(f + off); off += (size_t)TT*HH/2;
  ushort* OATTB = (ushort*)(f + off); off += (size_t)TT*HH/2;
  ushort* SHSB  = (ushort*)(f + off); off += (size_t)TT*ISHARED/2;
  ushort* KPK   = (ushort*)(f + off); off += (size_t)NKVH*(TT/32)*2048/2;
  ushort* VPK   = (ushort*)(f + off); off += (size_t)NKVH*(TT/32)*2048/2;
  ushort* ACTB  = (ushort*)(f + off); off += (size_t)(TT*TOPK_ + 128)*IMID/2;
  ushort* PARTB = (ushort*)(f + off); off += (size_t)TT*TOPK_*HH/2;
  ushort* PK_QKV = (ushort*)(f + off); off += (size_t)HH*QKV_W/2;
  ushort* PK_WO  = (ushort*)(f + off); off += (size_t)HH*HH/2;
  ushort* PK_WGU = (ushort*)(f + off); off += (size_t)NEXP*HH*(2*IMID)/2;
  ushort* PK_WD  = (ushort*)(f + off); off += (size_t)NEXP*IMID*HH/2;
  ushort* PK_GUSH= (ushort*)(f + off); off += (size_t)HH*(2*ISHARED)/2;
  ushort* PK_DSH = (ushort*)(f + off); off += (size_t)ISHARED*HH/2;
  int* ibase   = (int*)(f + off);
  int* SELE    = ibase;
  int* PERM    = ibase + TT*TOPK_;
  int* IPOS    = ibase + 2*TT*TOPK_;
  int* COUNTS  = ibase + 3*TT*TOPK_;
  int* OFFS    = COUNTS + NEXP;
  int* CURSOR  = OFFS + NEXP;

  // 0. pack all weights to bf16 tile images
  pack_B_kernel<<<dim3(QKV_W/64, HH/32), 256, 0, stream>>>(Wqkv, PK_QKV, QKV_W);
  pack_B_kernel<<<dim3(HH/64, HH/32), 256, 0, stream>>>(Wo, PK_WO, HH);
  pack_B_kernel<<<dim3((2*IMID)/64, NEXP*HH/32), 256, 0, stream>>>(Wgu, PK_WGU, 2*IMID);
  pack_B_kernel<<<dim3(HH/64, NEXP*IMID/32), 256, 0, stream>>>(Wd, PK_WD, HH);
  pack_B_kernel<<<dim3((2*ISHARED)/64, HH/32), 256, 0, stream>>>(Wgu_sh, PK_GUSH, 2*ISHARED);
  pack_B_kernel<<<dim3(HH/64, ISHARED/32), 256, 0, stream>>>(Wd_sh, PK_DSH, HH);

  // 1. pipeline
  add_rms_kernel<<<TT, 256, 0, stream>>>(hidden, residual, in_ln_w, R_A, HLN, HLNB);
  gemm128_bb<<<dim3(QKV_W/64, TT/128), 256, 0, stream>>>(HLNB, PK_QKV, QKV, TT, QKV_W, HH);
  qk_norm_rope_kernel<<<dim3(TT, 5), 256, 0, stream>>>(QKV, q_norm_w, k_norm_w, positions);
  pack_KV_kernel<<<dim3(TT/32, NKVH), 256, 0, stream>>>(QKV, KPK, VPK);
  attn_v2_kernel<<<dim3(NHEADS, 32), 256, 0, stream>>>(QKV, KPK, VPK, OATTB);
  gemm128_bb<<<dim3(HH/64, TT/128), 256, 0, stream>>>(OATTB, PK_WO, HLN, TT, HH, HH);
  add_rms_kernel<<<TT, 256, 0, stream>>>(HLN, R_A, post_ln_w, out + (size_t)TT*HH, HLN2, HLN2B);
  router_kernel<<<TT/4, 256, 0, stream>>>(HLN2, Wg, gate_bias, SELE, SELW);
  count_kernel<<<NEXP, 256, 0, stream>>>(SELE, COUNTS);
  scan_kernel<<<1, 64, 0, stream>>>(COUNTS, OFFS, CURSOR);
  scatter_kernel<<<(TT*TOPK_ + 255)/256, 256, 0, stream>>>(SELE, CURSOR, PERM, IPOS);
  moe_up_pk<<<dim3(NEXP, 16, IMID/64), 256, 0, stream>>>(HLN2B, PK_WGU, PERM, OFFS, COUNTS, ACTB);
  moe_down_pk<<<dim3(NEXP, 16, HH/64), 256, 0, stream>>>(ACTB, PK_WD, OFFS, COUNTS, PARTB);
  gemm128_bb<<<dim3((2*ISHARED)/64, TT/128), 256, 0, stream>>>(HLN2B, PK_GUSH, QKV, TT, 2*ISHARED, HH);
  silu_shared_kernel<<<(TT*(ISHARED/4) + 255)/256, 256, 0, stream>>>(QKV, SHSB);
  gemm128_bb<<<dim3(HH/64, TT/128), 256, 0, stream>>>(SHSB, PK_DSH, OATT, TT, HH, ISHARED);
  final_combine_kernel<<<TT, 256, 0, stream>>>(PARTB, SELW, IPOS, OATT, out);
}

// Round 10
// 400.512 us; speedup vs baseline: 1.2054x; 1.0388x over previous
//
#include <hip/hip_runtime.h>
#include <math.h>

// ---- problem constants ----
#define TT 2048
#define HH 1024
#define NHEADS 16
#define NKVH 4
#define HDIM 64
#define NEXP 32
#define TOPK_ 4
#define NGRP 4
#define IMID 384
#define ISHARED 384
#define QKV_W (24*64)   // 1536
#define EPS_ 1e-5f

typedef __attribute__((ext_vector_type(8))) short short8;
typedef __attribute__((ext_vector_type(4))) float f32x4;

__device__ __forceinline__ ushort f2bf(float x) {
  union { float f; unsigned u; } v; v.f = x;
  unsigned r = v.u + 0x7fffu + ((v.u >> 16) & 1u);
  return (ushort)(r >> 16);
}
__device__ __forceinline__ float bf2f(ushort u) {
  union { unsigned i; float f; } v; v.i = (unsigned)u << 16; return v.f;
}

// async global->LDS, 16B per lane; lds dst = wave-uniform base + lane*16
__device__ __forceinline__ void gload16(const void* g, void* l) {
  __builtin_amdgcn_global_load_lds(
      (const __attribute__((address_space(1))) unsigned int*)g,
      (__attribute__((address_space(3))) unsigned int*)l, 16, 0, 0);
}

// =====================================================================
// MFMA fragment layouts (16x16x32 bf16), verified rounds 1-9:
//   A-frag lane l: A[row=l&15][k in {4g+j, 16+4g+j}], g=l>>4
//   B-frag lane l: B[k in {4g+j, 16+4g+j}][col=l&15]
//   C lane l: C[row=(l>>4)*4+i][col=l&15]
// A LDS plane (64-row): [g][64 rows][8] with row^g swizzle; plane g at
//   ushort offset g*512. Wave wid stages plane wid: lane l -> row l^wid.
// B LDS plane: 4 planes x 1024B, 16B-granular column XOR swizzle (4 KB).
// Permuted activation row layout (bf16): within each 32-col block,
// position g*8 + hi*4 + j holds original col 4g + 16*hi + j -> a lane's
// A-frag (g fixed) is 16 CONTIGUOUS bytes -> global_load_lds-able.
// =====================================================================
__device__ __forceinline__ short8 read_a_frag64(const ushort* As, int lg, int row) {
  return *(const short8*)(As + ((lg * 64 + (row ^ lg)) * 8));
}
__device__ __forceinline__ short8 read_b_frag(const ushort* Bs, int lg, int col) {
  int boff = (col * 16) ^ (((col >> 3) & 7) << 4);
  return *(const short8*)((const char*)Bs + lg * 1024 + boff);
}

// B-tile staging from f32 (pack kernels only)
__device__ __forceinline__ void stage_B_tile(const float* __restrict__ B, int ldb,
                                             int k0, int col0, ushort* Bs, int tid) {
  int a = tid >> 4;
  int cG = tid & 15;
  int k = 2 * a;
  const float* p0 = B + (size_t)(k0 + k) * ldb + col0 + cG * 4;
  const float* p1 = p0 + ldb;
  float4 r0 = *(const float4*)p0;
  float4 r1 = *(const float4*)p1;
  int gg = (k & 15) >> 2;
  int slot = (k & 3) + ((k >> 4) << 2);
  float v0[4] = {r0.x, r0.y, r0.z, r0.w};
  float v1[4] = {r1.x, r1.y, r1.z, r1.w};
  char* plane = (char*)Bs + gg * 1024;
  #pragma unroll
  for (int j = 0; j < 4; ++j) {
    int c = cG * 4 + j;
    unsigned pk = (unsigned)f2bf(v0[j]) | ((unsigned)f2bf(v1[j]) << 16);
    int boff = ((c * 16) ^ (((c >> 3) & 7) << 4)) + slot * 2;
    *(unsigned*)(plane + boff) = pk;
  }
}

// ---------------------------------------------------------------------
// Pack kernel: f32 KxN matrix -> bf16 pre-swizzled B-tile images.
// ---------------------------------------------------------------------
__global__ __launch_bounds__(256) void pack_B_kernel(
    const float* __restrict__ src, ushort* __restrict__ dst, int N) {
  __shared__ ushort tileB[2048];
  int tid = threadIdx.x;
  stage_B_tile(src, N, blockIdx.y * 32, blockIdx.x * 64, tileB, tid);
  __syncthreads();
  size_t toff = ((size_t)blockIdx.y * gridDim.x + blockIdx.x) * 2048;
  *(short8*)(dst + toff + tid * 8) = *(const short8*)(tileB + tid * 8);
}

// ---------------------------------------------------------------------
// Dense GEMM: C(MxN,f32) = Ab(permuted bf16, MxK) @ Bpk. BM=64, BN=64.
// 4 waves in 2Mx2N split (wave tile 32x32). Ring-4, prefetch dist 3.
// 2 gloads/thread/iter -> steady vmcnt(4).
// ---------------------------------------------------------------------
__global__ __launch_bounds__(256) void gemm64_bb(
    const ushort* __restrict__ Ab, const ushort* __restrict__ Bpk,
    float* __restrict__ C, int M, int N, int K) {
  __shared__ ushort As[4][2048];
  __shared__ ushort Bs[4][2048];
  int tid = threadIdx.x;
  int row0 = blockIdx.y * 64, col0 = blockIdx.x * 64;
  int ntn = N >> 6;
  int wid = tid >> 6, lane = tid & 63;
  int lg = lane >> 4, lr = lane & 15;
  int wrow = (wid >> 1) * 32, wcol = (wid & 1) * 32;
  const ushort* asrc = Ab + (size_t)(row0 + (lane ^ wid)) * K + wid * 8;
  const ushort* bsrc = Bpk + (size_t)blockIdx.x * 2048 + wid * 512 + lane * 8;
  const int NT = K >> 5;
  f32x4 acc[2][2] = {};

  auto issue = [&](int tt) {
    int b = tt & 3;
    gload16(asrc + tt * 32, &As[b][wid * 512]);
    gload16(bsrc + (size_t)tt * ntn * 2048, &Bs[b][wid * 512]);
  };
  issue(0); issue(1); issue(2);
  for (int t = 0; t < NT; ++t) {
    int ahead = NT - 1 - t;
    if (ahead >= 2)      asm volatile("s_waitcnt vmcnt(4)" ::: "memory");
    else if (ahead == 1) asm volatile("s_waitcnt vmcnt(2)" ::: "memory");
    else                 asm volatile("s_waitcnt vmcnt(0)" ::: "memory");
    __builtin_amdgcn_s_barrier();
    if (t + 3 < NT) issue(t + 3);
    int cb = t & 3;
    short8 af0 = read_a_frag64(&As[cb][0], lg, wrow + lr);
    short8 af1 = read_a_frag64(&As[cb][0], lg, wrow + 16 + lr);
    #pragma unroll
    for (int nn = 0; nn < 2; ++nn) {
      short8 bf_ = read_b_frag(&Bs[cb][0], lg, wcol + nn * 16 + lr);
      acc[0][nn] = __builtin_amdgcn_mfma_f32_16x16x32_bf16(af0, bf_, acc[0][nn], 0, 0, 0);
      acc[1][nn] = __builtin_amdgcn_mfma_f32_16x16x32_bf16(af1, bf_, acc[1][nn], 0, 0, 0);
    }
  }
  #pragma unroll
  for (int mm = 0; mm < 2; ++mm)
    #pragma unroll
    for (int nn = 0; nn < 2; ++nn) {
      int row = row0 + wrow + mm * 16 + lg * 4;
      int col = col0 + wcol + nn * 16 + lr;
      #pragma unroll
      for (int i = 0; i < 4; ++i)
        C[(size_t)(row + i) * N + col] = acc[mm][nn][i];
    }
}

// ---------------------------------------------------------------------
// MoE up-proj: BM=64 slots, dual g/u, SiLU*mul, permuted bf16 out.
// grid (NEXP, 32, IMID/64). Ring-4, 3 gloads/thread -> steady vmcnt(6).
// ---------------------------------------------------------------------
__global__ __launch_bounds__(256) void moe_up_pk(
    const ushort* __restrict__ hln2b, const ushort* __restrict__ Wpk,
    const int* __restrict__ perm, const int* __restrict__ offs,
    const int* __restrict__ counts, ushort* __restrict__ actb) {
  int e = blockIdx.x;
  int cnt = counts[e];
  int base = blockIdx.y * 64;
  if (base >= cnt) return;
  int start = offs[e];
  int nt = min(64, cnt - base);
  __shared__ int tokmap[64];
  int tid = threadIdx.x;
  if (tid < 64) tokmap[tid] = perm[start + base + ((tid < nt) ? tid : 0)] >> 2;
  __shared__ ushort As[4][2048];
  __shared__ ushort Bg[4][2048];
  __shared__ ushort Bu[4][2048];
  __syncthreads();
  int bz = blockIdx.z, col0 = bz * 64;
  int wid = tid >> 6, lane = tid & 63;
  int lg = lane >> 4, lr = lane & 15;
  int wrow = (wid >> 1) * 32, wcol = (wid & 1) * 32;
  const ushort* bgt = Wpk + ((size_t)(e * 32) * 12 + bz) * 2048 + wid * 512 + lane * 8;
  const ushort* but = bgt + (size_t)6 * 2048;
  const ushort* asrc = hln2b + (size_t)tokmap[lane ^ wid] * HH + wid * 8;
  const int NT = HH >> 5;   // 32
  f32x4 accg[2][2] = {}, accu[2][2] = {};

  auto issue = [&](int tt) {
    int b = tt & 3;
    gload16(asrc + tt * 32, &As[b][wid * 512]);
    gload16(bgt + (size_t)tt * 12 * 2048, &Bg[b][wid * 512]);
    gload16(but + (size_t)tt * 12 * 2048, &Bu[b][wid * 512]);
  };
  issue(0); issue(1); issue(2);
  for (int t = 0; t < NT; ++t) {
    int ahead = NT - 1 - t;
    if (ahead >= 2)      asm volatile("s_waitcnt vmcnt(6)" ::: "memory");
    else if (ahead == 1) asm volatile("s_waitcnt vmcnt(3)" ::: "memory");
    else                 asm volatile("s_waitcnt vmcnt(0)" ::: "memory");
    __builtin_amdgcn_s_barrier();
    if (t + 3 < NT) issue(t + 3);
    int cb = t & 3;
    short8 af0 = read_a_frag64(&As[cb][0], lg, wrow + lr);
    short8 af1 = read_a_frag64(&As[cb][0], lg, wrow + 16 + lr);
    #pragma unroll
    for (int nn = 0; nn < 2; ++nn) {
      short8 bgf = read_b_frag(&Bg[cb][0], lg, wcol + nn * 16 + lr);
      short8 buf_ = read_b_frag(&Bu[cb][0], lg, wcol + nn * 16 + lr);
      accg[0][nn] = __builtin_amdgcn_mfma_f32_16x16x32_bf16(af0, bgf, accg[0][nn], 0, 0, 0);
      accg[1][nn] = __builtin_amdgcn_mfma_f32_16x16x32_bf16(af1, bgf, accg[1][nn], 0, 0, 0);
      accu[0][nn] = __builtin_amdgcn_mfma_f32_16x16x32_bf16(af0, buf_, accu[0][nn], 0, 0, 0);
      accu[1][nn] = __builtin_amdgcn_mfma_f32_16x16x32_bf16(af1, buf_, accu[1][nn], 0, 0, 0);
    }
  }
  // epilogue: SiLU*mul -> permuted bf16. col_in_tile = wcol + nn*16 + lr:
  // 32-block = wid&1, hi = nn, g = lr>>2, j = lr&3.
  #pragma unroll
  for (int mm = 0; mm < 2; ++mm)
    #pragma unroll
    for (int nn = 0; nn < 2; ++nn) {
      int pcol = col0 + ((wid & 1) << 5) + ((lr >> 2) << 3) + (nn << 2) + (lr & 3);
      #pragma unroll
      for (int i = 0; i < 4; ++i) {
        int rr = wrow + mm * 16 + lg * 4 + i;
        if (rr < nt) {
          float gv = accg[mm][nn][i], uv = accu[mm][nn][i];
          float av = gv / (1.f + expf(-gv)) * uv;
          actb[(size_t)(start + base + rr) * IMID + pcol] = f2bf(av);
        }
      }
    }
}

// ---------------------------------------------------------------------
// MoE down-proj: BM=64 slots. grid (NEXP, 32, HH/64). Ring-4,
// 2 gloads/thread -> steady vmcnt(4). Writes PARTIAL bf16.
// ---------------------------------------------------------------------
__global__ __launch_bounds__(256) void moe_down_pk(
    const ushort* __restrict__ actb, const ushort* __restrict__ Wpk,
    const int* __restrict__ offs, const int* __restrict__ counts,
    ushort* __restrict__ partialb) {
  int e = blockIdx.x;
  int cnt = counts[e];
  int base = blockIdx.y * 64;
  if (base >= cnt) return;
  int start = offs[e];
  int nt = min(64, cnt - base);
  __shared__ ushort As[4][2048];
  __shared__ ushort Bs[4][2048];
  int tid = threadIdx.x;
  int bz = blockIdx.z, col0 = bz * 64;
  int wid = tid >> 6, lane = tid & 63;
  int lg = lane >> 4, lr = lane & 15;
  int wrow = (wid >> 1) * 32, wcol = (wid & 1) * 32;
  const ushort* bt0 = Wpk + ((size_t)(e * 12) * 16 + bz) * 2048 + wid * 512 + lane * 8;
  const ushort* asrc = actb + (size_t)(start + base + (lane ^ wid)) * IMID + wid * 8;
  const int NT = IMID >> 5;   // 12
  f32x4 acc[2][2] = {};

  auto issue = [&](int tt) {
    int b = tt & 3;
    gload16(asrc + tt * 32, &As[b][wid * 512]);
    gload16(bt0 + (size_t)tt * 16 * 2048, &Bs[b][wid * 512]);
  };
  issue(0); issue(1); issue(2);
  for (int t = 0; t < NT; ++t) {
    int ahead = NT - 1 - t;
    if (ahead >= 2)      asm volatile("s_waitcnt vmcnt(4)" ::: "memory");
    else if (ahead == 1) asm volatile("s_waitcnt vmcnt(2)" ::: "memory");
    else                 asm volatile("s_waitcnt vmcnt(0)" ::: "memory");
    __builtin_amdgcn_s_barrier();
    if (t + 3 < NT) issue(t + 3);
    int cb = t & 3;
    short8 af0 = read_a_frag64(&As[cb][0], lg, wrow + lr);
    short8 af1 = read_a_frag64(&As[cb][0], lg, wrow + 16 + lr);
    #pragma unroll
    for (int nn = 0; nn < 2; ++nn) {
      short8 bf_ = read_b_frag(&Bs[cb][0], lg, wcol + nn * 16 + lr);
      acc[0][nn] = __builtin_amdgcn_mfma_f32_16x16x32_bf16(af0, bf_, acc[0][nn], 0, 0, 0);
      acc[1][nn] = __builtin_amdgcn_mfma_f32_16x16x32_bf16(af1, bf_, acc[1][nn], 0, 0, 0);
    }
  }
  #pragma unroll
  for (int mm = 0; mm < 2; ++mm)
    #pragma unroll
    for (int nn = 0; nn < 2; ++nn)
      #pragma unroll
      for (int i = 0; i < 4; ++i) {
        int rr = wrow + mm * 16 + lg * 4 + i;
        if (rr < nt)
          partialb[(size_t)(start + base + rr) * HH + col0 + wcol + nn * 16 + lr] = f2bf(acc[mm][nn][i]);
      }
}

// =====================================================================
// residual add + RMSNorm; emits f32 sum, f32 ln, permuted bf16 ln.
// =====================================================================
__global__ __launch_bounds__(256) void add_rms_kernel(
    const float* __restrict__ a, const float* __restrict__ b,
    const float* __restrict__ w, float* __restrict__ sum_out,
    float* __restrict__ ln_out, ushort* __restrict__ lnb) {
  int t = blockIdx.x, tid = threadIdx.x;
  float4 x = reinterpret_cast<const float4*>(a + (size_t)t*HH)[tid];
  float4 y = reinterpret_cast<const float4*>(b + (size_t)t*HH)[tid];
  x.x += y.x; x.y += y.y; x.z += y.z; x.w += y.w;
  float ss = x.x*x.x + x.y*x.y + x.z*x.z + x.w*x.w;
  #pragma unroll
  for (int off = 1; off < 64; off <<= 1) ss += __shfl_xor(ss, off);
  __shared__ float wsum[4];
  int wid = tid >> 6, lane = tid & 63;
  if (lane == 0) wsum[wid] = ss;
  __syncthreads();
  float tot = wsum[0] + wsum[1] + wsum[2] + wsum[3];
  float r = rsqrtf(tot * (1.0f/HH) + EPS_);
  reinterpret_cast<float4*>(sum_out + (size_t)t*HH)[tid] = x;
  float4 wl = reinterpret_cast<const float4*>(w)[tid];
  float4 o = make_float4(x.x*r*wl.x, x.y*r*wl.y, x.z*r*wl.z, x.w*r*wl.w);
  reinterpret_cast<float4*>(ln_out + (size_t)t*HH)[tid] = o;
  ushort4 ub;
  ub.x = f2bf(o.x); ub.y = f2bf(o.y); ub.z = f2bf(o.z); ub.w = f2bf(o.w);
  int dst = ((tid >> 3) << 5) + ((tid & 3) << 3) + (((tid >> 2) & 1) << 2);
  *(ushort4*)(lnb + (size_t)t * HH + dst) = ub;
}

// =====================================================================
// per-(t,head) QK RMSNorm + RoPE, in-place (f32)
// =====================================================================
__global__ __launch_bounds__(256) void qk_norm_rope_kernel(
    float* __restrict__ qkv, const float* __restrict__ qw,
    const float* __restrict__ kw, const int* __restrict__ pos) {
  int t = blockIdx.x;
  int hh = blockIdx.y * 4 + (threadIdx.x >> 6);
  int lane = threadIdx.x & 63;
  float* p = qkv + (size_t)t * QKV_W + hh * HDIM;
  float x = p[lane];
  float ss = x * x;
  #pragma unroll
  for (int off = 1; off < 64; off <<= 1) ss += __shfl_xor(ss, off);
  float r = rsqrtf(ss * (1.0f/HDIM) + EPS_);
  float wv = (hh < NHEADS ? qw : kw)[lane];
  float xn = x * r * wv;
  float partner = __shfl_xor(xn, 16);
  float out = xn;
  if (lane < 32) {
    int i = lane & 15;
    float inv = powf(10000.0f, -(float)i / 16.0f);
    float ang = (float)pos[t] * inv;
    float cv = cosf(ang), sv = sinf(ang);
    out = (lane < 16) ? (xn * cv - partner * sv) : (partner * sv + xn * cv);
  }
  p[lane] = out;
}

// =====================================================================
// pack_KV: rope'd K -> A-tile images; V -> B-tile images. grid (T/32, NKVH)
// (K A-tile here is 32-row x 64-dim = two 32-dim chunks of 1024 ushorts)
// =====================================================================
__global__ __launch_bounds__(256) void pack_KV_kernel(
    const float* __restrict__ qkv, ushort* __restrict__ Kpk,
    ushort* __restrict__ Vpk) {
  __shared__ ushort kimg[2048];
  __shared__ ushort vimg[2048];
  int tid = threadIdx.x;
  int kt = blockIdx.x, kvh = blockIdx.y;
  {
    int c = tid >> 7, t2 = tid & 127;
    int g = t2 & 3, r = t2 >> 2;
    const float* kp = qkv + (size_t)(kt*32 + r) * QKV_W + NHEADS*HDIM + kvh*HDIM + 32*c + 4*g;
    float4 h0 = *(const float4*)kp;
    float4 h1 = *(const float4*)(kp + 16);
    short8 v;
    v[0]=(short)f2bf(h0.x); v[1]=(short)f2bf(h0.y); v[2]=(short)f2bf(h0.z); v[3]=(short)f2bf(h0.w);
    v[4]=(short)f2bf(h1.x); v[5]=(short)f2bf(h1.y); v[6]=(short)f2bf(h1.z); v[7]=(short)f2bf(h1.w);
    *(short8*)(kimg + c*1024 + (g*32 + (r^g))*8) = v;
  }
  stage_B_tile(qkv + (size_t)(NHEADS+NKVH)*HDIM + (size_t)kvh*HDIM, QKV_W, kt*32, 0, vimg, tid);
  __syncthreads();
  size_t toff = ((size_t)(kvh * (TT/32) + kt)) * 2048;
  *(short8*)(Kpk + toff + tid * 8) = *(const short8*)(kimg + tid * 8);
  *(short8*)(Vpk + toff + tid * 8) = *(const short8*)(vimg + tid * 8);
}

// =====================================================================
// Attention v2 (r9 verified): packed K/V, ring-3 gload pipeline, log2
// softmax with pre-scaled Q, diagonal-only masking, defer-max.
// grid (NHEADS, 32). Output permuted bf16.
// =====================================================================
__global__ __launch_bounds__(256) void attn_v2_kernel(
    const float* __restrict__ qkv, const ushort* __restrict__ Kpk,
    const ushort* __restrict__ Vpk, ushort* __restrict__ ob) {
  __shared__ ushort Ks[3][2048];
  __shared__ ushort Vs[3][2048];
  int tid = threadIdx.x;
  int wid = tid >> 6, lane = tid & 63;
  int lg = lane >> 4, lr = lane & 15;
  int h = blockIdx.x;
  int qbr = blockIdx.y;
  int qb = (qbr < 16) ? qbr : 47 - qbr;
  int kvh = h >> 2;
  int q0 = qb * 64 + wid * 16;
  int qg = q0 + lr;
  const float SCL = 0.125f * 1.44269504f;

  const float* qrow = qkv + (size_t)qg * QKV_W + h * HDIM;
  short8 qfr[2];
  #pragma unroll
  for (int c = 0; c < 2; ++c) {
    float4 a = *(const float4*)(qrow + 32*c + 4*lg);
    float4 b = *(const float4*)(qrow + 32*c + 4*lg + 16);
    short8 v;
    v[0]=(short)f2bf(a.x*SCL); v[1]=(short)f2bf(a.y*SCL); v[2]=(short)f2bf(a.z*SCL); v[3]=(short)f2bf(a.w*SCL);
    v[4]=(short)f2bf(b.x*SCL); v[5]=(short)f2bf(b.y*SCL); v[6]=(short)f2bf(b.z*SCL); v[7]=(short)f2bf(b.w*SCL);
    qfr[c] = v;
  }

  int nkv = qb * 2 + 2;
  const ushort* ksrc = Kpk + (size_t)(kvh * (TT/32)) * 2048 + wid * 512 + lane * 8;
  const ushort* vsrc = Vpk + (size_t)(kvh * (TT/32)) * 2048 + wid * 512 + lane * 8;

  f32x4 o_acc[4] = {};
  float m_st = -1e30f, l_st = 0.f;

  auto issue = [&](int tt) {
    int b = tt % 3;
    gload16(ksrc + (size_t)tt * 2048, &Ks[b][wid * 512]);
    gload16(vsrc + (size_t)tt * 2048, &Vs[b][wid * 512]);
  };
  issue(0);
  issue(1);
  for (int t = 0; t < nkv; ++t) {
    if (t < nkv - 1) asm volatile("s_waitcnt vmcnt(2)" ::: "memory");
    else             asm volatile("s_waitcnt vmcnt(0)" ::: "memory");
    __builtin_amdgcn_s_barrier();
    if (t + 2 < nkv) issue(t + 2);
    if (t * 32 > q0 + 15) continue;
    int cb = t % 3;
    f32x4 st[2];
    #pragma unroll
    for (int n = 0; n < 2; ++n) {
      short8 kf0 = *(const short8*)(&Ks[cb][(lg*32 + ((16*n + lr) ^ lg)) * 8]);
      short8 kf1 = *(const short8*)(&Ks[cb][1024 + (lg*32 + ((16*n + lr) ^ lg)) * 8]);
      f32x4 z = {};
      z = __builtin_amdgcn_mfma_f32_16x16x32_bf16(kf0, qfr[0], z, 0, 0, 0);
      st[n] = __builtin_amdgcn_mfma_f32_16x16x32_bf16(kf1, qfr[1], z, 0, 0, 0);
    }
    float s[2][4];
    if (t * 32 + 31 <= q0) {
      #pragma unroll
      for (int n = 0; n < 2; ++n)
        #pragma unroll
        for (int i = 0; i < 4; ++i) s[n][i] = st[n][i];
    } else {
      #pragma unroll
      for (int n = 0; n < 2; ++n)
        #pragma unroll
        for (int i = 0; i < 4; ++i) {
          int kvg = t*32 + 16*n + 4*lg + i;
          s[n][i] = (kvg <= qg) ? st[n][i] : -1e30f;
        }
    }
    float tmax = s[0][0];
    #pragma unroll
    for (int n = 0; n < 2; ++n)
      #pragma unroll
      for (int i = 0; i < 4; ++i) tmax = fmaxf(tmax, s[n][i]);
    tmax = fmaxf(tmax, __shfl_xor(tmax, 16));
    tmax = fmaxf(tmax, __shfl_xor(tmax, 32));
    float p[2][4];
    if (__all(tmax - m_st <= 12.0f)) {
      float psum = 0.f;
      #pragma unroll
      for (int n = 0; n < 2; ++n)
        #pragma unroll
        for (int i = 0; i < 4; ++i) { float pv = exp2f(s[n][i] - m_st); p[n][i] = pv; psum += pv; }
      psum += __shfl_xor(psum, 16);
      psum += __shfl_xor(psum, 32);
      l_st += psum;
    } else {
      float m_new = fmaxf(m_st, tmax);
      float corr = exp2f(m_st - m_new);
      float psum = 0.f;
      #pragma unroll
      for (int n = 0; n < 2; ++n)
        #pragma unroll
        for (int i = 0; i < 4; ++i) { float pv = exp2f(s[n][i] - m_new); p[n][i] = pv; psum += pv; }
      psum += __shfl_xor(psum, 16);
      psum += __shfl_xor(psum, 32);
      l_st = l_st * corr + psum;
      m_st = m_new;
      #pragma unroll
      for (int i = 0; i < 4; ++i) {
        float oc = __shfl(corr, 4*lg + i);
        #pragma unroll
        for (int nd = 0; nd < 4; ++nd) o_acc[nd][i] *= oc;
      }
    }
    union { unsigned u[4]; short8 s8; } pu;
    asm volatile("v_cvt_pk_bf16_f32 %0, %1, %2" : "=v"(pu.u[0]) : "v"(p[0][0]), "v"(p[0][1]));
    asm volatile("v_cvt_pk_bf16_f32 %0, %1, %2" : "=v"(pu.u[1]) : "v"(p[0][2]), "v"(p[0][3]));
    asm volatile("v_cvt_pk_bf16_f32 %0, %1, %2" : "=v"(pu.u[2]) : "v"(p[1][0]), "v"(p[1][1]));
    asm volatile("v_cvt_pk_bf16_f32 %0, %1, %2" : "=v"(pu.u[3]) : "v"(p[1][2]), "v"(p[1][3]));
    short8 pa = pu.s8;
    #pragma unroll
    for (int nd = 0; nd < 4; ++nd) {
      short8 vf = read_b_frag(&Vs[cb][0], lg, 16*nd + lr);
      o_acc[nd] = __builtin_amdgcn_mfma_f32_16x16x32_bf16(pa, vf, o_acc[nd], 0, 0, 0);
    }
  }

  #pragma unroll
  for (int i = 0; i < 4; ++i) {
    float lrow = __shfl(l_st, 4*lg + i);
    float inv = 1.0f / lrow;
    int row = q0 + 4*lg + i;
    ushort* op = ob + (size_t)row * (NHEADS*HDIM) + h * HDIM;
    #pragma unroll
    for (int nd = 0; nd < 4; ++nd) {
      int pcol = ((nd >> 1) << 5) + ((lr >> 2) << 3) + ((nd & 1) << 2) + (lr & 3);
      op[pcol] = f2bf(o_acc[nd][i] * inv);
    }
  }
}

// =====================================================================
// router: wave-parallel (r8 verified)
// =====================================================================
__global__ __launch_bounds__(256) void router_kernel(
    const float* __restrict__ hln, const float* __restrict__ Wg,
    const float* __restrict__ bias, int* __restrict__ sel_e,
    float* __restrict__ sel_w) {
  __shared__ float hid[4][HH];
  int tid = threadIdx.x, wid = tid >> 6, lane = tid & 63;
  int t = blockIdx.x * 4 + wid;
  const float4* src = (const float4*)(hln + (size_t)t * HH);
  float4* dst = (float4*)hid[wid];
  #pragma unroll
  for (int j = 0; j < 4; ++j) dst[j * 64 + lane] = src[j * 64 + lane];
  int e = lane & 31, half = lane >> 5;
  const float* wp = Wg + (size_t)(half * 512) * NEXP + e;
  const float* hp = hid[wid] + half * 512;
  float p = 0.f;
  #pragma unroll 8
  for (int h = 0; h < 512; ++h) p += hp[h] * wp[(size_t)h * NEXP];
  p += __shfl_xor(p, 32);
  float sc = 1.0f / (1.0f + expf(-p));
  float sfc = sc + bias[e];
  float m1 = sfc, m2 = -1e30f;
  #pragma unroll
  for (int off = 1; off <= 4; off <<= 1) {
    float om1 = __shfl_xor(m1, off), om2 = __shfl_xor(m2, off);
    float hi_ = fmaxf(m1, om1);
    float lo_ = fmaxf(fminf(m1, om1), fmaxf(m2, om2));
    m1 = hi_; m2 = lo_;
  }
  float gs = m1 + m2;
  float gv[4] = {__shfl(gs, 0), __shfl(gs, 8), __shfl(gs, 16), __shfl(gs, 24)};
  int g1 = 0; float b1 = gv[0];
  #pragma unroll
  for (int g = 1; g < 4; ++g) if (gv[g] > b1) { b1 = gv[g]; g1 = g; }
  int g2 = -1; float b2 = -1e30f;
  #pragma unroll
  for (int g = 0; g < 4; ++g) if (g != g1 && gv[g] > b2) { b2 = gv[g]; g2 = g; }
  bool keep = ((e >> 3) == g1) || ((e >> 3) == g2);
  float cand = keep ? sfc : -1e30f;
  int ids[4]; float wv[4]; float wsum = 0.f;
  #pragma unroll
  for (int s = 0; s < 4; ++s) {
    float v = cand; int ix = e;
    #pragma unroll
    for (int off = 1; off < 64; off <<= 1) {
      float ov = __shfl_xor(v, off); int oix = __shfl_xor(ix, off);
      if (ov > v || (ov == v && oix < ix)) { v = ov; ix = oix; }
    }
    ids[s] = ix;
    if (e == ix) cand = -1e30f;
    float w = __shfl(sc, ix);
    wv[s] = w; wsum += w;
  }
  if (lane == 0) {
    #pragma unroll
    for (int s = 0; s < 4; ++s) {
      sel_e[t * 4 + s] = ids[s];
      sel_w[t * 4 + s] = wv[s] / wsum;
    }
  }
}

__global__ __launch_bounds__(256) void count_kernel(
    const int* __restrict__ sel_e, int* __restrict__ counts) {
  int e = blockIdx.x, tid = threadIdx.x;
  int c = 0;
  for (int i = tid; i < TT * TOPK_; i += 256) c += (sel_e[i] == e);
  #pragma unroll
  for (int off = 1; off < 64; off <<= 1) c += __shfl_xor(c, off);
  __shared__ int wsum[4];
  if ((tid & 63) == 0) wsum[tid >> 6] = c;
  __syncthreads();
  if (tid == 0) counts[e] = wsum[0] + wsum[1] + wsum[2] + wsum[3];
}

__global__ void scan_kernel(const int* __restrict__ counts,
                            int* __restrict__ offs, int* __restrict__ cursor) {
  if (threadIdx.x == 0) {
    int acc = 0;
    for (int e = 0; e < NEXP; ++e) { offs[e] = acc; cursor[e] = acc; acc += counts[e]; }
  }
}

__global__ void scatter_kernel(const int* __restrict__ sel_e,
                               int* __restrict__ cursor, int* __restrict__ perm,
                               int* __restrict__ ipos) {
  int i = blockIdx.x * 256 + threadIdx.x;
  if (i < TT * TOPK_) {
    int e = sel_e[i];
    int pos = atomicAdd(&cursor[e], 1);
    perm[pos] = i;
    ipos[i] = pos;
  }
}

// =====================================================================
// shared-expert SiLU*mul -> permuted bf16 (4 cols/thread)
// =====================================================================
__global__ __launch_bounds__(256) void silu_shared_kernel(
    const float* __restrict__ gus, ushort* __restrict__ shsb) {
  int i = blockIdx.x * 256 + threadIdx.x;
  if (i < TT * (ISHARED/4)) {
    int t = i / (ISHARED/4), k = i % (ISHARED/4);
    const float* gp = gus + (size_t)t * (2*ISHARED) + k * 4;
    float4 g4 = *(const float4*)gp;
    float4 u4 = *(const float4*)(gp + ISHARED);
    ushort4 r;
    r.x = f2bf(g4.x / (1.f + expf(-g4.x)) * u4.x);
    r.y = f2bf(g4.y / (1.f + expf(-g4.y)) * u4.y);
    r.z = f2bf(g4.z / (1.f + expf(-g4.z)) * u4.z);
    r.w = f2bf(g4.w / (1.f + expf(-g4.w)) * u4.w);
    int pdst = ((k >> 3) << 5) + ((k & 3) << 3) + (((k >> 2) & 1) << 2);
    *(ushort4*)(shsb + (size_t)t * ISHARED + pdst) = r;
  }
}

// =====================================================================
// final combine (bf16 partial)
// =====================================================================
__global__ __launch_bounds__(256) void final_combine_kernel(
    const ushort* __restrict__ partialb, const float* __restrict__ sel_w,
    const int* __restrict__ ipos, const float* __restrict__ shared_out,
    float* __restrict__ out_hidden) {
  int t = blockIdx.x, tid = threadIdx.x;
  float w0 = sel_w[t*4], w1 = sel_w[t*4+1], w2 = sel_w[t*4+2], w3 = sel_w[t*4+3];
  int p0 = ipos[t*4], p1 = ipos[t*4+1], p2 = ipos[t*4+2], p3 = ipos[t*4+3];
  ushort4 a0 = *(const ushort4*)(partialb + (size_t)p0*HH + tid*4);
  ushort4 a1 = *(const ushort4*)(partialb + (size_t)p1*HH + tid*4);
  ushort4 a2 = *(const ushort4*)(partialb + (size_t)p2*HH + tid*4);
  ushort4 a3 = *(const ushort4*)(partialb + (size_t)p3*HH + tid*4);
  float4 sh = reinterpret_cast<const float4*>(shared_out + (size_t)t*HH)[tid];
  float4 r;
  r.x = (w0*bf2f(a0.x) + w1*bf2f(a1.x) + w2*bf2f(a2.x) + w3*bf2f(a3.x)) + sh.x;
  r.y = (w0*bf2f(a0.y) + w1*bf2f(a1.y) + w2*bf2f(a2.y) + w3*bf2f(a3.y)) + sh.y;
  r.z = (w0*bf2f(a0.z) + w1*bf2f(a1.z) + w2*bf2f(a2.z) + w3*bf2f(a3.z)) + sh.z;
  r.w = (w0*bf2f(a0.w) + w1*bf2f(a1.w) + w2*bf2f(a2.w) + w3*bf2f(a3.w)) + sh.w;
  reinterpret_cast<float4*>(out_hidden + (size_t)t*HH)[tid] = r;
}

// =====================================================================
extern "C" void kernel_launch(void* const* d_in, const int* in_sizes, int n_in,
                              void* d_out, int out_size, void* d_ws, size_t ws_size,
                              hipStream_t stream) {
  const float* hidden   = (const float*)d_in[0];
  const float* residual = (const float*)d_in[1];
  const float* in_ln_w  = (const float*)d_in[2];
  const float* post_ln_w= (const float*)d_in[3];
  const float* q_norm_w = (const float*)d_in[4];
  const float* k_norm_w = (const float*)d_in[5];
  const float* Wqkv     = (const float*)d_in[6];
  const float* Wo       = (const float*)d_in[7];
  const float* Wg       = (const float*)d_in[8];
  const float* gate_bias= (const float*)d_in[9];
  const float* Wgu      = (const float*)d_in[10];
  const float* Wd       = (const float*)d_in[11];
  const float* Wgu_sh   = (const float*)d_in[12];
  const float* Wd_sh    = (const float*)d_in[13];
  const int*   positions= (const int*)d_in[14];
  float* out = (float*)d_out;

  float* f = (float*)d_ws;
  size_t off = 0;
  float* R_A   = f + off; off += (size_t)TT*HH;
  float* HLN   = f + off; off += (size_t)TT*HH;
  float* QKV   = f + off; off += (size_t)TT*QKV_W;        // reused as gus
  float* OATT  = f + off; off += (size_t)TT*HH;           // DSH output (shared_out)
  float* HLN2  = f + off; off += (size_t)TT*HH;
  float* SELW  = f + off; off += (size_t)TT*TOPK_;
  ushort* HLNB  = (ushort*)(f + off); off += (size_t)TT*HH/2;
  ushort* HLN2B = (ushort*)(f + off); off += (size_t)TT*HH/2;
  ushort* OATTB = (ushort*)(f + off); off += (size_t)TT*HH/2;
  ushort* SHSB  = (ushort*)(f + off); off += (size_t)TT*ISHARED/2;
  ushort* KPK   = (ushort*)(f + off); off += (size_t)NKVH*(TT/32)*2048/2;
  ushort* VPK   = (ushort*)(f + off); off += (size_t)NKVH*(TT/32)*2048/2;
  ushort* ACTB  = (ushort*)(f + off); off += (size_t)(TT*TOPK_ + 128)*IMID/2;
  ushort* PARTB = (ushort*)(f + off); off += (size_t)TT*TOPK_*HH/2;
  ushort* PK_QKV = (ushort*)(f + off); off += (size_t)HH*QKV_W/2;
  ushort* PK_WO  = (ushort*)(f + off); off += (size_t)HH*HH/2;
  ushort* PK_WGU = (ushort*)(f + off); off += (size_t)NEXP*HH*(2*IMID)/2;
  ushort* PK_WD  = (ushort*)(f + off); off += (size_t)NEXP*IMID*HH/2;
  ushort* PK_GUSH= (ushort*)(f + off); off += (size_t)HH*(2*ISHARED)/2;
  ushort* PK_DSH = (ushort*)(f + off); off += (size_t)ISHARED*HH/2;
  int* ibase   = (int*)(f + off);
  int* SELE    = ibase;
  int* PERM    = ibase + TT*TOPK_;
  int* IPOS    = ibase + 2*TT*TOPK_;
  int* COUNTS  = ibase + 3*TT*TOPK_;
  int* OFFS    = COUNTS + NEXP;
  int* CURSOR  = OFFS + NEXP;

  // 0. pack all weights to bf16 tile images
  pack_B_kernel<<<dim3(QKV_W/64, HH/32), 256, 0, stream>>>(Wqkv, PK_QKV, QKV_W);
  pack_B_kernel<<<dim3(HH/64, HH/32), 256, 0, stream>>>(Wo, PK_WO, HH);
  pack_B_kernel<<<dim3((2*IMID)/64, NEXP*HH/32), 256, 0, stream>>>(Wgu, PK_WGU, 2*IMID);
  pack_B_kernel<<<dim3(HH/64, NEXP*IMID/32), 256, 0, stream>>>(Wd, PK_WD, HH);
  pack_B_kernel<<<dim3((2*ISHARED)/64, HH/32), 256, 0, stream>>>(Wgu_sh, PK_GUSH, 2*ISHARED);
  pack_B_kernel<<<dim3(HH/64, ISHARED/32), 256, 0, stream>>>(Wd_sh, PK_DSH, HH);

  // 1. pipeline
  add_rms_kernel<<<TT, 256, 0, stream>>>(hidden, residual, in_ln_w, R_A, HLN, HLNB);
  gemm64_bb<<<dim3(QKV_W/64, TT/64), 256, 0, stream>>>(HLNB, PK_QKV, QKV, TT, QKV_W, HH);
  qk_norm_rope_kernel<<<dim3(TT, 5), 256, 0, stream>>>(QKV, q_norm_w, k_norm_w, positions);
  pack_KV_kernel<<<dim3(TT/32, NKVH), 256, 0, stream>>>(QKV, KPK, VPK);
  attn_v2_kernel<<<dim3(NHEADS, 32), 256, 0, stream>>>(QKV, KPK, VPK, OATTB);
  gemm64_bb<<<dim3(HH/64, TT/64), 256, 0, stream>>>(OATTB, PK_WO, HLN, TT, HH, HH);
  add_rms_kernel<<<TT, 256, 0, stream>>>(HLN, R_A, post_ln_w, out + (size_t)TT*HH, HLN2, HLN2B);
  router_kernel<<<TT/4, 256, 0, stream>>>(HLN2, Wg, gate_bias, SELE, SELW);
  count_kernel<<<NEXP, 256, 0, stream>>>(SELE, COUNTS);
  scan_kernel<<<1, 64, 0, stream>>>(COUNTS, OFFS, CURSOR);
  scatter_kernel<<<(TT*TOPK_ + 255)/256, 256, 0, stream>>>(SELE, CURSOR, PERM, IPOS);
  moe_up_pk<<<dim3(NEXP, 32, IMID/64), 256, 0, stream>>>(HLN2B, PK_WGU, PERM, OFFS, COUNTS, ACTB);
  moe_down_pk<<<dim3(NEXP, 32, HH/64), 256, 0, stream>>>(ACTB, PK_WD, OFFS, COUNTS, PARTB);
  gemm64_bb<<<dim3((2*ISHARED)/64, TT/64), 256, 0, stream>>>(HLN2B, PK_GUSH, QKV, TT, 2*ISHARED, HH);
  silu_shared_kernel<<<(TT*(ISHARED/4) + 255)/256, 256, 0, stream>>>(QKV, SHSB);
  gemm64_bb<<<dim3(HH/64, TT/64), 256, 0, stream>>>(SHSB, PK_DSH, OATT, TT, HH, ISHARED);
  final_combine_kernel<<<TT, 256, 0, stream>>>(PARTB, SELW, IPOS, OATT, out);
}

// Round 11
// 384.434 us; speedup vs baseline: 1.2558x; 1.0418x over previous
//
#include <hip/hip_runtime.h>
#include <math.h>

// ---- problem constants ----
#define TT 2048
#define HH 1024
#define NHEADS 16
#define NKVH 4
#define HDIM 64
#define NEXP 32
#define TOPK_ 4
#define NGRP 4
#define IMID 384
#define ISHARED 384
#define QKV_W (24*64)   // 1536
#define EPS_ 1e-5f
#define MAXSB 288       // max slot-blocks: 8192/32 + 32

typedef __attribute__((ext_vector_type(8))) short short8;
typedef __attribute__((ext_vector_type(4))) float f32x4;

__device__ __forceinline__ ushort f2bf(float x) {
  union { float f; unsigned u; } v; v.f = x;
  unsigned r = v.u + 0x7fffu + ((v.u >> 16) & 1u);
  return (ushort)(r >> 16);
}
__device__ __forceinline__ float bf2f(ushort u) {
  union { unsigned i; float f; } v; v.i = (unsigned)u << 16; return v.f;
}

// async global->LDS, 16B per lane; lds dst = wave-uniform base + lane*16
__device__ __forceinline__ void gload16(const void* g, void* l) {
  __builtin_amdgcn_global_load_lds(
      (const __attribute__((address_space(1))) unsigned int*)g,
      (__attribute__((address_space(3))) unsigned int*)l, 16, 0, 0);
}

// =====================================================================
// MFMA fragment layouts (16x16x32 bf16), verified rounds 1-10:
//   A-frag lane l: A[row=l&15][k in {4g+j, 16+4g+j}], g=l>>4
//   B-frag lane l: B[k in {4g+j, 16+4g+j}][col=l&15]
//   C lane l: C[row=(l>>4)*4+i][col=l&15]
// A LDS plane (32-row): [g][32 rows][8] with row^g swizzle; plane g at
//   ushort offset g*256. Waves 0-1 stage: lane l of wave w covers plane
//   g = w*2+(l>>5), slot x=l&31 (holds row x^g) -> per-lane source
//   row (l&31)^g, 16 contiguous bytes (permuted activation layout).
// A LDS plane (64-row, dense gemm): [g][64][8], row^g swizzle.
// B LDS plane: 4 planes x 1024B, 16B-granular column XOR swizzle (4 KB).
// Permuted activation row layout (bf16): within each 32-col block,
// position g*8 + hi*4 + j holds original col 4g + 16*hi + j.
// =====================================================================
__device__ __forceinline__ short8 read_a_frag32(const ushort* As, int lg, int row) {
  return *(const short8*)(As + ((lg * 32 + (row ^ lg)) * 8));
}
__device__ __forceinline__ short8 read_a_frag64(const ushort* As, int lg, int row) {
  return *(const short8*)(As + ((lg * 64 + (row ^ lg)) * 8));
}
__device__ __forceinline__ short8 read_b_frag(const ushort* Bs, int lg, int col) {
  int boff = (col * 16) ^ (((col >> 3) & 7) << 4);
  return *(const short8*)((const char*)Bs + lg * 1024 + boff);
}

// B-tile staging from f32 (pack kernels only)
__device__ __forceinline__ void stage_B_tile(const float* __restrict__ B, int ldb,
                                             int k0, int col0, ushort* Bs, int tid) {
  int a = tid >> 4;
  int cG = tid & 15;
  int k = 2 * a;
  const float* p0 = B + (size_t)(k0 + k) * ldb + col0 + cG * 4;
  const float* p1 = p0 + ldb;
  float4 r0 = *(const float4*)p0;
  float4 r1 = *(const float4*)p1;
  int gg = (k & 15) >> 2;
  int slot = (k & 3) + ((k >> 4) << 2);
  float v0[4] = {r0.x, r0.y, r0.z, r0.w};
  float v1[4] = {r1.x, r1.y, r1.z, r1.w};
  char* plane = (char*)Bs + gg * 1024;
  #pragma unroll
  for (int j = 0; j < 4; ++j) {
    int c = cG * 4 + j;
    unsigned pk = (unsigned)f2bf(v0[j]) | ((unsigned)f2bf(v1[j]) << 16);
    int boff = ((c * 16) ^ (((c >> 3) & 7) << 4)) + slot * 2;
    *(unsigned*)(plane + boff) = pk;
  }
}

// ---------------------------------------------------------------------
// Pack kernel: f32 KxN matrix -> bf16 pre-swizzled B-tile images.
// ---------------------------------------------------------------------
__global__ __launch_bounds__(256) void pack_B_kernel(
    const float* __restrict__ src, ushort* __restrict__ dst, int N) {
  __shared__ ushort tileB[2048];
  int tid = threadIdx.x;
  stage_B_tile(src, N, blockIdx.y * 32, blockIdx.x * 64, tileB, tid);
  __syncthreads();
  size_t toff = ((size_t)blockIdx.y * gridDim.x + blockIdx.x) * 2048;
  *(short8*)(dst + toff + tid * 8) = *(const short8*)(tileB + tid * 8);
}

// ---------------------------------------------------------------------
// Dense GEMM (r10 verified): BM=64, BN=64, ring-4, dist-3.
// ---------------------------------------------------------------------
__global__ __launch_bounds__(256) void gemm64_bb(
    const ushort* __restrict__ Ab, const ushort* __restrict__ Bpk,
    float* __restrict__ C, int M, int N, int K) {
  __shared__ ushort As[4][2048];
  __shared__ ushort Bs[4][2048];
  int tid = threadIdx.x;
  int row0 = blockIdx.y * 64, col0 = blockIdx.x * 64;
  int ntn = N >> 6;
  int wid = tid >> 6, lane = tid & 63;
  int lg = lane >> 4, lr = lane & 15;
  int wrow = (wid >> 1) * 32, wcol = (wid & 1) * 32;
  const ushort* asrc = Ab + (size_t)(row0 + (lane ^ wid)) * K + wid * 8;
  const ushort* bsrc = Bpk + (size_t)blockIdx.x * 2048 + wid * 512 + lane * 8;
  const int NT = K >> 5;
  f32x4 acc[2][2] = {};

  auto issue = [&](int tt) {
    int b = tt & 3;
    gload16(asrc + tt * 32, &As[b][wid * 512]);
    gload16(bsrc + (size_t)tt * ntn * 2048, &Bs[b][wid * 512]);
  };
  issue(0); issue(1); issue(2);
  for (int t = 0; t < NT; ++t) {
    int ahead = NT - 1 - t;
    if (ahead >= 2)      asm volatile("s_waitcnt vmcnt(4)" ::: "memory");
    else if (ahead == 1) asm volatile("s_waitcnt vmcnt(2)" ::: "memory");
    else                 asm volatile("s_waitcnt vmcnt(0)" ::: "memory");
    __builtin_amdgcn_s_barrier();
    if (t + 3 < NT) issue(t + 3);
    int cb = t & 3;
    short8 af0 = read_a_frag64(&As[cb][0], lg, wrow + lr);
    short8 af1 = read_a_frag64(&As[cb][0], lg, wrow + 16 + lr);
    #pragma unroll
    for (int nn = 0; nn < 2; ++nn) {
      short8 bf_ = read_b_frag(&Bs[cb][0], lg, wcol + nn * 16 + lr);
      acc[0][nn] = __builtin_amdgcn_mfma_f32_16x16x32_bf16(af0, bf_, acc[0][nn], 0, 0, 0);
      acc[1][nn] = __builtin_amdgcn_mfma_f32_16x16x32_bf16(af1, bf_, acc[1][nn], 0, 0, 0);
    }
  }
  #pragma unroll
  for (int mm = 0; mm < 2; ++mm)
    #pragma unroll
    for (int nn = 0; nn < 2; ++nn) {
      int row = row0 + wrow + mm * 16 + lg * 4;
      int col = col0 + wcol + nn * 16 + lr;
      #pragma unroll
      for (int i = 0; i < 4; ++i)
        C[(size_t)(row + i) * N + col] = acc[mm][nn][i];
    }
}

// ---------------------------------------------------------------------
// MoE up-proj v3: BM=32 slots, flat slot-block table, ring-3 dist-2.
// grid (MAXSB, IMID/64). Waves 0-1 stage A (3 loads/it), 2-3 only B (2).
// ---------------------------------------------------------------------
__global__ __launch_bounds__(256) void moe_up_pk(
    const ushort* __restrict__ hln2b, const ushort* __restrict__ Wpk,
    const int* __restrict__ perm, const int* __restrict__ offs,
    const int* __restrict__ counts, const int* __restrict__ sb_e,
    const int* __restrict__ sb_base, const int* __restrict__ nsb,
    ushort* __restrict__ actb) {
  int sb = blockIdx.x;
  if (sb >= *nsb) return;
  int e = sb_e[sb];
  int base = sb_base[sb];
  int start = offs[e];
  int nt = min(32, counts[e] - base);
  __shared__ int tokmap[32];
  int tid = threadIdx.x;
  if (tid < 32) tokmap[tid] = perm[start + base + ((tid < nt) ? tid : 0)] >> 2;
  __shared__ ushort As[3][1024];
  __shared__ ushort Bg[3][2048];
  __shared__ ushort Bu[3][2048];
  __syncthreads();
  int bz = blockIdx.y, col0 = bz * 64;
  int wid = tid >> 6, lane = tid & 63;
  int lg = lane >> 4, lr = lane & 15;
  int wrow = (wid >> 1) * 16, wcol = (wid & 1) * 32;
  const ushort* bgt = Wpk + ((size_t)(e * 32) * 12 + bz) * 2048 + wid * 512 + lane * 8;
  const ushort* but = bgt + (size_t)6 * 2048;
  // A source for waves 0-1: plane g = wid*2 + (lane>>5), row (lane&31)^g
  int ga = wid * 2 + (lane >> 5);
  const ushort* asrcA = hln2b + (size_t)tokmap[(lane & 31) ^ ga] * HH + ga * 8;
  const int NT = HH >> 5;   // 32
  f32x4 accg[2] = {}, accu[2] = {};

  auto issue = [&](int tt) {
    int b = tt % 3;
    if (wid < 2) gload16(asrcA + tt * 32, &As[b][wid * 1024 / 2]);
    gload16(bgt + (size_t)tt * 12 * 2048, &Bg[b][wid * 512]);
    gload16(but + (size_t)tt * 12 * 2048, &Bu[b][wid * 512]);
  };
  issue(0); issue(1);
  for (int t = 0; t < NT; ++t) {
    if (t < NT - 1) {
      if (wid < 2) asm volatile("s_waitcnt vmcnt(3)" ::: "memory");
      else         asm volatile("s_waitcnt vmcnt(2)" ::: "memory");
    } else {
      asm volatile("s_waitcnt vmcnt(0)" ::: "memory");
    }
    __builtin_amdgcn_s_barrier();
    if (t + 2 < NT) issue(t + 2);
    int cb = t % 3;
    short8 af = read_a_frag32(&As[cb][0], lg, wrow + lr);
    #pragma unroll
    for (int nn = 0; nn < 2; ++nn) {
      short8 bgf = read_b_frag(&Bg[cb][0], lg, wcol + nn * 16 + lr);
      short8 buf_ = read_b_frag(&Bu[cb][0], lg, wcol + nn * 16 + lr);
      accg[nn] = __builtin_amdgcn_mfma_f32_16x16x32_bf16(af, bgf, accg[nn], 0, 0, 0);
      accu[nn] = __builtin_amdgcn_mfma_f32_16x16x32_bf16(af, buf_, accu[nn], 0, 0, 0);
    }
  }
  // epilogue: SiLU*mul -> permuted bf16
  #pragma unroll
  for (int nn = 0; nn < 2; ++nn) {
    int pcol = col0 + ((wid & 1) << 5) + ((lr >> 2) << 3) + (nn << 2) + (lr & 3);
    #pragma unroll
    for (int i = 0; i < 4; ++i) {
      int rr = wrow + lg * 4 + i;
      if (rr < nt) {
        float gv = accg[nn][i], uv = accu[nn][i];
        float av = gv / (1.f + expf(-gv)) * uv;
        actb[(size_t)(start + base + rr) * IMID + pcol] = f2bf(av);
      }
    }
  }
}

// ---------------------------------------------------------------------
// MoE down-proj v3: BM=32, flat slot-block table, ring-3 dist-2.
// grid (MAXSB, HH/64). Waves 0-1: 2 loads/it; waves 2-3: 1.
// ---------------------------------------------------------------------
__global__ __launch_bounds__(256) void moe_down_pk(
    const ushort* __restrict__ actb, const ushort* __restrict__ Wpk,
    const int* __restrict__ offs, const int* __restrict__ counts,
    const int* __restrict__ sb_e, const int* __restrict__ sb_base,
    const int* __restrict__ nsb, ushort* __restrict__ partialb) {
  int sb = blockIdx.x;
  if (sb >= *nsb) return;
  int e = sb_e[sb];
  int base = sb_base[sb];
  int start = offs[e];
  int nt = min(32, counts[e] - base);
  __shared__ ushort As[3][1024];
  __shared__ ushort Bs[3][2048];
  int tid = threadIdx.x;
  int bz = blockIdx.y, col0 = bz * 64;
  int wid = tid >> 6, lane = tid & 63;
  int lg = lane >> 4, lr = lane & 15;
  int wrow = (wid >> 1) * 16, wcol = (wid & 1) * 32;
  const ushort* bt0 = Wpk + ((size_t)(e * 12) * 16 + bz) * 2048 + wid * 512 + lane * 8;
  int ga = wid * 2 + (lane >> 5);
  const ushort* asrcA = actb + (size_t)(start + base + ((lane & 31) ^ ga)) * IMID + ga * 8;
  const int NT = IMID >> 5;   // 12
  f32x4 acc[2] = {};

  auto issue = [&](int tt) {
    int b = tt % 3;
    if (wid < 2) gload16(asrcA + tt * 32, &As[b][wid * 512]);
    gload16(bt0 + (size_t)tt * 16 * 2048, &Bs[b][wid * 512]);
  };
  issue(0); issue(1);
  for (int t = 0; t < NT; ++t) {
    if (t < NT - 1) {
      if (wid < 2) asm volatile("s_waitcnt vmcnt(2)" ::: "memory");
      else         asm volatile("s_waitcnt vmcnt(1)" ::: "memory");
    } else {
      asm volatile("s_waitcnt vmcnt(0)" ::: "memory");
    }
    __builtin_amdgcn_s_barrier();
    if (t + 2 < NT) issue(t + 2);
    int cb = t % 3;
    short8 af = read_a_frag32(&As[cb][0], lg, wrow + lr);
    #pragma unroll
    for (int nn = 0; nn < 2; ++nn) {
      short8 bf_ = read_b_frag(&Bs[cb][0], lg, wcol + nn * 16 + lr);
      acc[nn] = __builtin_amdgcn_mfma_f32_16x16x32_bf16(af, bf_, acc[nn], 0, 0, 0);
    }
  }
  #pragma unroll
  for (int nn = 0; nn < 2; ++nn)
    #pragma unroll
    for (int i = 0; i < 4; ++i) {
      int rr = wrow + lg * 4 + i;
      if (rr < nt)
        partialb[(size_t)(start + base + rr) * HH + col0 + wcol + nn * 16 + lr] = f2bf(acc[nn][i]);
    }
}

// =====================================================================
// residual add + RMSNorm; emits f32 sum, f32 ln, permuted bf16 ln.
// =====================================================================
__global__ __launch_bounds__(256) void add_rms_kernel(
    const float* __restrict__ a, const float* __restrict__ b,
    const float* __restrict__ w, float* __restrict__ sum_out,
    float* __restrict__ ln_out, ushort* __restrict__ lnb) {
  int t = blockIdx.x, tid = threadIdx.x;
  float4 x = reinterpret_cast<const float4*>(a + (size_t)t*HH)[tid];
  float4 y = reinterpret_cast<const float4*>(b + (size_t)t*HH)[tid];
  x.x += y.x; x.y += y.y; x.z += y.z; x.w += y.w;
  float ss = x.x*x.x + x.y*x.y + x.z*x.z + x.w*x.w;
  #pragma unroll
  for (int off = 1; off < 64; off <<= 1) ss += __shfl_xor(ss, off);
  __shared__ float wsum[4];
  int wid = tid >> 6, lane = tid & 63;
  if (lane == 0) wsum[wid] = ss;
  __syncthreads();
  float tot = wsum[0] + wsum[1] + wsum[2] + wsum[3];
  float r = rsqrtf(tot * (1.0f/HH) + EPS_);
  reinterpret_cast<float4*>(sum_out + (size_t)t*HH)[tid] = x;
  float4 wl = reinterpret_cast<const float4*>(w)[tid];
  float4 o = make_float4(x.x*r*wl.x, x.y*r*wl.y, x.z*r*wl.z, x.w*r*wl.w);
  reinterpret_cast<float4*>(ln_out + (size_t)t*HH)[tid] = o;
  ushort4 ub;
  ub.x = f2bf(o.x); ub.y = f2bf(o.y); ub.z = f2bf(o.z); ub.w = f2bf(o.w);
  int dst = ((tid >> 3) << 5) + ((tid & 3) << 3) + (((tid >> 2) & 1) << 2);
  *(ushort4*)(lnb + (size_t)t * HH + dst) = ub;
}

// =====================================================================
// per-(t,head) QK RMSNorm + RoPE, in-place (f32)
// =====================================================================
__global__ __launch_bounds__(256) void qk_norm_rope_kernel(
    float* __restrict__ qkv, const float* __restrict__ qw,
    const float* __restrict__ kw, const int* __restrict__ pos) {
  int t = blockIdx.x;
  int hh = blockIdx.y * 4 + (threadIdx.x >> 6);
  int lane = threadIdx.x & 63;
  float* p = qkv + (size_t)t * QKV_W + hh * HDIM;
  float x = p[lane];
  float ss = x * x;
  #pragma unroll
  for (int off = 1; off < 64; off <<= 1) ss += __shfl_xor(ss, off);
  float r = rsqrtf(ss * (1.0f/HDIM) + EPS_);
  float wv = (hh < NHEADS ? qw : kw)[lane];
  float xn = x * r * wv;
  float partner = __shfl_xor(xn, 16);
  float out = xn;
  if (lane < 32) {
    int i = lane & 15;
    float inv = powf(10000.0f, -(float)i / 16.0f);
    float ang = (float)pos[t] * inv;
    float cv = cosf(ang), sv = sinf(ang);
    out = (lane < 16) ? (xn * cv - partner * sv) : (partner * sv + xn * cv);
  }
  p[lane] = out;
}

// =====================================================================
// pack_KV: rope'd K -> A-tile images; V -> B-tile images. grid (T/32, NKVH)
// =====================================================================
__global__ __launch_bounds__(256) void pack_KV_kernel(
    const float* __restrict__ qkv, ushort* __restrict__ Kpk,
    ushort* __restrict__ Vpk) {
  __shared__ ushort kimg[2048];
  __shared__ ushort vimg[2048];
  int tid = threadIdx.x;
  int kt = blockIdx.x, kvh = blockIdx.y;
  {
    int c = tid >> 7, t2 = tid & 127;
    int g = t2 & 3, r = t2 >> 2;
    const float* kp = qkv + (size_t)(kt*32 + r) * QKV_W + NHEADS*HDIM + kvh*HDIM + 32*c + 4*g;
    float4 h0 = *(const float4*)kp;
    float4 h1 = *(const float4*)(kp + 16);
    short8 v;
    v[0]=(short)f2bf(h0.x); v[1]=(short)f2bf(h0.y); v[2]=(short)f2bf(h0.z); v[3]=(short)f2bf(h0.w);
    v[4]=(short)f2bf(h1.x); v[5]=(short)f2bf(h1.y); v[6]=(short)f2bf(h1.z); v[7]=(short)f2bf(h1.w);
    *(short8*)(kimg + c*1024 + (g*32 + (r^g))*8) = v;
  }
  stage_B_tile(qkv + (size_t)(NHEADS+NKVH)*HDIM + (size_t)kvh*HDIM, QKV_W, kt*32, 0, vimg, tid);
  __syncthreads();
  size_t toff = ((size_t)(kvh * (TT/32) + kt)) * 2048;
  *(short8*)(Kpk + toff + tid * 8) = *(const short8*)(kimg + tid * 8);
  *(short8*)(Vpk + toff + tid * 8) = *(const short8*)(vimg + tid * 8);
}

// =====================================================================
// Attention v2 (r9 verified): packed K/V, ring-3 gload pipeline, log2
// softmax, diagonal-only masking, defer-max. grid (NHEADS, 32).
// =====================================================================
__global__ __launch_bounds__(256) void attn_v2_kernel(
    const float* __restrict__ qkv, const ushort* __restrict__ Kpk,
    const ushort* __restrict__ Vpk, ushort* __restrict__ ob) {
  __shared__ ushort Ks[3][2048];
  __shared__ ushort Vs[3][2048];
  int tid = threadIdx.x;
  int wid = tid >> 6, lane = tid & 63;
  int lg = lane >> 4, lr = lane & 15;
  int h = blockIdx.x;
  int qbr = blockIdx.y;
  int qb = (qbr < 16) ? qbr : 47 - qbr;
  int kvh = h >> 2;
  int q0 = qb * 64 + wid * 16;
  int qg = q0 + lr;
  const float SCL = 0.125f * 1.44269504f;

  const float* qrow = qkv + (size_t)qg * QKV_W + h * HDIM;
  short8 qfr[2];
  #pragma unroll
  for (int c = 0; c < 2; ++c) {
    float4 a = *(const float4*)(qrow + 32*c + 4*lg);
    float4 b = *(const float4*)(qrow + 32*c + 4*lg + 16);
    short8 v;
    v[0]=(short)f2bf(a.x*SCL); v[1]=(short)f2bf(a.y*SCL); v[2]=(short)f2bf(a.z*SCL); v[3]=(short)f2bf(a.w*SCL);
    v[4]=(short)f2bf(b.x*SCL); v[5]=(short)f2bf(b.y*SCL); v[6]=(short)f2bf(b.z*SCL); v[7]=(short)f2bf(b.w*SCL);
    qfr[c] = v;
  }

  int nkv = qb * 2 + 2;
  const ushort* ksrc = Kpk + (size_t)(kvh * (TT/32)) * 2048 + wid * 512 + lane * 8;
  const ushort* vsrc = Vpk + (size_t)(kvh * (TT/32)) * 2048 + wid * 512 + lane * 8;

  f32x4 o_acc[4] = {};
  float m_st = -1e30f, l_st = 0.f;

  auto issue = [&](int tt) {
    int b = tt % 3;
    gload16(ksrc + (size_t)tt * 2048, &Ks[b][wid * 512]);
    gload16(vsrc + (size_t)tt * 2048, &Vs[b][wid * 512]);
  };
  issue(0);
  issue(1);
  for (int t = 0; t < nkv; ++t) {
    if (t < nkv - 1) asm volatile("s_waitcnt vmcnt(2)" ::: "memory");
    else             asm volatile("s_waitcnt vmcnt(0)" ::: "memory");
    __builtin_amdgcn_s_barrier();
    if (t + 2 < nkv) issue(t + 2);
    if (t * 32 > q0 + 15) continue;
    int cb = t % 3;
    f32x4 st[2];
    #pragma unroll
    for (int n = 0; n < 2; ++n) {
      short8 kf0 = *(const short8*)(&Ks[cb][(lg*32 + ((16*n + lr) ^ lg)) * 8]);
      short8 kf1 = *(const short8*)(&Ks[cb][1024 + (lg*32 + ((16*n + lr) ^ lg)) * 8]);
      f32x4 z = {};
      z = __builtin_amdgcn_mfma_f32_16x16x32_bf16(kf0, qfr[0], z, 0, 0, 0);
      st[n] = __builtin_amdgcn_mfma_f32_16x16x32_bf16(kf1, qfr[1], z, 0, 0, 0);
    }
    float s[2][4];
    if (t * 32 + 31 <= q0) {
      #pragma unroll
      for (int n = 0; n < 2; ++n)
        #pragma unroll
        for (int i = 0; i < 4; ++i) s[n][i] = st[n][i];
    } else {
      #pragma unroll
      for (int n = 0; n < 2; ++n)
        #pragma unroll
        for (int i = 0; i < 4; ++i) {
          int kvg = t*32 + 16*n + 4*lg + i;
          s[n][i] = (kvg <= qg) ? st[n][i] : -1e30f;
        }
    }
    float tmax = s[0][0];
    #pragma unroll
    for (int n = 0; n < 2; ++n)
      #pragma unroll
      for (int i = 0; i < 4; ++i) tmax = fmaxf(tmax, s[n][i]);
    tmax = fmaxf(tmax, __shfl_xor(tmax, 16));
    tmax = fmaxf(tmax, __shfl_xor(tmax, 32));
    float p[2][4];
    if (__all(tmax - m_st <= 12.0f)) {
      float psum = 0.f;
      #pragma unroll
      for (int n = 0; n < 2; ++n)
        #pragma unroll
        for (int i = 0; i < 4; ++i) { float pv = exp2f(s[n][i] - m_st); p[n][i] = pv; psum += pv; }
      psum += __shfl_xor(psum, 16);
      psum += __shfl_xor(psum, 32);
      l_st += psum;
    } else {
      float m_new = fmaxf(m_st, tmax);
      float corr = exp2f(m_st - m_new);
      float psum = 0.f;
      #pragma unroll
      for (int n = 0; n < 2; ++n)
        #pragma unroll
        for (int i = 0; i < 4; ++i) { float pv = exp2f(s[n][i] - m_new); p[n][i] = pv; psum += pv; }
      psum += __shfl_xor(psum, 16);
      psum += __shfl_xor(psum, 32);
      l_st = l_st * corr + psum;
      m_st = m_new;
      #pragma unroll
      for (int i = 0; i < 4; ++i) {
        float oc = __shfl(corr, 4*lg + i);
        #pragma unroll
        for (int nd = 0; nd < 4; ++nd) o_acc[nd][i] *= oc;
      }
    }
    union { unsigned u[4]; short8 s8; } pu;
    asm volatile("v_cvt_pk_bf16_f32 %0, %1, %2" : "=v"(pu.u[0]) : "v"(p[0][0]), "v"(p[0][1]));
    asm volatile("v_cvt_pk_bf16_f32 %0, %1, %2" : "=v"(pu.u[1]) : "v"(p[0][2]), "v"(p[0][3]));
    asm volatile("v_cvt_pk_bf16_f32 %0, %1, %2" : "=v"(pu.u[2]) : "v"(p[1][0]), "v"(p[1][1]));
    asm volatile("v_cvt_pk_bf16_f32 %0, %1, %2" : "=v"(pu.u[3]) : "v"(p[1][2]), "v"(p[1][3]));
    short8 pa = pu.s8;
    #pragma unroll
    for (int nd = 0; nd < 4; ++nd) {
      short8 vf = read_b_frag(&Vs[cb][0], lg, 16*nd + lr);
      o_acc[nd] = __builtin_amdgcn_mfma_f32_16x16x32_bf16(pa, vf, o_acc[nd], 0, 0, 0);
    }
  }

  #pragma unroll
  for (int i = 0; i < 4; ++i) {
    float lrow = __shfl(l_st, 4*lg + i);
    float inv = 1.0f / lrow;
    int row = q0 + 4*lg + i;
    ushort* op = ob + (size_t)row * (NHEADS*HDIM) + h * HDIM;
    #pragma unroll
    for (int nd = 0; nd < 4; ++nd) {
      int pcol = ((nd >> 1) << 5) + ((lr >> 2) << 3) + ((nd & 1) << 2) + (lr & 3);
      op[pcol] = f2bf(o_acc[nd][i] * inv);
    }
  }
}

// =====================================================================
// router: wave-parallel (r8 verified)
// =====================================================================
__global__ __launch_bounds__(256) void router_kernel(
    const float* __restrict__ hln, const float* __restrict__ Wg,
    const float* __restrict__ bias, int* __restrict__ sel_e,
    float* __restrict__ sel_w) {
  __shared__ float hid[4][HH];
  int tid = threadIdx.x, wid = tid >> 6, lane = tid & 63;
  int t = blockIdx.x * 4 + wid;
  const float4* src = (const float4*)(hln + (size_t)t * HH);
  float4* dst = (float4*)hid[wid];
  #pragma unroll
  for (int j = 0; j < 4; ++j) dst[j * 64 + lane] = src[j * 64 + lane];
  int e = lane & 31, half = lane >> 5;
  const float* wp = Wg + (size_t)(half * 512) * NEXP + e;
  const float* hp = hid[wid] + half * 512;
  float p = 0.f;
  #pragma unroll 8
  for (int h = 0; h < 512; ++h) p += hp[h] * wp[(size_t)h * NEXP];
  p += __shfl_xor(p, 32);
  float sc = 1.0f / (1.0f + expf(-p));
  float sfc = sc + bias[e];
  float m1 = sfc, m2 = -1e30f;
  #pragma unroll
  for (int off = 1; off <= 4; off <<= 1) {
    float om1 = __shfl_xor(m1, off), om2 = __shfl_xor(m2, off);
    float hi_ = fmaxf(m1, om1);
    float lo_ = fmaxf(fminf(m1, om1), fmaxf(m2, om2));
    m1 = hi_; m2 = lo_;
  }
  float gs = m1 + m2;
  float gv[4] = {__shfl(gs, 0), __shfl(gs, 8), __shfl(gs, 16), __shfl(gs, 24)};
  int g1 = 0; float b1 = gv[0];
  #pragma unroll
  for (int g = 1; g < 4; ++g) if (gv[g] > b1) { b1 = gv[g]; g1 = g; }
  int g2 = -1; float b2 = -1e30f;
  #pragma unroll
  for (int g = 0; g < 4; ++g) if (g != g1 && gv[g] > b2) { b2 = gv[g]; g2 = g; }
  bool keep = ((e >> 3) == g1) || ((e >> 3) == g2);
  float cand = keep ? sfc : -1e30f;
  int ids[4]; float wv[4]; float wsum = 0.f;
  #pragma unroll
  for (int s = 0; s < 4; ++s) {
    float v = cand; int ix = e;
    #pragma unroll
    for (int off = 1; off < 64; off <<= 1) {
      float ov = __shfl_xor(v, off); int oix = __shfl_xor(ix, off);
      if (ov > v || (ov == v && oix < ix)) { v = ov; ix = oix; }
    }
    ids[s] = ix;
    if (e == ix) cand = -1e30f;
    float w = __shfl(sc, ix);
    wv[s] = w; wsum += w;
  }
  if (lane == 0) {
    #pragma unroll
    for (int s = 0; s < 4; ++s) {
      sel_e[t * 4 + s] = ids[s];
      sel_w[t * 4 + s] = wv[s] / wsum;
    }
  }
}

__global__ __launch_bounds__(256) void count_kernel(
    const int* __restrict__ sel_e, int* __restrict__ counts) {
  int e = blockIdx.x, tid = threadIdx.x;
  int c = 0;
  for (int i = tid; i < TT * TOPK_; i += 256) c += (sel_e[i] == e);
  #pragma unroll
  for (int off = 1; off < 64; off <<= 1) c += __shfl_xor(c, off);
  __shared__ int wsum[4];
  if ((tid & 63) == 0) wsum[tid >> 6] = c;
  __syncthreads();
  if (tid == 0) counts[e] = wsum[0] + wsum[1] + wsum[2] + wsum[3];
}

// scan + flat slot-block table (BM=32 granularity)
__global__ void scan_kernel(const int* __restrict__ counts,
                            int* __restrict__ offs, int* __restrict__ cursor,
                            int* __restrict__ sb_e, int* __restrict__ sb_base,
                            int* __restrict__ nsb) {
  if (threadIdx.x == 0) {
    int acc = 0, n = 0;
    for (int e = 0; e < NEXP; ++e) {
      offs[e] = acc; cursor[e] = acc;
      int c = counts[e];
      for (int b = 0; b < c; b += 32) { sb_e[n] = e; sb_base[n] = b; ++n; }
      acc += c;
    }
    *nsb = n;
  }
}

__global__ void scatter_kernel(const int* __restrict__ sel_e,
                               int* __restrict__ cursor, int* __restrict__ perm,
                               int* __restrict__ ipos) {
  int i = blockIdx.x * 256 + threadIdx.x;
  if (i < TT * TOPK_) {
    int e = sel_e[i];
    int pos = atomicAdd(&cursor[e], 1);
    perm[pos] = i;
    ipos[i] = pos;
  }
}

// =====================================================================
// shared-expert SiLU*mul -> permuted bf16 (4 cols/thread)
// =====================================================================
__global__ __launch_bounds__(256) void silu_shared_kernel(
    const float* __restrict__ gus, ushort* __restrict__ shsb) {
  int i = blockIdx.x * 256 + threadIdx.x;
  if (i < TT * (ISHARED/4)) {
    int t = i / (ISHARED/4), k = i % (ISHARED/4);
    const float* gp = gus + (size_t)t * (2*ISHARED) + k * 4;
    float4 g4 = *(const float4*)gp;
    float4 u4 = *(const float4*)(gp + ISHARED);
    ushort4 r;
    r.x = f2bf(g4.x / (1.f + expf(-g4.x)) * u4.x);
    r.y = f2bf(g4.y / (1.f + expf(-g4.y)) * u4.y);
    r.z = f2bf(g4.z / (1.f + expf(-g4.z)) * u4.z);
    r.w = f2bf(g4.w / (1.f + expf(-g4.w)) * u4.w);
    int pdst = ((k >> 3) << 5) + ((k & 3) << 3) + (((k >> 2) & 1) << 2);
    *(ushort4*)(shsb + (size_t)t * ISHARED + pdst) = r;
  }
}

// =====================================================================
// final combine (bf16 partial)
// =====================================================================
__global__ __launch_bounds__(256) void final_combine_kernel(
    const ushort* __restrict__ partialb, const float* __restrict__ sel_w,
    const int* __restrict__ ipos, const float* __restrict__ shared_out,
    float* __restrict__ out_hidden) {
  int t = blockIdx.x, tid = threadIdx.x;
  float w0 = sel_w[t*4], w1 = sel_w[t*4+1], w2 = sel_w[t*4+2], w3 = sel_w[t*4+3];
  int p0 = ipos[t*4], p1 = ipos[t*4+1], p2 = ipos[t*4+2], p3 = ipos[t*4+3];
  ushort4 a0 = *(const ushort4*)(partialb + (size_t)p0*HH + tid*4);
  ushort4 a1 = *(const ushort4*)(partialb + (size_t)p1*HH + tid*4);
  ushort4 a2 = *(const ushort4*)(partialb + (size_t)p2*HH + tid*4);
  ushort4 a3 = *(const ushort4*)(partialb + (size_t)p3*HH + tid*4);
  float4 sh = reinterpret_cast<const float4*>(shared_out + (size_t)t*HH)[tid];
  float4 r;
  r.x = (w0*bf2f(a0.x) + w1*bf2f(a1.x) + w2*bf2f(a2.x) + w3*bf2f(a3.x)) + sh.x;
  r.y = (w0*bf2f(a0.y) + w1*bf2f(a1.y) + w2*bf2f(a2.y) + w3*bf2f(a3.y)) + sh.y;
  r.z = (w0*bf2f(a0.z) + w1*bf2f(a1.z) + w2*bf2f(a2.z) + w3*bf2f(a3.z)) + sh.z;
  r.w = (w0*bf2f(a0.w) + w1*bf2f(a1.w) + w2*bf2f(a2.w) + w3*bf2f(a3.w)) + sh.w;
  reinterpret_cast<float4*>(out_hidden + (size_t)t*HH)[tid] = r;
}

// =====================================================================
extern "C" void kernel_launch(void* const* d_in, const int* in_sizes, int n_in,
                              void* d_out, int out_size, void* d_ws, size_t ws_size,
                              hipStream_t stream) {
  const float* hidden   = (const float*)d_in[0];
  const float* residual = (const float*)d_in[1];
  const float* in_ln_w  = (const float*)d_in[2];
  const float* post_ln_w= (const float*)d_in[3];
  const float* q_norm_w = (const float*)d_in[4];
  const float* k_norm_w = (const float*)d_in[5];
  const float* Wqkv     = (const float*)d_in[6];
  const float* Wo       = (const float*)d_in[7];
  const float* Wg       = (const float*)d_in[8];
  const float* gate_bias= (const float*)d_in[9];
  const float* Wgu      = (const float*)d_in[10];
  const float* Wd       = (const float*)d_in[11];
  const float* Wgu_sh   = (const float*)d_in[12];
  const float* Wd_sh    = (const float*)d_in[13];
  const int*   positions= (const int*)d_in[14];
  float* out = (float*)d_out;

  float* f = (float*)d_ws;
  size_t off = 0;
  float* R_A   = f + off; off += (size_t)TT*HH;
  float* HLN   = f + off; off += (size_t)TT*HH;
  float* QKV   = f + off; off += (size_t)TT*QKV_W;        // reused as gus
  float* OATT  = f + off; off += (size_t)TT*HH;           // DSH output (shared_out)
  float* HLN2  = f + off; off += (size_t)TT*HH;
  float* SELW  = f + off; off += (size_t)TT*TOPK_;
  ushort* HLNB  = (ushort*)(f + off); off += (size_t)TT*HH/2;
  ushort* HLN2B = (ushort*)(f + off); off += (size_t)TT*HH/2;
  ushort* OATTB = (ushort*)(f + off); off += (size_t)TT*HH/2;
  ushort* SHSB  = (ushort*)(f + off); off += (size_t)TT*ISHARED/2;
  ushort* KPK   = (ushort*)(f + off); off += (size_t)NKVH*(TT/32)*2048/2;
  ushort* VPK   = (ushort*)(f + off); off += (size_t)NKVH*(TT/32)*2048/2;
  ushort* ACTB  = (ushort*)(f + off); off += (size_t)(TT*TOPK_ + 128)*IMID/2;
  ushort* PARTB = (ushort*)(f + off); off += (size_t)TT*TOPK_*HH/2;
  ushort* PK_QKV = (ushort*)(f + off); off += (size_t)HH*QKV_W/2;
  ushort* PK_WO  = (ushort*)(f + off); off += (size_t)HH*HH/2;
  ushort* PK_WGU = (ushort*)(f + off); off += (size_t)NEXP*HH*(2*IMID)/2;
  ushort* PK_WD  = (ushort*)(f + off); off += (size_t)NEXP*IMID*HH/2;
  ushort* PK_GUSH= (ushort*)(f + off); off += (size_t)HH*(2*ISHARED)/2;
  ushort* PK_DSH = (ushort*)(f + off); off += (size_t)ISHARED*HH/2;
  int* ibase   = (int*)(f + off);
  int* SELE    = ibase;
  int* PERM    = ibase + TT*TOPK_;
  int* IPOS    = ibase + 2*TT*TOPK_;
  int* COUNTS  = ibase + 3*TT*TOPK_;
  int* OFFS    = COUNTS + NEXP;
  int* CURSOR  = OFFS + NEXP;
  int* SB_E    = CURSOR + NEXP;
  int* SB_BASE = SB_E + MAXSB;
  int* NSB     = SB_BASE + MAXSB;

  // 0. pack all weights to bf16 tile images
  pack_B_kernel<<<dim3(QKV_W/64, HH/32), 256, 0, stream>>>(Wqkv, PK_QKV, QKV_W);
  pack_B_kernel<<<dim3(HH/64, HH/32), 256, 0, stream>>>(Wo, PK_WO, HH);
  pack_B_kernel<<<dim3((2*IMID)/64, NEXP*HH/32), 256, 0, stream>>>(Wgu, PK_WGU, 2*IMID);
  pack_B_kernel<<<dim3(HH/64, NEXP*IMID/32), 256, 0, stream>>>(Wd, PK_WD, HH);
  pack_B_kernel<<<dim3((2*ISHARED)/64, HH/32), 256, 0, stream>>>(Wgu_sh, PK_GUSH, 2*ISHARED);
  pack_B_kernel<<<dim3(HH/64, ISHARED/32), 256, 0, stream>>>(Wd_sh, PK_DSH, HH);

  // 1. pipeline
  add_rms_kernel<<<TT, 256, 0, stream>>>(hidden, residual, in_ln_w, R_A, HLN, HLNB);
  gemm64_bb<<<dim3(QKV_W/64, TT/64), 256, 0, stream>>>(HLNB, PK_QKV, QKV, TT, QKV_W, HH);
  qk_norm_rope_kernel<<<dim3(TT, 5), 256, 0, stream>>>(QKV, q_norm_w, k_norm_w, positions);
  pack_KV_kernel<<<dim3(TT/32, NKVH), 256, 0, stream>>>(QKV, KPK, VPK);
  attn_v2_kernel<<<dim3(NHEADS, 32), 256, 0, stream>>>(QKV, KPK, VPK, OATTB);
  gemm64_bb<<<dim3(HH/64, TT/64), 256, 0, stream>>>(OATTB, PK_WO, HLN, TT, HH, HH);
  add_rms_kernel<<<TT, 256, 0, stream>>>(HLN, R_A, post_ln_w, out + (size_t)TT*HH, HLN2, HLN2B);
  router_kernel<<<TT/4, 256, 0, stream>>>(HLN2, Wg, gate_bias, SELE, SELW);
  count_kernel<<<NEXP, 256, 0, stream>>>(SELE, COUNTS);
  scan_kernel<<<1, 64, 0, stream>>>(COUNTS, OFFS, CURSOR, SB_E, SB_BASE, NSB);
  scatter_kernel<<<(TT*TOPK_ + 255)/256, 256, 0, stream>>>(SELE, CURSOR, PERM, IPOS);
  moe_up_pk<<<dim3(MAXSB, IMID/64), 256, 0, stream>>>(HLN2B, PK_WGU, PERM, OFFS, COUNTS, SB_E, SB_BASE, NSB, ACTB);
  moe_down_pk<<<dim3(MAXSB, HH/64), 256, 0, stream>>>(ACTB, PK_WD, OFFS, COUNTS, SB_E, SB_BASE, NSB, PARTB);
  gemm64_bb<<<dim3((2*ISHARED)/64, TT/64), 256, 0, stream>>>(HLN2B, PK_GUSH, QKV, TT, 2*ISHARED, HH);
  silu_shared_kernel<<<(TT*(ISHARED/4) + 255)/256, 256, 0, stream>>>(QKV, SHSB);
  gemm64_bb<<<dim3(HH/64, TT/64), 256, 0, stream>>>(SHSB, PK_DSH, OATT, TT, HH, ISHARED);
  final_combine_kernel<<<TT, 256, 0, stream>>>(PARTB, SELW, IPOS, OATT, out);
}

// Round 12
// 355.448 us; speedup vs baseline: 1.3582x; 1.0815x over previous
//
#include <hip/hip_runtime.h>
#include <math.h>

// ---- problem constants ----
#define TT 2048
#define HH 1024
#define NHEADS 16
#define NKVH 4
#define HDIM 64
#define NEXP 32
#define TOPK_ 4
#define NGRP 4
#define IMID 384
#define ISHARED 384
#define QKV_W (24*64)   // 1536
#define EPS_ 1e-5f
#define MAXSB 288       // max slot-blocks: 8192/32 + 32
#define NSPLITS 80      // attn split-entries per head (see decode below)

typedef __attribute__((ext_vector_type(8))) short short8;
typedef __attribute__((ext_vector_type(4))) float f32x4;

__device__ __forceinline__ ushort f2bf(float x) {
  union { float f; unsigned u; } v; v.f = x;
  unsigned r = v.u + 0x7fffu + ((v.u >> 16) & 1u);
  return (ushort)(r >> 16);
}
__device__ __forceinline__ float bf2f(ushort u) {
  union { unsigned i; float f; } v; v.i = (unsigned)u << 16; return v.f;
}

// async global->LDS, 16B per lane; lds dst = wave-uniform base + lane*16
__device__ __forceinline__ void gload16(const void* g, void* l) {
  __builtin_amdgcn_global_load_lds(
      (const __attribute__((address_space(1))) unsigned int*)g,
      (__attribute__((address_space(3))) unsigned int*)l, 16, 0, 0);
}

// =====================================================================
// MFMA fragment layouts (16x16x32 bf16), verified rounds 1-11:
//   A-frag lane l: A[row=l&15][k in {4g+j, 16+4g+j}], g=l>>4
//   B-frag lane l: B[k in {4g+j, 16+4g+j}][col=l&15]
//   C lane l: C[row=(l>>4)*4+i][col=l&15]
// A LDS plane (32-row): [g][32][8], row^g swizzle, plane g at g*256.
// A LDS plane (64-row): [g][64][8], row^g swizzle.
// B LDS plane: 4 planes x 1024B, 16B-granular column XOR swizzle.
// Permuted activation row layout (bf16): within each 32-col block,
// position g*8 + hi*4 + j holds original col 4g + 16*hi + j.
// =====================================================================
__device__ __forceinline__ short8 read_a_frag32(const ushort* As, int lg, int row) {
  return *(const short8*)(As + ((lg * 32 + (row ^ lg)) * 8));
}
__device__ __forceinline__ short8 read_a_frag64(const ushort* As, int lg, int row) {
  return *(const short8*)(As + ((lg * 64 + (row ^ lg)) * 8));
}
__device__ __forceinline__ short8 read_b_frag(const ushort* Bs, int lg, int col) {
  int boff = (col * 16) ^ (((col >> 3) & 7) << 4);
  return *(const short8*)((const char*)Bs + lg * 1024 + boff);
}

// B-tile staging from f32 (pack kernels only)
__device__ __forceinline__ void stage_B_tile(const float* __restrict__ B, int ldb,
                                             int k0, int col0, ushort* Bs, int tid) {
  int a = tid >> 4;
  int cG = tid & 15;
  int k = 2 * a;
  const float* p0 = B + (size_t)(k0 + k) * ldb + col0 + cG * 4;
  const float* p1 = p0 + ldb;
  float4 r0 = *(const float4*)p0;
  float4 r1 = *(const float4*)p1;
  int gg = (k & 15) >> 2;
  int slot = (k & 3) + ((k >> 4) << 2);
  float v0[4] = {r0.x, r0.y, r0.z, r0.w};
  float v1[4] = {r1.x, r1.y, r1.z, r1.w};
  char* plane = (char*)Bs + gg * 1024;
  #pragma unroll
  for (int j = 0; j < 4; ++j) {
    int c = cG * 4 + j;
    unsigned pk = (unsigned)f2bf(v0[j]) | ((unsigned)f2bf(v1[j]) << 16);
    int boff = ((c * 16) ^ (((c >> 3) & 7) << 4)) + slot * 2;
    *(unsigned*)(plane + boff) = pk;
  }
}

// ---------------------------------------------------------------------
// Pack kernel: f32 KxN matrix -> bf16 pre-swizzled B-tile images.
// ---------------------------------------------------------------------
__global__ __launch_bounds__(256) void pack_B_kernel(
    const float* __restrict__ src, ushort* __restrict__ dst, int N) {
  __shared__ ushort tileB[2048];
  int tid = threadIdx.x;
  stage_B_tile(src, N, blockIdx.y * 32, blockIdx.x * 64, tileB, tid);
  __syncthreads();
  size_t toff = ((size_t)blockIdx.y * gridDim.x + blockIdx.x) * 2048;
  *(short8*)(dst + toff + tid * 8) = *(const short8*)(tileB + tid * 8);
}

// ---------------------------------------------------------------------
// Dense GEMM (r10 verified): BM=64, BN=64, ring-4, dist-3.
// ---------------------------------------------------------------------
__global__ __launch_bounds__(256) void gemm64_bb(
    const ushort* __restrict__ Ab, const ushort* __restrict__ Bpk,
    float* __restrict__ C, int M, int N, int K) {
  __shared__ ushort As[4][2048];
  __shared__ ushort Bs[4][2048];
  int tid = threadIdx.x;
  int row0 = blockIdx.y * 64, col0 = blockIdx.x * 64;
  int ntn = N >> 6;
  int wid = tid >> 6, lane = tid & 63;
  int lg = lane >> 4, lr = lane & 15;
  int wrow = (wid >> 1) * 32, wcol = (wid & 1) * 32;
  const ushort* asrc = Ab + (size_t)(row0 + (lane ^ wid)) * K + wid * 8;
  const ushort* bsrc = Bpk + (size_t)blockIdx.x * 2048 + wid * 512 + lane * 8;
  const int NT = K >> 5;
  f32x4 acc[2][2] = {};

  auto issue = [&](int tt) {
    int b = tt & 3;
    gload16(asrc + tt * 32, &As[b][wid * 512]);
    gload16(bsrc + (size_t)tt * ntn * 2048, &Bs[b][wid * 512]);
  };
  issue(0); issue(1); issue(2);
  for (int t = 0; t < NT; ++t) {
    int ahead = NT - 1 - t;
    if (ahead >= 2)      asm volatile("s_waitcnt vmcnt(4)" ::: "memory");
    else if (ahead == 1) asm volatile("s_waitcnt vmcnt(2)" ::: "memory");
    else                 asm volatile("s_waitcnt vmcnt(0)" ::: "memory");
    __builtin_amdgcn_s_barrier();
    if (t + 3 < NT) issue(t + 3);
    int cb = t & 3;
    short8 af0 = read_a_frag64(&As[cb][0], lg, wrow + lr);
    short8 af1 = read_a_frag64(&As[cb][0], lg, wrow + 16 + lr);
    #pragma unroll
    for (int nn = 0; nn < 2; ++nn) {
      short8 bf_ = read_b_frag(&Bs[cb][0], lg, wcol + nn * 16 + lr);
      acc[0][nn] = __builtin_amdgcn_mfma_f32_16x16x32_bf16(af0, bf_, acc[0][nn], 0, 0, 0);
      acc[1][nn] = __builtin_amdgcn_mfma_f32_16x16x32_bf16(af1, bf_, acc[1][nn], 0, 0, 0);
    }
  }
  #pragma unroll
  for (int mm = 0; mm < 2; ++mm)
    #pragma unroll
    for (int nn = 0; nn < 2; ++nn) {
      int row = row0 + wrow + mm * 16 + lg * 4;
      int col = col0 + wcol + nn * 16 + lr;
      #pragma unroll
      for (int i = 0; i < 4; ++i)
        C[(size_t)(row + i) * N + col] = acc[mm][nn][i];
    }
}

// ---------------------------------------------------------------------
// MoE up-proj v3 (r11 verified): BM=32 slots, flat slot-block table.
// ---------------------------------------------------------------------
__global__ __launch_bounds__(256) void moe_up_pk(
    const ushort* __restrict__ hln2b, const ushort* __restrict__ Wpk,
    const int* __restrict__ perm, const int* __restrict__ offs,
    const int* __restrict__ counts, const int* __restrict__ sb_e,
    const int* __restrict__ sb_base, const int* __restrict__ nsb,
    ushort* __restrict__ actb) {
  int sb = blockIdx.x;
  if (sb >= *nsb) return;
  int e = sb_e[sb];
  int base = sb_base[sb];
  int start = offs[e];
  int nt = min(32, counts[e] - base);
  __shared__ int tokmap[32];
  int tid = threadIdx.x;
  if (tid < 32) tokmap[tid] = perm[start + base + ((tid < nt) ? tid : 0)] >> 2;
  __shared__ ushort As[3][1024];
  __shared__ ushort Bg[3][2048];
  __shared__ ushort Bu[3][2048];
  __syncthreads();
  int bz = blockIdx.y, col0 = bz * 64;
  int wid = tid >> 6, lane = tid & 63;
  int lg = lane >> 4, lr = lane & 15;
  int wrow = (wid >> 1) * 16, wcol = (wid & 1) * 32;
  const ushort* bgt = Wpk + ((size_t)(e * 32) * 12 + bz) * 2048 + wid * 512 + lane * 8;
  const ushort* but = bgt + (size_t)6 * 2048;
  int ga = wid * 2 + (lane >> 5);
  const ushort* asrcA = hln2b + (size_t)tokmap[(lane & 31) ^ ga] * HH + ga * 8;
  const int NT = HH >> 5;   // 32
  f32x4 accg[2] = {}, accu[2] = {};

  auto issue = [&](int tt) {
    int b = tt % 3;
    if (wid < 2) gload16(asrcA + tt * 32, &As[b][wid * 1024 / 2]);
    gload16(bgt + (size_t)tt * 12 * 2048, &Bg[b][wid * 512]);
    gload16(but + (size_t)tt * 12 * 2048, &Bu[b][wid * 512]);
  };
  issue(0); issue(1);
  for (int t = 0; t < NT; ++t) {
    if (t < NT - 1) {
      if (wid < 2) asm volatile("s_waitcnt vmcnt(3)" ::: "memory");
      else         asm volatile("s_waitcnt vmcnt(2)" ::: "memory");
    } else {
      asm volatile("s_waitcnt vmcnt(0)" ::: "memory");
    }
    __builtin_amdgcn_s_barrier();
    if (t + 2 < NT) issue(t + 2);
    int cb = t % 3;
    short8 af = read_a_frag32(&As[cb][0], lg, wrow + lr);
    #pragma unroll
    for (int nn = 0; nn < 2; ++nn) {
      short8 bgf = read_b_frag(&Bg[cb][0], lg, wcol + nn * 16 + lr);
      short8 buf_ = read_b_frag(&Bu[cb][0], lg, wcol + nn * 16 + lr);
      accg[nn] = __builtin_amdgcn_mfma_f32_16x16x32_bf16(af, bgf, accg[nn], 0, 0, 0);
      accu[nn] = __builtin_amdgcn_mfma_f32_16x16x32_bf16(af, buf_, accu[nn], 0, 0, 0);
    }
  }
  #pragma unroll
  for (int nn = 0; nn < 2; ++nn) {
    int pcol = col0 + ((wid & 1) << 5) + ((lr >> 2) << 3) + (nn << 2) + (lr & 3);
    #pragma unroll
    for (int i = 0; i < 4; ++i) {
      int rr = wrow + lg * 4 + i;
      if (rr < nt) {
        float gv = accg[nn][i], uv = accu[nn][i];
        float av = gv / (1.f + expf(-gv)) * uv;
        actb[(size_t)(start + base + rr) * IMID + pcol] = f2bf(av);
      }
    }
  }
}

// ---------------------------------------------------------------------
// MoE down-proj v3 (r11 verified): BM=32, flat slot-block table.
// ---------------------------------------------------------------------
__global__ __launch_bounds__(256) void moe_down_pk(
    const ushort* __restrict__ actb, const ushort* __restrict__ Wpk,
    const int* __restrict__ offs, const int* __restrict__ counts,
    const int* __restrict__ sb_e, const int* __restrict__ sb_base,
    const int* __restrict__ nsb, ushort* __restrict__ partialb) {
  int sb = blockIdx.x;
  if (sb >= *nsb) return;
  int e = sb_e[sb];
  int base = sb_base[sb];
  int start = offs[e];
  int nt = min(32, counts[e] - base);
  __shared__ ushort As[3][1024];
  __shared__ ushort Bs[3][2048];
  int tid = threadIdx.x;
  int bz = blockIdx.y, col0 = bz * 64;
  int wid = tid >> 6, lane = tid & 63;
  int lg = lane >> 4, lr = lane & 15;
  int wrow = (wid >> 1) * 16, wcol = (wid & 1) * 32;
  const ushort* bt0 = Wpk + ((size_t)(e * 12) * 16 + bz) * 2048 + wid * 512 + lane * 8;
  int ga = wid * 2 + (lane >> 5);
  const ushort* asrcA = actb + (size_t)(start + base + ((lane & 31) ^ ga)) * IMID + ga * 8;
  const int NT = IMID >> 5;   // 12
  f32x4 acc[2] = {};

  auto issue = [&](int tt) {
    int b = tt % 3;
    if (wid < 2) gload16(asrcA + tt * 32, &As[b][wid * 512]);
    gload16(bt0 + (size_t)tt * 16 * 2048, &Bs[b][wid * 512]);
  };
  issue(0); issue(1);
  for (int t = 0; t < NT; ++t) {
    if (t < NT - 1) {
      if (wid < 2) asm volatile("s_waitcnt vmcnt(2)" ::: "memory");
      else         asm volatile("s_waitcnt vmcnt(1)" ::: "memory");
    } else {
      asm volatile("s_waitcnt vmcnt(0)" ::: "memory");
    }
    __builtin_amdgcn_s_barrier();
    if (t + 2 < NT) issue(t + 2);
    int cb = t % 3;
    short8 af = read_a_frag32(&As[cb][0], lg, wrow + lr);
    #pragma unroll
    for (int nn = 0; nn < 2; ++nn) {
      short8 bf_ = read_b_frag(&Bs[cb][0], lg, wcol + nn * 16 + lr);
      acc[nn] = __builtin_amdgcn_mfma_f32_16x16x32_bf16(af, bf_, acc[nn], 0, 0, 0);
    }
  }
  #pragma unroll
  for (int nn = 0; nn < 2; ++nn)
    #pragma unroll
    for (int i = 0; i < 4; ++i) {
      int rr = wrow + lg * 4 + i;
      if (rr < nt)
        partialb[(size_t)(start + base + rr) * HH + col0 + wcol + nn * 16 + lr] = f2bf(acc[nn][i]);
    }
}

// =====================================================================
// residual add + RMSNorm; emits f32 sum, f32 ln, permuted bf16 ln.
// =====================================================================
__global__ __launch_bounds__(256) void add_rms_kernel(
    const float* __restrict__ a, const float* __restrict__ b,
    const float* __restrict__ w, float* __restrict__ sum_out,
    float* __restrict__ ln_out, ushort* __restrict__ lnb) {
  int t = blockIdx.x, tid = threadIdx.x;
  float4 x = reinterpret_cast<const float4*>(a + (size_t)t*HH)[tid];
  float4 y = reinterpret_cast<const float4*>(b + (size_t)t*HH)[tid];
  x.x += y.x; x.y += y.y; x.z += y.z; x.w += y.w;
  float ss = x.x*x.x + x.y*x.y + x.z*x.z + x.w*x.w;
  #pragma unroll
  for (int off = 1; off < 64; off <<= 1) ss += __shfl_xor(ss, off);
  __shared__ float wsum[4];
  int wid = tid >> 6, lane = tid & 63;
  if (lane == 0) wsum[wid] = ss;
  __syncthreads();
  float tot = wsum[0] + wsum[1] + wsum[2] + wsum[3];
  float r = rsqrtf(tot * (1.0f/HH) + EPS_);
  reinterpret_cast<float4*>(sum_out + (size_t)t*HH)[tid] = x;
  float4 wl = reinterpret_cast<const float4*>(w)[tid];
  float4 o = make_float4(x.x*r*wl.x, x.y*r*wl.y, x.z*r*wl.z, x.w*r*wl.w);
  reinterpret_cast<float4*>(ln_out + (size_t)t*HH)[tid] = o;
  ushort4 ub;
  ub.x = f2bf(o.x); ub.y = f2bf(o.y); ub.z = f2bf(o.z); ub.w = f2bf(o.w);
  int dst = ((tid >> 3) << 5) + ((tid & 3) << 3) + (((tid >> 2) & 1) << 2);
  *(ushort4*)(lnb + (size_t)t * HH + dst) = ub;
}

// =====================================================================
// per-(t,head) QK RMSNorm + RoPE, in-place (f32)
// =====================================================================
__global__ __launch_bounds__(256) void qk_norm_rope_kernel(
    float* __restrict__ qkv, const float* __restrict__ qw,
    const float* __restrict__ kw, const int* __restrict__ pos) {
  int t = blockIdx.x;
  int hh = blockIdx.y * 4 + (threadIdx.x >> 6);
  int lane = threadIdx.x & 63;
  float* p = qkv + (size_t)t * QKV_W + hh * HDIM;
  float x = p[lane];
  float ss = x * x;
  #pragma unroll
  for (int off = 1; off < 64; off <<= 1) ss += __shfl_xor(ss, off);
  float r = rsqrtf(ss * (1.0f/HDIM) + EPS_);
  float wv = (hh < NHEADS ? qw : kw)[lane];
  float xn = x * r * wv;
  float partner = __shfl_xor(xn, 16);
  float out = xn;
  if (lane < 32) {
    int i = lane & 15;
    float inv = powf(10000.0f, -(float)i / 16.0f);
    float ang = (float)pos[t] * inv;
    float cv = cosf(ang), sv = sinf(ang);
    out = (lane < 16) ? (xn * cv - partner * sv) : (partner * sv + xn * cv);
  }
  p[lane] = out;
}

// =====================================================================
// pack_KV: rope'd K -> A-tile images; V -> B-tile images. grid (T/32, NKVH)
// =====================================================================
__global__ __launch_bounds__(256) void pack_KV_kernel(
    const float* __restrict__ qkv, ushort* __restrict__ Kpk,
    ushort* __restrict__ Vpk) {
  __shared__ ushort kimg[2048];
  __shared__ ushort vimg[2048];
  int tid = threadIdx.x;
  int kt = blockIdx.x, kvh = blockIdx.y;
  {
    int c = tid >> 7, t2 = tid & 127;
    int g = t2 & 3, r = t2 >> 2;
    const float* kp = qkv + (size_t)(kt*32 + r) * QKV_W + NHEADS*HDIM + kvh*HDIM + 32*c + 4*g;
    float4 h0 = *(const float4*)kp;
    float4 h1 = *(const float4*)(kp + 16);
    short8 v;
    v[0]=(short)f2bf(h0.x); v[1]=(short)f2bf(h0.y); v[2]=(short)f2bf(h0.z); v[3]=(short)f2bf(h0.w);
    v[4]=(short)f2bf(h1.x); v[5]=(short)f2bf(h1.y); v[6]=(short)f2bf(h1.z); v[7]=(short)f2bf(h1.w);
    *(short8*)(kimg + c*1024 + (g*32 + (r^g))*8) = v;
  }
  stage_B_tile(qkv + (size_t)(NHEADS+NKVH)*HDIM + (size_t)kvh*HDIM, QKV_W, kt*32, 0, vimg, tid);
  __syncthreads();
  size_t toff = ((size_t)(kvh * (TT/32) + kt)) * 2048;
  *(short8*)(Kpk + toff + tid * 8) = *(const short8*)(kimg + tid * 8);
  *(short8*)(Vpk + toff + tid * 8) = *(const short8*)(vimg + tid * 8);
}

// =====================================================================
// Attention v3: split-KV + FIXED-MAX log2 softmax (p = exp2(s-16);
// exact since softmax is shift-invariant and |s|<=~12 is bounded by
// RMS-normed q,k). Partials combine by pure addition.
// Flat split table (per head): qb 0..31, ns(qb) = (qb>>3)+1,
//   cum(g) = 4g(g+1); entry f -> (qb, s). 80 entries. grid (80, NH).
// ns==1 (qb<8): write permuted bf16 directly. Else: write f32 O,l.
// =====================================================================
__global__ __launch_bounds__(256) void attn_v3_kernel(
    const float* __restrict__ qkv, const ushort* __restrict__ Kpk,
    const ushort* __restrict__ Vpk, ushort* __restrict__ ob,
    float* __restrict__ po, float* __restrict__ pl) {
  __shared__ ushort Ks[3][2048];
  __shared__ ushort Vs[3][2048];
  int tid = threadIdx.x;
  int wid = tid >> 6, lane = tid & 63;
  int lg = lane >> 4, lr = lane & 15;
  int h = blockIdx.y;
  int f = blockIdx.x;
  int g = 0;
  while (f >= 4 * (g + 1) * (g + 2)) ++g;       // group: ns = g+1
  int r_ = f - 4 * g * (g + 1);
  int ns = g + 1;
  int qb = 8 * g + r_ / ns;
  int s = r_ % ns;
  int tiles_total = 2 * qb + 2;
  int per = (tiles_total + ns - 1) / ns;
  int lo = s * per;
  int nloc = min(per, tiles_total - lo);
  int kvh = h >> 2;
  int q0 = qb * 64 + wid * 16;
  int qg = q0 + lr;
  const float SCL = 0.125f * 1.44269504f;       // 1/8 * log2(e)
  const float FM = 16.0f;                       // fixed softmax max (log2 domain)

  const float* qrow = qkv + (size_t)qg * QKV_W + h * HDIM;
  short8 qfr[2];
  #pragma unroll
  for (int c = 0; c < 2; ++c) {
    float4 a = *(const float4*)(qrow + 32*c + 4*lg);
    float4 b = *(const float4*)(qrow + 32*c + 4*lg + 16);
    short8 v;
    v[0]=(short)f2bf(a.x*SCL); v[1]=(short)f2bf(a.y*SCL); v[2]=(short)f2bf(a.z*SCL); v[3]=(short)f2bf(a.w*SCL);
    v[4]=(short)f2bf(b.x*SCL); v[5]=(short)f2bf(b.y*SCL); v[6]=(short)f2bf(b.z*SCL); v[7]=(short)f2bf(b.w*SCL);
    qfr[c] = v;
  }

  const ushort* ksrc = Kpk + (size_t)(kvh * (TT/32) + lo) * 2048 + wid * 512 + lane * 8;
  const ushort* vsrc = Vpk + (size_t)(kvh * (TT/32) + lo) * 2048 + wid * 512 + lane * 8;

  f32x4 o_acc[4] = {};
  float l_st = 0.f;

  auto issue = [&](int tt) {
    int b = tt % 3;
    gload16(ksrc + (size_t)tt * 2048, &Ks[b][wid * 512]);
    gload16(vsrc + (size_t)tt * 2048, &Vs[b][wid * 512]);
  };
  issue(0);
  if (nloc > 1) issue(1);
  for (int tt = 0; tt < nloc; ++tt) {
    if (tt < nloc - 1) asm volatile("s_waitcnt vmcnt(2)" ::: "memory");
    else               asm volatile("s_waitcnt vmcnt(0)" ::: "memory");
    __builtin_amdgcn_s_barrier();
    if (tt + 2 < nloc) issue(tt + 2);
    int t = lo + tt;
    if (t * 32 > q0 + 15) continue;
    int cb = tt % 3;
    f32x4 st[2];
    #pragma unroll
    for (int n = 0; n < 2; ++n) {
      short8 kf0 = *(const short8*)(&Ks[cb][(lg*32 + ((16*n + lr) ^ lg)) * 8]);
      short8 kf1 = *(const short8*)(&Ks[cb][1024 + (lg*32 + ((16*n + lr) ^ lg)) * 8]);
      f32x4 z = {};
      z = __builtin_amdgcn_mfma_f32_16x16x32_bf16(kf0, qfr[0], z, 0, 0, 0);
      st[n] = __builtin_amdgcn_mfma_f32_16x16x32_bf16(kf1, qfr[1], z, 0, 0, 0);
    }
    float p[2][4];
    float psum = 0.f;
    if (t * 32 + 31 <= q0) {          // fully unmasked (common)
      #pragma unroll
      for (int n = 0; n < 2; ++n)
        #pragma unroll
        for (int i = 0; i < 4; ++i) {
          float pv = exp2f(st[n][i] - FM);
          p[n][i] = pv; psum += pv;
        }
    } else {                          // diagonal tile
      #pragma unroll
      for (int n = 0; n < 2; ++n)
        #pragma unroll
        for (int i = 0; i < 4; ++i) {
          int kvg = t*32 + 16*n + 4*lg + i;
          float pv = (kvg <= qg) ? exp2f(st[n][i] - FM) : 0.f;
          p[n][i] = pv; psum += pv;
        }
    }
    psum += __shfl_xor(psum, 16);
    psum += __shfl_xor(psum, 32);
    l_st += psum;
    union { unsigned u[4]; short8 s8; } pu;
    asm volatile("v_cvt_pk_bf16_f32 %0, %1, %2" : "=v"(pu.u[0]) : "v"(p[0][0]), "v"(p[0][1]));
    asm volatile("v_cvt_pk_bf16_f32 %0, %1, %2" : "=v"(pu.u[1]) : "v"(p[0][2]), "v"(p[0][3]));
    asm volatile("v_cvt_pk_bf16_f32 %0, %1, %2" : "=v"(pu.u[2]) : "v"(p[1][0]), "v"(p[1][1]));
    asm volatile("v_cvt_pk_bf16_f32 %0, %1, %2" : "=v"(pu.u[3]) : "v"(p[1][2]), "v"(p[1][3]));
    short8 pa = pu.s8;
    #pragma unroll
    for (int nd = 0; nd < 4; ++nd) {
      short8 vf = read_b_frag(&Vs[cb][0], lg, 16*nd + lr);
      o_acc[nd] = __builtin_amdgcn_mfma_f32_16x16x32_bf16(pa, vf, o_acc[nd], 0, 0, 0);
    }
  }

  if (ns == 1) {
    // single split: normalize + write permuted bf16
    #pragma unroll
    for (int i = 0; i < 4; ++i) {
      float lrow = __shfl(l_st, 4*lg + i);
      float inv = 1.0f / lrow;
      int row = q0 + 4*lg + i;
      ushort* op = ob + (size_t)row * (NHEADS*HDIM) + h * HDIM;
      #pragma unroll
      for (int nd = 0; nd < 4; ++nd) {
        int pcol = ((nd >> 1) << 5) + ((lr >> 2) << 3) + ((nd & 1) << 2) + (lr & 3);
        op[pcol] = f2bf(o_acc[nd][i] * inv);
      }
    }
  } else {
    // partial: unnormalized O (f32) + l
    float* pob = po + ((size_t)f * NHEADS + h) * 4096;
    #pragma unroll
    for (int nd = 0; nd < 4; ++nd)
      #pragma unroll
      for (int i = 0; i < 4; ++i)
        pob[(wid * 16 + lg * 4 + i) * 64 + 16 * nd + lr] = o_acc[nd][i];
    if (lg == 0)
      pl[((size_t)f * NHEADS + h) * 64 + wid * 16 + lr] = l_st;
  }
}

// =====================================================================
// attn combine: for qb>=8, sum splits, normalize, write permuted bf16.
// grid (NHEADS, 24): qb = 8 + blockIdx.y.
// =====================================================================
__global__ __launch_bounds__(256) void attn_combine_kernel(
    const float* __restrict__ po, const float* __restrict__ pl,
    ushort* __restrict__ ob) {
  int h = blockIdx.x;
  int qb = 8 + blockIdx.y;
  int g = qb >> 3;                      // 1..3
  int ns = g + 1;
  int f0 = 4 * g * (g + 1) + (qb - 8 * g) * ns;
  int tid = threadIdx.x;
  int r = tid >> 2, c = tid & 3;        // row 0..63, col quad 0..3 (16 cols)
  float acc[16] = {};
  float lsum = 0.f;
  for (int s = 0; s < ns; ++s) {
    size_t base = ((size_t)(f0 + s) * NHEADS + h) * 4096 + r * 64 + c * 16;
    #pragma unroll
    for (int j = 0; j < 4; ++j) {
      float4 v = *(const float4*)(po + base + j * 4);
      acc[j*4+0] += v.x; acc[j*4+1] += v.y; acc[j*4+2] += v.z; acc[j*4+3] += v.w;
    }
    lsum += pl[((size_t)(f0 + s) * NHEADS + h) * 64 + r];
  }
  float inv = 1.0f / lsum;
  int row = qb * 64 + r;
  ushort* op = ob + (size_t)row * (NHEADS*HDIM) + h * HDIM + (c >> 1) * 32 + (c & 1) * 4;
  #pragma unroll
  for (int a = 0; a < 4; ++a) {
    ushort4 u;
    u.x = f2bf(acc[a*4+0] * inv); u.y = f2bf(acc[a*4+1] * inv);
    u.z = f2bf(acc[a*4+2] * inv); u.w = f2bf(acc[a*4+3] * inv);
    *(ushort4*)(op + a * 8) = u;
  }
}

// =====================================================================
// router: wave-parallel (r8 verified)
// =====================================================================
__global__ __launch_bounds__(256) void router_kernel(
    const float* __restrict__ hln, const float* __restrict__ Wg,
    const float* __restrict__ bias, int* __restrict__ sel_e,
    float* __restrict__ sel_w) {
  __shared__ float hid[4][HH];
  int tid = threadIdx.x, wid = tid >> 6, lane = tid & 63;
  int t = blockIdx.x * 4 + wid;
  const float4* src = (const float4*)(hln + (size_t)t * HH);
  float4* dst = (float4*)hid[wid];
  #pragma unroll
  for (int j = 0; j < 4; ++j) dst[j * 64 + lane] = src[j * 64 + lane];
  int e = lane & 31, half = lane >> 5;
  const float* wp = Wg + (size_t)(half * 512) * NEXP + e;
  const float* hp = hid[wid] + half * 512;
  float p = 0.f;
  #pragma unroll 8
  for (int h = 0; h < 512; ++h) p += hp[h] * wp[(size_t)h * NEXP];
  p += __shfl_xor(p, 32);
  float sc = 1.0f / (1.0f + expf(-p));
  float sfc = sc + bias[e];
  float m1 = sfc, m2 = -1e30f;
  #pragma unroll
  for (int off = 1; off <= 4; off <<= 1) {
    float om1 = __shfl_xor(m1, off), om2 = __shfl_xor(m2, off);
    float hi_ = fmaxf(m1, om1);
    float lo_ = fmaxf(fminf(m1, om1), fmaxf(m2, om2));
    m1 = hi_; m2 = lo_;
  }
  float gs = m1 + m2;
  float gv[4] = {__shfl(gs, 0), __shfl(gs, 8), __shfl(gs, 16), __shfl(gs, 24)};
  int g1 = 0; float b1 = gv[0];
  #pragma unroll
  for (int g = 1; g < 4; ++g) if (gv[g] > b1) { b1 = gv[g]; g1 = g; }
  int g2 = -1; float b2 = -1e30f;
  #pragma unroll
  for (int g = 0; g < 4; ++g) if (g != g1 && gv[g] > b2) { b2 = gv[g]; g2 = g; }
  bool keep = ((e >> 3) == g1) || ((e >> 3) == g2);
  float cand = keep ? sfc : -1e30f;
  int ids[4]; float wv[4]; float wsum = 0.f;
  #pragma unroll
  for (int s = 0; s < 4; ++s) {
    float v = cand; int ix = e;
    #pragma unroll
    for (int off = 1; off < 64; off <<= 1) {
      float ov = __shfl_xor(v, off); int oix = __shfl_xor(ix, off);
      if (ov > v || (ov == v && oix < ix)) { v = ov; ix = oix; }
    }
    ids[s] = ix;
    if (e == ix) cand = -1e30f;
    float w = __shfl(sc, ix);
    wv[s] = w; wsum += w;
  }
  if (lane == 0) {
    #pragma unroll
    for (int s = 0; s < 4; ++s) {
      sel_e[t * 4 + s] = ids[s];
      sel_w[t * 4 + s] = wv[s] / wsum;
    }
  }
}

__global__ __launch_bounds__(256) void count_kernel(
    const int* __restrict__ sel_e, int* __restrict__ counts) {
  int e = blockIdx.x, tid = threadIdx.x;
  int c = 0;
  for (int i = tid; i < TT * TOPK_; i += 256) c += (sel_e[i] == e);
  #pragma unroll
  for (int off = 1; off < 64; off <<= 1) c += __shfl_xor(c, off);
  __shared__ int wsum[4];
  if ((tid & 63) == 0) wsum[tid >> 6] = c;
  __syncthreads();
  if (tid == 0) counts[e] = wsum[0] + wsum[1] + wsum[2] + wsum[3];
}

// scan + flat slot-block table (BM=32 granularity)
__global__ void scan_kernel(const int* __restrict__ counts,
                            int* __restrict__ offs, int* __restrict__ cursor,
                            int* __restrict__ sb_e, int* __restrict__ sb_base,
                            int* __restrict__ nsb) {
  if (threadIdx.x == 0) {
    int acc = 0, n = 0;
    for (int e = 0; e < NEXP; ++e) {
      offs[e] = acc; cursor[e] = acc;
      int c = counts[e];
      for (int b = 0; b < c; b += 32) { sb_e[n] = e; sb_base[n] = b; ++n; }
      acc += c;
    }
    *nsb = n;
  }
}

__global__ void scatter_kernel(const int* __restrict__ sel_e,
                               int* __restrict__ cursor, int* __restrict__ perm,
                               int* __restrict__ ipos) {
  int i = blockIdx.x * 256 + threadIdx.x;
  if (i < TT * TOPK_) {
    int e = sel_e[i];
    int pos = atomicAdd(&cursor[e], 1);
    perm[pos] = i;
    ipos[i] = pos;
  }
}

// =====================================================================
// shared-expert SiLU*mul -> permuted bf16 (4 cols/thread)
// =====================================================================
__global__ __launch_bounds__(256) void silu_shared_kernel(
    const float* __restrict__ gus, ushort* __restrict__ shsb) {
  int i = blockIdx.x * 256 + threadIdx.x;
  if (i < TT * (ISHARED/4)) {
    int t = i / (ISHARED/4), k = i % (ISHARED/4);
    const float* gp = gus + (size_t)t * (2*ISHARED) + k * 4;
    float4 g4 = *(const float4*)gp;
    float4 u4 = *(const float4*)(gp + ISHARED);
    ushort4 r;
    r.x = f2bf(g4.x / (1.f + expf(-g4.x)) * u4.x);
    r.y = f2bf(g4.y / (1.f + expf(-g4.y)) * u4.y);
    r.z = f2bf(g4.z / (1.f + expf(-g4.z)) * u4.z);
    r.w = f2bf(g4.w / (1.f + expf(-g4.w)) * u4.w);
    int pdst = ((k >> 3) << 5) + ((k & 3) << 3) + (((k >> 2) & 1) << 2);
    *(ushort4*)(shsb + (size_t)t * ISHARED + pdst) = r;
  }
}

// =====================================================================
// final combine (bf16 partial)
// =====================================================================
__global__ __launch_bounds__(256) void final_combine_kernel(
    const ushort* __restrict__ partialb, const float* __restrict__ sel_w,
    const int* __restrict__ ipos, const float* __restrict__ shared_out,
    float* __restrict__ out_hidden) {
  int t = blockIdx.x, tid = threadIdx.x;
  float w0 = sel_w[t*4], w1 = sel_w[t*4+1], w2 = sel_w[t*4+2], w3 = sel_w[t*4+3];
  int p0 = ipos[t*4], p1 = ipos[t*4+1], p2 = ipos[t*4+2], p3 = ipos[t*4+3];
  ushort4 a0 = *(const ushort4*)(partialb + (size_t)p0*HH + tid*4);
  ushort4 a1 = *(const ushort4*)(partialb + (size_t)p1*HH + tid*4);
  ushort4 a2 = *(const ushort4*)(partialb + (size_t)p2*HH + tid*4);
  ushort4 a3 = *(const ushort4*)(partialb + (size_t)p3*HH + tid*4);
  float4 sh = reinterpret_cast<const float4*>(shared_out + (size_t)t*HH)[tid];
  float4 r;
  r.x = (w0*bf2f(a0.x) + w1*bf2f(a1.x) + w2*bf2f(a2.x) + w3*bf2f(a3.x)) + sh.x;
  r.y = (w0*bf2f(a0.y) + w1*bf2f(a1.y) + w2*bf2f(a2.y) + w3*bf2f(a3.y)) + sh.y;
  r.z = (w0*bf2f(a0.z) + w1*bf2f(a1.z) + w2*bf2f(a2.z) + w3*bf2f(a3.z)) + sh.z;
  r.w = (w0*bf2f(a0.w) + w1*bf2f(a1.w) + w2*bf2f(a2.w) + w3*bf2f(a3.w)) + sh.w;
  reinterpret_cast<float4*>(out_hidden + (size_t)t*HH)[tid] = r;
}

// =====================================================================
extern "C" void kernel_launch(void* const* d_in, const int* in_sizes, int n_in,
                              void* d_out, int out_size, void* d_ws, size_t ws_size,
                              hipStream_t stream) {
  const float* hidden   = (const float*)d_in[0];
  const float* residual = (const float*)d_in[1];
  const float* in_ln_w  = (const float*)d_in[2];
  const float* post_ln_w= (const float*)d_in[3];
  const float* q_norm_w = (const float*)d_in[4];
  const float* k_norm_w = (const float*)d_in[5];
  const float* Wqkv     = (const float*)d_in[6];
  const float* Wo       = (const float*)d_in[7];
  const float* Wg       = (const float*)d_in[8];
  const float* gate_bias= (const float*)d_in[9];
  const float* Wgu      = (const float*)d_in[10];
  const float* Wd       = (const float*)d_in[11];
  const float* Wgu_sh   = (const float*)d_in[12];
  const float* Wd_sh    = (const float*)d_in[13];
  const int*   positions= (const int*)d_in[14];
  float* out = (float*)d_out;

  float* f = (float*)d_ws;
  size_t off = 0;
  float* R_A   = f + off; off += (size_t)TT*HH;
  float* HLN   = f + off; off += (size_t)TT*HH;
  float* QKV   = f + off; off += (size_t)TT*QKV_W;        // reused as gus
  float* OATT  = f + off; off += (size_t)TT*HH;           // DSH output (shared_out)
  float* HLN2  = f + off; off += (size_t)TT*HH;
  float* SELW  = f + off; off += (size_t)TT*TOPK_;
  float* PO    = f + off; off += (size_t)NSPLITS*NHEADS*4096;  // attn partial O
  float* PL    = f + off; off += (size_t)NSPLITS*NHEADS*64;    // attn partial l
  ushort* HLNB  = (ushort*)(f + off); off += (size_t)TT*HH/2;
  ushort* HLN2B = (ushort*)(f + off); off += (size_t)TT*HH/2;
  ushort* OATTB = (ushort*)(f + off); off += (size_t)TT*HH/2;
  ushort* SHSB  = (ushort*)(f + off); off += (size_t)TT*ISHARED/2;
  ushort* KPK   = (ushort*)(f + off); off += (size_t)NKVH*(TT/32)*2048/2;
  ushort* VPK   = (ushort*)(f + off); off += (size_t)NKVH*(TT/32)*2048/2;
  ushort* ACTB  = (ushort*)(f + off); off += (size_t)(TT*TOPK_ + 128)*IMID/2;
  ushort* PARTB = (ushort*)(f + off); off += (size_t)TT*TOPK_*HH/2;
  ushort* PK_QKV = (ushort*)(f + off); off += (size_t)HH*QKV_W/2;
  ushort* PK_WO  = (ushort*)(f + off); off += (size_t)HH*HH/2;
  ushort* PK_WGU = (ushort*)(f + off); off += (size_t)NEXP*HH*(2*IMID)/2;
  ushort* PK_WD  = (ushort*)(f + off); off += (size_t)NEXP*IMID*HH/2;
  ushort* PK_GUSH= (ushort*)(f + off); off += (size_t)HH*(2*ISHARED)/2;
  ushort* PK_DSH = (ushort*)(f + off); off += (size_t)ISHARED*HH/2;
  int* ibase   = (int*)(f + off);
  int* SELE    = ibase;
  int* PERM    = ibase + TT*TOPK_;
  int* IPOS    = ibase + 2*TT*TOPK_;
  int* COUNTS  = ibase + 3*TT*TOPK_;
  int* OFFS    = COUNTS + NEXP;
  int* CURSOR  = OFFS + NEXP;
  int* SB_E    = CURSOR + NEXP;
  int* SB_BASE = SB_E + MAXSB;
  int* NSB     = SB_BASE + MAXSB;

  // 0. pack all weights to bf16 tile images
  pack_B_kernel<<<dim3(QKV_W/64, HH/32), 256, 0, stream>>>(Wqkv, PK_QKV, QKV_W);
  pack_B_kernel<<<dim3(HH/64, HH/32), 256, 0, stream>>>(Wo, PK_WO, HH);
  pack_B_kernel<<<dim3((2*IMID)/64, NEXP*HH/32), 256, 0, stream>>>(Wgu, PK_WGU, 2*IMID);
  pack_B_kernel<<<dim3(HH/64, NEXP*IMID/32), 256, 0, stream>>>(Wd, PK_WD, HH);
  pack_B_kernel<<<dim3((2*ISHARED)/64, HH/32), 256, 0, stream>>>(Wgu_sh, PK_GUSH, 2*ISHARED);
  pack_B_kernel<<<dim3(HH/64, ISHARED/32), 256, 0, stream>>>(Wd_sh, PK_DSH, HH);

  // 1. pipeline
  add_rms_kernel<<<TT, 256, 0, stream>>>(hidden, residual, in_ln_w, R_A, HLN, HLNB);
  gemm64_bb<<<dim3(QKV_W/64, TT/64), 256, 0, stream>>>(HLNB, PK_QKV, QKV, TT, QKV_W, HH);
  qk_norm_rope_kernel<<<dim3(TT, 5), 256, 0, stream>>>(QKV, q_norm_w, k_norm_w, positions);
  pack_KV_kernel<<<dim3(TT/32, NKVH), 256, 0, stream>>>(QKV, KPK, VPK);
  attn_v3_kernel<<<dim3(NSPLITS, NHEADS), 256, 0, stream>>>(QKV, KPK, VPK, OATTB, PO, PL);
  attn_combine_kernel<<<dim3(NHEADS, 24), 256, 0, stream>>>(PO, PL, OATTB);
  gemm64_bb<<<dim3(HH/64, TT/64), 256, 0, stream>>>(OATTB, PK_WO, HLN, TT, HH, HH);
  add_rms_kernel<<<TT, 256, 0, stream>>>(HLN, R_A, post_ln_w, out + (size_t)TT*HH, HLN2, HLN2B);
  router_kernel<<<TT/4, 256, 0, stream>>>(HLN2, Wg, gate_bias, SELE, SELW);
  count_kernel<<<NEXP, 256, 0, stream>>>(SELE, COUNTS);
  scan_kernel<<<1, 64, 0, stream>>>(COUNTS, OFFS, CURSOR, SB_E, SB_BASE, NSB);
  scatter_kernel<<<(TT*TOPK_ + 255)/256, 256, 0, stream>>>(SELE, CURSOR, PERM, IPOS);
  moe_up_pk<<<dim3(MAXSB, IMID/64), 256, 0, stream>>>(HLN2B, PK_WGU, PERM, OFFS, COUNTS, SB_E, SB_BASE, NSB, ACTB);
  moe_down_pk<<<dim3(MAXSB, HH/64), 256, 0, stream>>>(ACTB, PK_WD, OFFS, COUNTS, SB_E, SB_BASE, NSB, PARTB);
  gemm64_bb<<<dim3((2*ISHARED)/64, TT/64), 256, 0, stream>>>(HLN2B, PK_GUSH, QKV, TT, 2*ISHARED, HH);
  silu_shared_kernel<<<(TT*(ISHARED/4) + 255)/256, 256, 0, stream>>>(QKV, SHSB);
  gemm64_bb<<<dim3(HH/64, TT/64), 256, 0, stream>>>(SHSB, PK_DSH, OATT, TT, HH, ISHARED);
  final_combine_kernel<<<TT, 256, 0, stream>>>(PARTB, SELW, IPOS, OATT, out);
}

// Round 13
// 349.993 us; speedup vs baseline: 1.3794x; 1.0156x over previous
//
#include <hip/hip_runtime.h>
#include <math.h>

// ---- problem constants ----
#define TT 2048
#define HH 1024
#define NHEADS 16
#define NKVH 4
#define HDIM 64
#define NEXP 32
#define TOPK_ 4
#define NGRP 4
#define IMID 384
#define ISHARED 384
#define QKV_W (24*64)   // 1536
#define EPS_ 1e-5f
#define MAXSB 288       // max slot-blocks: 8192/32 + 32 (= 8*36)
#define NSPLITS 80      // attn split-entries per head

typedef __attribute__((ext_vector_type(8))) short short8;
typedef __attribute__((ext_vector_type(4))) float f32x4;

__device__ __forceinline__ ushort f2bf(float x) {
  union { float f; unsigned u; } v; v.f = x;
  unsigned r = v.u + 0x7fffu + ((v.u >> 16) & 1u);
  return (ushort)(r >> 16);
}
__device__ __forceinline__ float bf2f(ushort u) {
  union { unsigned i; float f; } v; v.i = (unsigned)u << 16; return v.f;
}

// async global->LDS, 16B per lane; lds dst = wave-uniform base + lane*16
__device__ __forceinline__ void gload16(const void* g, void* l) {
  __builtin_amdgcn_global_load_lds(
      (const __attribute__((address_space(1))) unsigned int*)g,
      (__attribute__((address_space(3))) unsigned int*)l, 16, 0, 0);
}

// =====================================================================
// MFMA fragment layouts (16x16x32 bf16), verified rounds 1-12:
//   A-frag lane l: A[row=l&15][k in {4g+j, 16+4g+j}], g=l>>4
//   B-frag lane l: B[k in {4g+j, 16+4g+j}][col=l&15]
//   C lane l: C[row=(l>>4)*4+i][col=l&15]
// A LDS plane (32-row): [g][32][8], row^g swizzle, plane g at g*256.
// A LDS plane (64-row): [g][64][8], row^g swizzle.
// B LDS plane: 4 planes x 1024B, 16B-granular column XOR swizzle.
// Permuted activation row layout (bf16): within each 32-col block,
// position g*8 + hi*4 + j holds original col 4g + 16*hi + j.
// =====================================================================
__device__ __forceinline__ short8 read_a_frag32(const ushort* As, int lg, int row) {
  return *(const short8*)(As + ((lg * 32 + (row ^ lg)) * 8));
}
__device__ __forceinline__ short8 read_a_frag64(const ushort* As, int lg, int row) {
  return *(const short8*)(As + ((lg * 64 + (row ^ lg)) * 8));
}
__device__ __forceinline__ short8 read_b_frag(const ushort* Bs, int lg, int col) {
  int boff = (col * 16) ^ (((col >> 3) & 7) << 4);
  return *(const short8*)((const char*)Bs + lg * 1024 + boff);
}

// B-tile staging from f32 (pack kernels only)
__device__ __forceinline__ void stage_B_tile(const float* __restrict__ B, int ldb,
                                             int k0, int col0, ushort* Bs, int tid) {
  int a = tid >> 4;
  int cG = tid & 15;
  int k = 2 * a;
  const float* p0 = B + (size_t)(k0 + k) * ldb + col0 + cG * 4;
  const float* p1 = p0 + ldb;
  float4 r0 = *(const float4*)p0;
  float4 r1 = *(const float4*)p1;
  int gg = (k & 15) >> 2;
  int slot = (k & 3) + ((k >> 4) << 2);
  float v0[4] = {r0.x, r0.y, r0.z, r0.w};
  float v1[4] = {r1.x, r1.y, r1.z, r1.w};
  char* plane = (char*)Bs + gg * 1024;
  #pragma unroll
  for (int j = 0; j < 4; ++j) {
    int c = cG * 4 + j;
    unsigned pk = (unsigned)f2bf(v0[j]) | ((unsigned)f2bf(v1[j]) << 16);
    int boff = ((c * 16) ^ (((c >> 3) & 7) << 4)) + slot * 2;
    *(unsigned*)(plane + boff) = pk;
  }
}

// ---------------------------------------------------------------------
// Pack kernel: f32 KxN matrix -> bf16 pre-swizzled B-tile images.
// ---------------------------------------------------------------------
__global__ __launch_bounds__(256) void pack_B_kernel(
    const float* __restrict__ src, ushort* __restrict__ dst, int N) {
  __shared__ ushort tileB[2048];
  int tid = threadIdx.x;
  stage_B_tile(src, N, blockIdx.y * 32, blockIdx.x * 64, tileB, tid);
  __syncthreads();
  size_t toff = ((size_t)blockIdx.y * gridDim.x + blockIdx.x) * 2048;
  *(short8*)(dst + toff + tid * 8) = *(const short8*)(tileB + tid * 8);
}

// ---------------------------------------------------------------------
// Dense GEMM (r10 verified): BM=64, BN=64, ring-4, dist-3.
// ---------------------------------------------------------------------
__global__ __launch_bounds__(256) void gemm64_bb(
    const ushort* __restrict__ Ab, const ushort* __restrict__ Bpk,
    float* __restrict__ C, int M, int N, int K) {
  __shared__ ushort As[4][2048];
  __shared__ ushort Bs[4][2048];
  int tid = threadIdx.x;
  int row0 = blockIdx.y * 64, col0 = blockIdx.x * 64;
  int ntn = N >> 6;
  int wid = tid >> 6, lane = tid & 63;
  int lg = lane >> 4, lr = lane & 15;
  int wrow = (wid >> 1) * 32, wcol = (wid & 1) * 32;
  const ushort* asrc = Ab + (size_t)(row0 + (lane ^ wid)) * K + wid * 8;
  const ushort* bsrc = Bpk + (size_t)blockIdx.x * 2048 + wid * 512 + lane * 8;
  const int NT = K >> 5;
  f32x4 acc[2][2] = {};

  auto issue = [&](int tt) {
    int b = tt & 3;
    gload16(asrc + tt * 32, &As[b][wid * 512]);
    gload16(bsrc + (size_t)tt * ntn * 2048, &Bs[b][wid * 512]);
  };
  issue(0); issue(1); issue(2);
  for (int t = 0; t < NT; ++t) {
    int ahead = NT - 1 - t;
    if (ahead >= 2)      asm volatile("s_waitcnt vmcnt(4)" ::: "memory");
    else if (ahead == 1) asm volatile("s_waitcnt vmcnt(2)" ::: "memory");
    else                 asm volatile("s_waitcnt vmcnt(0)" ::: "memory");
    __builtin_amdgcn_s_barrier();
    if (t + 3 < NT) issue(t + 3);
    int cb = t & 3;
    short8 af0 = read_a_frag64(&As[cb][0], lg, wrow + lr);
    short8 af1 = read_a_frag64(&As[cb][0], lg, wrow + 16 + lr);
    #pragma unroll
    for (int nn = 0; nn < 2; ++nn) {
      short8 bf_ = read_b_frag(&Bs[cb][0], lg, wcol + nn * 16 + lr);
      acc[0][nn] = __builtin_amdgcn_mfma_f32_16x16x32_bf16(af0, bf_, acc[0][nn], 0, 0, 0);
      acc[1][nn] = __builtin_amdgcn_mfma_f32_16x16x32_bf16(af1, bf_, acc[1][nn], 0, 0, 0);
    }
  }
  #pragma unroll
  for (int mm = 0; mm < 2; ++mm)
    #pragma unroll
    for (int nn = 0; nn < 2; ++nn) {
      int row = row0 + wrow + mm * 16 + lg * 4;
      int col = col0 + wcol + nn * 16 + lr;
      #pragma unroll
      for (int i = 0; i < 4; ++i)
        C[(size_t)(row + i) * N + col] = acc[mm][nn][i];
    }
}

// ---------------------------------------------------------------------
// MoE up-proj v3 + XCD-chunked swizzle: all slot-blocks of an expert
// (consecutive sb) land on the SAME XCD so weight slices are L2-shared.
// grid (MAXSB=8*36, IMID/64); gridX%8==0 keeps mapping bz-invariant.
// ---------------------------------------------------------------------
__global__ __launch_bounds__(256) void moe_up_pk(
    const ushort* __restrict__ hln2b, const ushort* __restrict__ Wpk,
    const int* __restrict__ perm, const int* __restrict__ offs,
    const int* __restrict__ counts, const int* __restrict__ sb_e,
    const int* __restrict__ sb_base, const int* __restrict__ nsb,
    ushort* __restrict__ actb) {
  int b = blockIdx.x;
  int sb = ((b & 7) * 36) + (b >> 3);   // XCD-chunked remap (T1, m192 form)
  if (sb >= *nsb) return;
  int e = sb_e[sb];
  int base = sb_base[sb];
  int start = offs[e];
  int nt = min(32, counts[e] - base);
  __shared__ int tokmap[32];
  int tid = threadIdx.x;
  if (tid < 32) tokmap[tid] = perm[start + base + ((tid < nt) ? tid : 0)] >> 2;
  __shared__ ushort As[3][1024];
  __shared__ ushort Bg[3][2048];
  __shared__ ushort Bu[3][2048];
  __syncthreads();
  int bz = blockIdx.y, col0 = bz * 64;
  int wid = tid >> 6, lane = tid & 63;
  int lg = lane >> 4, lr = lane & 15;
  int wrow = (wid >> 1) * 16, wcol = (wid & 1) * 32;
  const ushort* bgt = Wpk + ((size_t)(e * 32) * 12 + bz) * 2048 + wid * 512 + lane * 8;
  const ushort* but = bgt + (size_t)6 * 2048;
  int ga = wid * 2 + (lane >> 5);
  const ushort* asrcA = hln2b + (size_t)tokmap[(lane & 31) ^ ga] * HH + ga * 8;
  const int NT = HH >> 5;   // 32
  f32x4 accg[2] = {}, accu[2] = {};

  auto issue = [&](int tt) {
    int bb = tt % 3;
    if (wid < 2) gload16(asrcA + tt * 32, &As[bb][wid * 1024 / 2]);
    gload16(bgt + (size_t)tt * 12 * 2048, &Bg[bb][wid * 512]);
    gload16(but + (size_t)tt * 12 * 2048, &Bu[bb][wid * 512]);
  };
  issue(0); issue(1);
  for (int t = 0; t < NT; ++t) {
    if (t < NT - 1) {
      if (wid < 2) asm volatile("s_waitcnt vmcnt(3)" ::: "memory");
      else         asm volatile("s_waitcnt vmcnt(2)" ::: "memory");
    } else {
      asm volatile("s_waitcnt vmcnt(0)" ::: "memory");
    }
    __builtin_amdgcn_s_barrier();
    if (t + 2 < NT) issue(t + 2);
    int cb = t % 3;
    short8 af = read_a_frag32(&As[cb][0], lg, wrow + lr);
    #pragma unroll
    for (int nn = 0; nn < 2; ++nn) {
      short8 bgf = read_b_frag(&Bg[cb][0], lg, wcol + nn * 16 + lr);
      short8 buf_ = read_b_frag(&Bu[cb][0], lg, wcol + nn * 16 + lr);
      accg[nn] = __builtin_amdgcn_mfma_f32_16x16x32_bf16(af, bgf, accg[nn], 0, 0, 0);
      accu[nn] = __builtin_amdgcn_mfma_f32_16x16x32_bf16(af, buf_, accu[nn], 0, 0, 0);
    }
  }
  #pragma unroll
  for (int nn = 0; nn < 2; ++nn) {
    int pcol = col0 + ((wid & 1) << 5) + ((lr >> 2) << 3) + (nn << 2) + (lr & 3);
    #pragma unroll
    for (int i = 0; i < 4; ++i) {
      int rr = wrow + lg * 4 + i;
      if (rr < nt) {
        float gv = accg[nn][i], uv = accu[nn][i];
        float av = gv / (1.f + expf(-gv)) * uv;
        actb[(size_t)(start + base + rr) * IMID + pcol] = f2bf(av);
      }
    }
  }
}

// ---------------------------------------------------------------------
// MoE down-proj v3 + XCD-chunked swizzle. grid (MAXSB, HH/64).
// ---------------------------------------------------------------------
__global__ __launch_bounds__(256) void moe_down_pk(
    const ushort* __restrict__ actb, const ushort* __restrict__ Wpk,
    const int* __restrict__ offs, const int* __restrict__ counts,
    const int* __restrict__ sb_e, const int* __restrict__ sb_base,
    const int* __restrict__ nsb, ushort* __restrict__ partialb) {
  int b = blockIdx.x;
  int sb = ((b & 7) * 36) + (b >> 3);   // XCD-chunked remap
  if (sb >= *nsb) return;
  int e = sb_e[sb];
  int base = sb_base[sb];
  int start = offs[e];
  int nt = min(32, counts[e] - base);
  __shared__ ushort As[3][1024];
  __shared__ ushort Bs[3][2048];
  int tid = threadIdx.x;
  int bz = blockIdx.y, col0 = bz * 64;
  int wid = tid >> 6, lane = tid & 63;
  int lg = lane >> 4, lr = lane & 15;
  int wrow = (wid >> 1) * 16, wcol = (wid & 1) * 32;
  const ushort* bt0 = Wpk + ((size_t)(e * 12) * 16 + bz) * 2048 + wid * 512 + lane * 8;
  int ga = wid * 2 + (lane >> 5);
  const ushort* asrcA = actb + (size_t)(start + base + ((lane & 31) ^ ga)) * IMID + ga * 8;
  const int NT = IMID >> 5;   // 12
  f32x4 acc[2] = {};

  auto issue = [&](int tt) {
    int bb = tt % 3;
    if (wid < 2) gload16(asrcA + tt * 32, &As[bb][wid * 512]);
    gload16(bt0 + (size_t)tt * 16 * 2048, &Bs[bb][wid * 512]);
  };
  issue(0); issue(1);
  for (int t = 0; t < NT; ++t) {
    if (t < NT - 1) {
      if (wid < 2) asm volatile("s_waitcnt vmcnt(2)" ::: "memory");
      else         asm volatile("s_waitcnt vmcnt(1)" ::: "memory");
    } else {
      asm volatile("s_waitcnt vmcnt(0)" ::: "memory");
    }
    __builtin_amdgcn_s_barrier();
    if (t + 2 < NT) issue(t + 2);
    int cb = t % 3;
    short8 af = read_a_frag32(&As[cb][0], lg, wrow + lr);
    #pragma unroll
    for (int nn = 0; nn < 2; ++nn) {
      short8 bf_ = read_b_frag(&Bs[cb][0], lg, wcol + nn * 16 + lr);
      acc[nn] = __builtin_amdgcn_mfma_f32_16x16x32_bf16(af, bf_, acc[nn], 0, 0, 0);
    }
  }
  #pragma unroll
  for (int nn = 0; nn < 2; ++nn)
    #pragma unroll
    for (int i = 0; i < 4; ++i) {
      int rr = wrow + lg * 4 + i;
      if (rr < nt)
        partialb[(size_t)(start + base + rr) * HH + col0 + wcol + nn * 16 + lr] = f2bf(acc[nn][i]);
    }
}

// =====================================================================
// residual add + RMSNorm; emits f32 sum, f32 ln, permuted bf16 ln.
// =====================================================================
__global__ __launch_bounds__(256) void add_rms_kernel(
    const float* __restrict__ a, const float* __restrict__ b,
    const float* __restrict__ w, float* __restrict__ sum_out,
    float* __restrict__ ln_out, ushort* __restrict__ lnb) {
  int t = blockIdx.x, tid = threadIdx.x;
  float4 x = reinterpret_cast<const float4*>(a + (size_t)t*HH)[tid];
  float4 y = reinterpret_cast<const float4*>(b + (size_t)t*HH)[tid];
  x.x += y.x; x.y += y.y; x.z += y.z; x.w += y.w;
  float ss = x.x*x.x + x.y*x.y + x.z*x.z + x.w*x.w;
  #pragma unroll
  for (int off = 1; off < 64; off <<= 1) ss += __shfl_xor(ss, off);
  __shared__ float wsum[4];
  int wid = tid >> 6, lane = tid & 63;
  if (lane == 0) wsum[wid] = ss;
  __syncthreads();
  float tot = wsum[0] + wsum[1] + wsum[2] + wsum[3];
  float r = rsqrtf(tot * (1.0f/HH) + EPS_);
  reinterpret_cast<float4*>(sum_out + (size_t)t*HH)[tid] = x;
  float4 wl = reinterpret_cast<const float4*>(w)[tid];
  float4 o = make_float4(x.x*r*wl.x, x.y*r*wl.y, x.z*r*wl.z, x.w*r*wl.w);
  reinterpret_cast<float4*>(ln_out + (size_t)t*HH)[tid] = o;
  ushort4 ub;
  ub.x = f2bf(o.x); ub.y = f2bf(o.y); ub.z = f2bf(o.z); ub.w = f2bf(o.w);
  int dst = ((tid >> 3) << 5) + ((tid & 3) << 3) + (((tid >> 2) & 1) << 2);
  *(ushort4*)(lnb + (size_t)t * HH + dst) = ub;
}

// =====================================================================
// per-(t,head) QK RMSNorm + RoPE, in-place (f32)
// =====================================================================
__global__ __launch_bounds__(256) void qk_norm_rope_kernel(
    float* __restrict__ qkv, const float* __restrict__ qw,
    const float* __restrict__ kw, const int* __restrict__ pos) {
  int t = blockIdx.x;
  int hh = blockIdx.y * 4 + (threadIdx.x >> 6);
  int lane = threadIdx.x & 63;
  float* p = qkv + (size_t)t * QKV_W + hh * HDIM;
  float x = p[lane];
  float ss = x * x;
  #pragma unroll
  for (int off = 1; off < 64; off <<= 1) ss += __shfl_xor(ss, off);
  float r = rsqrtf(ss * (1.0f/HDIM) + EPS_);
  float wv = (hh < NHEADS ? qw : kw)[lane];
  float xn = x * r * wv;
  float partner = __shfl_xor(xn, 16);
  float out = xn;
  if (lane < 32) {
    int i = lane & 15;
    float inv = powf(10000.0f, -(float)i / 16.0f);
    float ang = (float)pos[t] * inv;
    float cv = cosf(ang), sv = sinf(ang);
    out = (lane < 16) ? (xn * cv - partner * sv) : (partner * sv + xn * cv);
  }
  p[lane] = out;
}

// =====================================================================
// pack_KV: rope'd K -> A-tile images; V -> B-tile images. grid (T/32, NKVH)
// =====================================================================
__global__ __launch_bounds__(256) void pack_KV_kernel(
    const float* __restrict__ qkv, ushort* __restrict__ Kpk,
    ushort* __restrict__ Vpk) {
  __shared__ ushort kimg[2048];
  __shared__ ushort vimg[2048];
  int tid = threadIdx.x;
  int kt = blockIdx.x, kvh = blockIdx.y;
  {
    int c = tid >> 7, t2 = tid & 127;
    int g = t2 & 3, r = t2 >> 2;
    const float* kp = qkv + (size_t)(kt*32 + r) * QKV_W + NHEADS*HDIM + kvh*HDIM + 32*c + 4*g;
    float4 h0 = *(const float4*)kp;
    float4 h1 = *(const float4*)(kp + 16);
    short8 v;
    v[0]=(short)f2bf(h0.x); v[1]=(short)f2bf(h0.y); v[2]=(short)f2bf(h0.z); v[3]=(short)f2bf(h0.w);
    v[4]=(short)f2bf(h1.x); v[5]=(short)f2bf(h1.y); v[6]=(short)f2bf(h1.z); v[7]=(short)f2bf(h1.w);
    *(short8*)(kimg + c*1024 + (g*32 + (r^g))*8) = v;
  }
  stage_B_tile(qkv + (size_t)(NHEADS+NKVH)*HDIM + (size_t)kvh*HDIM, QKV_W, kt*32, 0, vimg, tid);
  __syncthreads();
  size_t toff = ((size_t)(kvh * (TT/32) + kt)) * 2048;
  *(short8*)(Kpk + toff + tid * 8) = *(const short8*)(kimg + tid * 8);
  *(short8*)(Vpk + toff + tid * 8) = *(const short8*)(vimg + tid * 8);
}

// =====================================================================
// Attention v3 (r12 verified): split-KV + fixed-max log2 softmax.
// =====================================================================
__global__ __launch_bounds__(256) void attn_v3_kernel(
    const float* __restrict__ qkv, const ushort* __restrict__ Kpk,
    const ushort* __restrict__ Vpk, ushort* __restrict__ ob,
    float* __restrict__ po, float* __restrict__ pl) {
  __shared__ ushort Ks[3][2048];
  __shared__ ushort Vs[3][2048];
  int tid = threadIdx.x;
  int wid = tid >> 6, lane = tid & 63;
  int lg = lane >> 4, lr = lane & 15;
  int h = blockIdx.y;
  int f = blockIdx.x;
  int g = 0;
  while (f >= 4 * (g + 1) * (g + 2)) ++g;
  int r_ = f - 4 * g * (g + 1);
  int ns = g + 1;
  int qb = 8 * g + r_ / ns;
  int s = r_ % ns;
  int tiles_total = 2 * qb + 2;
  int per = (tiles_total + ns - 1) / ns;
  int lo = s * per;
  int nloc = min(per, tiles_total - lo);
  int kvh = h >> 2;
  int q0 = qb * 64 + wid * 16;
  int qg = q0 + lr;
  const float SCL = 0.125f * 1.44269504f;
  const float FM = 16.0f;

  const float* qrow = qkv + (size_t)qg * QKV_W + h * HDIM;
  short8 qfr[2];
  #pragma unroll
  for (int c = 0; c < 2; ++c) {
    float4 a = *(const float4*)(qrow + 32*c + 4*lg);
    float4 b = *(const float4*)(qrow + 32*c + 4*lg + 16);
    short8 v;
    v[0]=(short)f2bf(a.x*SCL); v[1]=(short)f2bf(a.y*SCL); v[2]=(short)f2bf(a.z*SCL); v[3]=(short)f2bf(a.w*SCL);
    v[4]=(short)f2bf(b.x*SCL); v[5]=(short)f2bf(b.y*SCL); v[6]=(short)f2bf(b.z*SCL); v[7]=(short)f2bf(b.w*SCL);
    qfr[c] = v;
  }

  const ushort* ksrc = Kpk + (size_t)(kvh * (TT/32) + lo) * 2048 + wid * 512 + lane * 8;
  const ushort* vsrc = Vpk + (size_t)(kvh * (TT/32) + lo) * 2048 + wid * 512 + lane * 8;

  f32x4 o_acc[4] = {};
  float l_st = 0.f;

  auto issue = [&](int tt) {
    int b = tt % 3;
    gload16(ksrc + (size_t)tt * 2048, &Ks[b][wid * 512]);
    gload16(vsrc + (size_t)tt * 2048, &Vs[b][wid * 512]);
  };
  issue(0);
  if (nloc > 1) issue(1);
  for (int tt = 0; tt < nloc; ++tt) {
    if (tt < nloc - 1) asm volatile("s_waitcnt vmcnt(2)" ::: "memory");
    else               asm volatile("s_waitcnt vmcnt(0)" ::: "memory");
    __builtin_amdgcn_s_barrier();
    if (tt + 2 < nloc) issue(tt + 2);
    int t = lo + tt;
    if (t * 32 > q0 + 15) continue;
    int cb = tt % 3;
    f32x4 st[2];
    #pragma unroll
    for (int n = 0; n < 2; ++n) {
      short8 kf0 = *(const short8*)(&Ks[cb][(lg*32 + ((16*n + lr) ^ lg)) * 8]);
      short8 kf1 = *(const short8*)(&Ks[cb][1024 + (lg*32 + ((16*n + lr) ^ lg)) * 8]);
      f32x4 z = {};
      z = __builtin_amdgcn_mfma_f32_16x16x32_bf16(kf0, qfr[0], z, 0, 0, 0);
      st[n] = __builtin_amdgcn_mfma_f32_16x16x32_bf16(kf1, qfr[1], z, 0, 0, 0);
    }
    float p[2][4];
    float psum = 0.f;
    if (t * 32 + 31 <= q0) {
      #pragma unroll
      for (int n = 0; n < 2; ++n)
        #pragma unroll
        for (int i = 0; i < 4; ++i) {
          float pv = exp2f(st[n][i] - FM);
          p[n][i] = pv; psum += pv;
        }
    } else {
      #pragma unroll
      for (int n = 0; n < 2; ++n)
        #pragma unroll
        for (int i = 0; i < 4; ++i) {
          int kvg = t*32 + 16*n + 4*lg + i;
          float pv = (kvg <= qg) ? exp2f(st[n][i] - FM) : 0.f;
          p[n][i] = pv; psum += pv;
        }
    }
    psum += __shfl_xor(psum, 16);
    psum += __shfl_xor(psum, 32);
    l_st += psum;
    union { unsigned u[4]; short8 s8; } pu;
    asm volatile("v_cvt_pk_bf16_f32 %0, %1, %2" : "=v"(pu.u[0]) : "v"(p[0][0]), "v"(p[0][1]));
    asm volatile("v_cvt_pk_bf16_f32 %0, %1, %2" : "=v"(pu.u[1]) : "v"(p[0][2]), "v"(p[0][3]));
    asm volatile("v_cvt_pk_bf16_f32 %0, %1, %2" : "=v"(pu.u[2]) : "v"(p[1][0]), "v"(p[1][1]));
    asm volatile("v_cvt_pk_bf16_f32 %0, %1, %2" : "=v"(pu.u[3]) : "v"(p[1][2]), "v"(p[1][3]));
    short8 pa = pu.s8;
    #pragma unroll
    for (int nd = 0; nd < 4; ++nd) {
      short8 vf = read_b_frag(&Vs[cb][0], lg, 16*nd + lr);
      o_acc[nd] = __builtin_amdgcn_mfma_f32_16x16x32_bf16(pa, vf, o_acc[nd], 0, 0, 0);
    }
  }

  if (ns == 1) {
    #pragma unroll
    for (int i = 0; i < 4; ++i) {
      float lrow = __shfl(l_st, 4*lg + i);
      float inv = 1.0f / lrow;
      int row = q0 + 4*lg + i;
      ushort* op = ob + (size_t)row * (NHEADS*HDIM) + h * HDIM;
      #pragma unroll
      for (int nd = 0; nd < 4; ++nd) {
        int pcol = ((nd >> 1) << 5) + ((lr >> 2) << 3) + ((nd & 1) << 2) + (lr & 3);
        op[pcol] = f2bf(o_acc[nd][i] * inv);
      }
    }
  } else {
    float* pob = po + ((size_t)f * NHEADS + h) * 4096;
    #pragma unroll
    for (int nd = 0; nd < 4; ++nd)
      #pragma unroll
      for (int i = 0; i < 4; ++i)
        pob[(wid * 16 + lg * 4 + i) * 64 + 16 * nd + lr] = o_acc[nd][i];
    if (lg == 0)
      pl[((size_t)f * NHEADS + h) * 64 + wid * 16 + lr] = l_st;
  }
}

// =====================================================================
// attn combine (r12 verified)
// =====================================================================
__global__ __launch_bounds__(256) void attn_combine_kernel(
    const float* __restrict__ po, const float* __restrict__ pl,
    ushort* __restrict__ ob) {
  int h = blockIdx.x;
  int qb = 8 + blockIdx.y;
  int g = qb >> 3;
  int ns = g + 1;
  int f0 = 4 * g * (g + 1) + (qb - 8 * g) * ns;
  int tid = threadIdx.x;
  int r = tid >> 2, c = tid & 3;
  float acc[16] = {};
  float lsum = 0.f;
  for (int s = 0; s < ns; ++s) {
    size_t base = ((size_t)(f0 + s) * NHEADS + h) * 4096 + r * 64 + c * 16;
    #pragma unroll
    for (int j = 0; j < 4; ++j) {
      float4 v = *(const float4*)(po + base + j * 4);
      acc[j*4+0] += v.x; acc[j*4+1] += v.y; acc[j*4+2] += v.z; acc[j*4+3] += v.w;
    }
    lsum += pl[((size_t)(f0 + s) * NHEADS + h) * 64 + r];
  }
  float inv = 1.0f / lsum;
  int row = qb * 64 + r;
  ushort* op = ob + (size_t)row * (NHEADS*HDIM) + h * HDIM + (c >> 1) * 32 + (c & 1) * 4;
  #pragma unroll
  for (int a = 0; a < 4; ++a) {
    ushort4 u;
    u.x = f2bf(acc[a*4+0] * inv); u.y = f2bf(acc[a*4+1] * inv);
    u.z = f2bf(acc[a*4+2] * inv); u.w = f2bf(acc[a*4+3] * inv);
    *(ushort4*)(op + a * 8) = u;
  }
}

// =====================================================================
// router: wave-parallel (r8 verified)
// =====================================================================
__global__ __launch_bounds__(256) void router_kernel(
    const float* __restrict__ hln, const float* __restrict__ Wg,
    const float* __restrict__ bias, int* __restrict__ sel_e,
    float* __restrict__ sel_w) {
  __shared__ float hid[4][HH];
  int tid = threadIdx.x, wid = tid >> 6, lane = tid & 63;
  int t = blockIdx.x * 4 + wid;
  const float4* src = (const float4*)(hln + (size_t)t * HH);
  float4* dst = (float4*)hid[wid];
  #pragma unroll
  for (int j = 0; j < 4; ++j) dst[j * 64 + lane] = src[j * 64 + lane];
  int e = lane & 31, half = lane >> 5;
  const float* wp = Wg + (size_t)(half * 512) * NEXP + e;
  const float* hp = hid[wid] + half * 512;
  float p = 0.f;
  #pragma unroll 8
  for (int h = 0; h < 512; ++h) p += hp[h] * wp[(size_t)h * NEXP];
  p += __shfl_xor(p, 32);
  float sc = 1.0f / (1.0f + expf(-p));
  float sfc = sc + bias[e];
  float m1 = sfc, m2 = -1e30f;
  #pragma unroll
  for (int off = 1; off <= 4; off <<= 1) {
    float om1 = __shfl_xor(m1, off), om2 = __shfl_xor(m2, off);
    float hi_ = fmaxf(m1, om1);
    float lo_ = fmaxf(fminf(m1, om1), fmaxf(m2, om2));
    m1 = hi_; m2 = lo_;
  }
  float gs = m1 + m2;
  float gv[4] = {__shfl(gs, 0), __shfl(gs, 8), __shfl(gs, 16), __shfl(gs, 24)};
  int g1 = 0; float b1 = gv[0];
  #pragma unroll
  for (int g = 1; g < 4; ++g) if (gv[g] > b1) { b1 = gv[g]; g1 = g; }
  int g2 = -1; float b2 = -1e30f;
  #pragma unroll
  for (int g = 0; g < 4; ++g) if (g != g1 && gv[g] > b2) { b2 = gv[g]; g2 = g; }
  bool keep = ((e >> 3) == g1) || ((e >> 3) == g2);
  float cand = keep ? sfc : -1e30f;
  int ids[4]; float wv[4]; float wsum = 0.f;
  #pragma unroll
  for (int s = 0; s < 4; ++s) {
    float v = cand; int ix = e;
    #pragma unroll
    for (int off = 1; off < 64; off <<= 1) {
      float ov = __shfl_xor(v, off); int oix = __shfl_xor(ix, off);
      if (ov > v || (ov == v && oix < ix)) { v = ov; ix = oix; }
    }
    ids[s] = ix;
    if (e == ix) cand = -1e30f;
    float w = __shfl(sc, ix);
    wv[s] = w; wsum += w;
  }
  if (lane == 0) {
    #pragma unroll
    for (int s = 0; s < 4; ++s) {
      sel_e[t * 4 + s] = ids[s];
      sel_w[t * 4 + s] = wv[s] / wsum;
    }
  }
}

__global__ __launch_bounds__(256) void count_kernel(
    const int* __restrict__ sel_e, int* __restrict__ counts) {
  int e = blockIdx.x, tid = threadIdx.x;
  int c = 0;
  for (int i = tid; i < TT * TOPK_; i += 256) c += (sel_e[i] == e);
  #pragma unroll
  for (int off = 1; off < 64; off <<= 1) c += __shfl_xor(c, off);
  __shared__ int wsum[4];
  if ((tid & 63) == 0) wsum[tid >> 6] = c;
  __syncthreads();
  if (tid == 0) counts[e] = wsum[0] + wsum[1] + wsum[2] + wsum[3];
}

// scan + flat slot-block table (BM=32 granularity)
__global__ void scan_kernel(const int* __restrict__ counts,
                            int* __restrict__ offs, int* __restrict__ cursor,
                            int* __restrict__ sb_e, int* __restrict__ sb_base,
                            int* __restrict__ nsb) {
  if (threadIdx.x == 0) {
    int acc = 0, n = 0;
    for (int e = 0; e < NEXP; ++e) {
      offs[e] = acc; cursor[e] = acc;
      int c = counts[e];
      for (int b = 0; b < c; b += 32) { sb_e[n] = e; sb_base[n] = b; ++n; }
      acc += c;
    }
    *nsb = n;
  }
}

__global__ void scatter_kernel(const int* __restrict__ sel_e,
                               int* __restrict__ cursor, int* __restrict__ perm,
                               int* __restrict__ ipos) {
  int i = blockIdx.x * 256 + threadIdx.x;
  if (i < TT * TOPK_) {
    int e = sel_e[i];
    int pos = atomicAdd(&cursor[e], 1);
    perm[pos] = i;
    ipos[i] = pos;
  }
}

// =====================================================================
// shared-expert SiLU*mul -> permuted bf16 (4 cols/thread)
// =====================================================================
__global__ __launch_bounds__(256) void silu_shared_kernel(
    const float* __restrict__ gus, ushort* __restrict__ shsb) {
  int i = blockIdx.x * 256 + threadIdx.x;
  if (i < TT * (ISHARED/4)) {
    int t = i / (ISHARED/4), k = i % (ISHARED/4);
    const float* gp = gus + (size_t)t * (2*ISHARED) + k * 4;
    float4 g4 = *(const float4*)gp;
    float4 u4 = *(const float4*)(gp + ISHARED);
    ushort4 r;
    r.x = f2bf(g4.x / (1.f + expf(-g4.x)) * u4.x);
    r.y = f2bf(g4.y / (1.f + expf(-g4.y)) * u4.y);
    r.z = f2bf(g4.z / (1.f + expf(-g4.z)) * u4.z);
    r.w = f2bf(g4.w / (1.f + expf(-g4.w)) * u4.w);
    int pdst = ((k >> 3) << 5) + ((k & 3) << 3) + (((k >> 2) & 1) << 2);
    *(ushort4*)(shsb + (size_t)t * ISHARED + pdst) = r;
  }
}

// =====================================================================
// final combine (bf16 partial)
// =====================================================================
__global__ __launch_bounds__(256) void final_combine_kernel(
    const ushort* __restrict__ partialb, const float* __restrict__ sel_w,
    const int* __restrict__ ipos, const float* __restrict__ shared_out,
    float* __restrict__ out_hidden) {
  int t = blockIdx.x, tid = threadIdx.x;
  float w0 = sel_w[t*4], w1 = sel_w[t*4+1], w2 = sel_w[t*4+2], w3 = sel_w[t*4+3];
  int p0 = ipos[t*4], p1 = ipos[t*4+1], p2 = ipos[t*4+2], p3 = ipos[t*4+3];
  ushort4 a0 = *(const ushort4*)(partialb + (size_t)p0*HH + tid*4);
  ushort4 a1 = *(const ushort4*)(partialb + (size_t)p1*HH + tid*4);
  ushort4 a2 = *(const ushort4*)(partialb + (size_t)p2*HH + tid*4);
  ushort4 a3 = *(const ushort4*)(partialb + (size_t)p3*HH + tid*4);
  float4 sh = reinterpret_cast<const float4*>(shared_out + (size_t)t*HH)[tid];
  float4 r;
  r.x = (w0*bf2f(a0.x) + w1*bf2f(a1.x) + w2*bf2f(a2.x) + w3*bf2f(a3.x)) + sh.x;
  r.y = (w0*bf2f(a0.y) + w1*bf2f(a1.y) + w2*bf2f(a2.y) + w3*bf2f(a3.y)) + sh.y;
  r.z = (w0*bf2f(a0.z) + w1*bf2f(a1.z) + w2*bf2f(a2.z) + w3*bf2f(a3.z)) + sh.z;
  r.w = (w0*bf2f(a0.w) + w1*bf2f(a1.w) + w2*bf2f(a2.w) + w3*bf2f(a3.w)) + sh.w;
  reinterpret_cast<float4*>(out_hidden + (size_t)t*HH)[tid] = r;
}

// =====================================================================
extern "C" void kernel_launch(void* const* d_in, const int* in_sizes, int n_in,
                              void* d_out, int out_size, void* d_ws, size_t ws_size,
                              hipStream_t stream) {
  const float* hidden   = (const float*)d_in[0];
  const float* residual = (const float*)d_in[1];
  const float* in_ln_w  = (const float*)d_in[2];
  const float* post_ln_w= (const float*)d_in[3];
  const float* q_norm_w = (const float*)d_in[4];
  const float* k_norm_w = (const float*)d_in[5];
  const float* Wqkv     = (const float*)d_in[6];
  const float* Wo       = (const float*)d_in[7];
  const float* Wg       = (const float*)d_in[8];
  const float* gate_bias= (const float*)d_in[9];
  const float* Wgu      = (const float*)d_in[10];
  const float* Wd       = (const float*)d_in[11];
  const float* Wgu_sh   = (const float*)d_in[12];
  const float* Wd_sh    = (const float*)d_in[13];
  const int*   positions= (const int*)d_in[14];
  float* out = (float*)d_out;

  float* f = (float*)d_ws;
  size_t off = 0;
  float* R_A   = f + off; off += (size_t)TT*HH;
  float* HLN   = f + off; off += (size_t)TT*HH;
  float* QKV   = f + off; off += (size_t)TT*QKV_W;        // reused as gus
  float* OATT  = f + off; off += (size_t)TT*HH;           // DSH output (shared_out)
  float* HLN2  = f + off; off += (size_t)TT*HH;
  float* SELW  = f + off; off += (size_t)TT*TOPK_;
  float* PO    = f + off; off += (size_t)NSPLITS*NHEADS*4096;  // attn partial O
  float* PL    = f + off; off += (size_t)NSPLITS*NHEADS*64;    // attn partial l
  ushort* HLNB  = (ushort*)(f + off); off += (size_t)TT*HH/2;
  ushort* HLN2B = (ushort*)(f + off); off += (size_t)TT*HH/2;
  ushort* OATTB = (ushort*)(f + off); off += (size_t)TT*HH/2;
  ushort* SHSB  = (ushort*)(f + off); off += (size_t)TT*ISHARED/2;
  ushort* KPK   = (ushort*)(f + off); off += (size_t)NKVH*(TT/32)*2048/2;
  ushort* VPK   = (ushort*)(f + off); off += (size_t)NKVH*(TT/32)*2048/2;
  ushort* ACTB  = (ushort*)(f + off); off += (size_t)(TT*TOPK_ + 128)*IMID/2;
  ushort* PARTB = (ushort*)(f + off); off += (size_t)TT*TOPK_*HH/2;
  ushort* PK_QKV = (ushort*)(f + off); off += (size_t)HH*QKV_W/2;
  ushort* PK_WO  = (ushort*)(f + off); off += (size_t)HH*HH/2;
  ushort* PK_WGU = (ushort*)(f + off); off += (size_t)NEXP*HH*(2*IMID)/2;
  ushort* PK_WD  = (ushort*)(f + off); off += (size_t)NEXP*IMID*HH/2;
  ushort* PK_GUSH= (ushort*)(f + off); off += (size_t)HH*(2*ISHARED)/2;
  ushort* PK_DSH = (ushort*)(f + off); off += (size_t)ISHARED*HH/2;
  int* ibase   = (int*)(f + off);
  int* SELE    = ibase;
  int* PERM    = ibase + TT*TOPK_;
  int* IPOS    = ibase + 2*TT*TOPK_;
  int* COUNTS  = ibase + 3*TT*TOPK_;
  int* OFFS    = COUNTS + NEXP;
  int* CURSOR  = OFFS + NEXP;
  int* SB_E    = CURSOR + NEXP;
  int* SB_BASE = SB_E + MAXSB;
  int* NSB     = SB_BASE + MAXSB;

  // 0. pack all weights to bf16 tile images
  pack_B_kernel<<<dim3(QKV_W/64, HH/32), 256, 0, stream>>>(Wqkv, PK_QKV, QKV_W);
  pack_B_kernel<<<dim3(HH/64, HH/32), 256, 0, stream>>>(Wo, PK_WO, HH);
  pack_B_kernel<<<dim3((2*IMID)/64, NEXP*HH/32), 256, 0, stream>>>(Wgu, PK_WGU, 2*IMID);
  pack_B_kernel<<<dim3(HH/64, NEXP*IMID/32), 256, 0, stream>>>(Wd, PK_WD, HH);
  pack_B_kernel<<<dim3((2*ISHARED)/64, HH/32), 256, 0, stream>>>(Wgu_sh, PK_GUSH, 2*ISHARED);
  pack_B_kernel<<<dim3(HH/64, ISHARED/32), 256, 0, stream>>>(Wd_sh, PK_DSH, HH);

  // 1. pipeline
  add_rms_kernel<<<TT, 256, 0, stream>>>(hidden, residual, in_ln_w, R_A, HLN, HLNB);
  gemm64_bb<<<dim3(QKV_W/64, TT/64), 256, 0, stream>>>(HLNB, PK_QKV, QKV, TT, QKV_W, HH);
  qk_norm_rope_kernel<<<dim3(TT, 5), 256, 0, stream>>>(QKV, q_norm_w, k_norm_w, positions);
  pack_KV_kernel<<<dim3(TT/32, NKVH), 256, 0, stream>>>(QKV, KPK, VPK);
  attn_v3_kernel<<<dim3(NSPLITS, NHEADS), 256, 0, stream>>>(QKV, KPK, VPK, OATTB, PO, PL);
  attn_combine_kernel<<<dim3(NHEADS, 24), 256, 0, stream>>>(PO, PL, OATTB);
  gemm64_bb<<<dim3(HH/64, TT/64), 256, 0, stream>>>(OATTB, PK_WO, HLN, TT, HH, HH);
  add_rms_kernel<<<TT, 256, 0, stream>>>(HLN, R_A, post_ln_w, out + (size_t)TT*HH, HLN2, HLN2B);
  router_kernel<<<TT/4, 256, 0, stream>>>(HLN2, Wg, gate_bias, SELE, SELW);
  count_kernel<<<NEXP, 256, 0, stream>>>(SELE, COUNTS);
  scan_kernel<<<1, 64, 0, stream>>>(COUNTS, OFFS, CURSOR, SB_E, SB_BASE, NSB);
  scatter_kernel<<<(TT*TOPK_ + 255)/256, 256, 0, stream>>>(SELE, CURSOR, PERM, IPOS);
  moe_up_pk<<<dim3(MAXSB, IMID/64), 256, 0, stream>>>(HLN2B, PK_WGU, PERM, OFFS, COUNTS, SB_E, SB_BASE, NSB, ACTB);
  moe_down_pk<<<dim3(MAXSB, HH/64), 256, 0, stream>>>(ACTB, PK_WD, OFFS, COUNTS, SB_E, SB_BASE, NSB, PARTB);
  gemm64_bb<<<dim3((2*ISHARED)/64, TT/64), 256, 0, stream>>>(HLN2B, PK_GUSH, QKV, TT, 2*ISHARED, HH);
  silu_shared_kernel<<<(TT*(ISHARED/4) + 255)/256, 256, 0, stream>>>(QKV, SHSB);
  gemm64_bb<<<dim3(HH/64, TT/64), 256, 0, stream>>>(SHSB, PK_DSH, OATT, TT, HH, ISHARED);
  final_combine_kernel<<<TT, 256, 0, stream>>>(PARTB, SELW, IPOS, OATT, out);
}